// Round 4
// baseline (1312.653 us; speedup 1.0000x reference)
//
#include <hip/hip_runtime.h>
#include <hip/hip_fp16.h>
#include <math.h>
#include <stdio.h>

// N=50000, E=800000, IN=128, C=64, H=8, H*C=512
// R3: GEMM epilogue rebuilt — LDS-staged coalesced stores. Evidence: layer-1
// GEMM WRITE_SIZE 208MB vs 154MB ideal (byte-scattered fp8 stores at 1KB
// stride = write amplification + instruction-bound tail), occupancy 19.9%
// capped by launch_bounds(256,2). Fix: stage output tile in LDS (reuse the
// 48KB main-loop buffer), store 16B fp16 rows / 8B fp8 chunks dense;
// fp8 still sourced from f32 (no double rounding). launch_bounds(256,3).
// attn unchanged (fp8 KV from R2: attn_h8 ~<150us each, off top-5).

using f16x8 = __attribute__((ext_vector_type(8))) _Float16;
using f32x4 = __attribute__((ext_vector_type(4))) float;

__device__ __forceinline__ void load_lds16(const void* g, void* l) {
  __builtin_amdgcn_global_load_lds((const __attribute__((address_space(1))) void*)g,
                                   (__attribute__((address_space(3))) void*)l,
                                   16, 0, 0);
}

// ---- fp8 e4m3 helpers (HW cvt on gfx950; software fallback kept for safety) ----
__device__ __forceinline__ void fp8x4_to_f32(unsigned int w, float* o4) {
#if __has_builtin(__builtin_amdgcn_cvt_pk_f32_fp8)
  auto lo = __builtin_amdgcn_cvt_pk_f32_fp8(w, false);
  auto hi = __builtin_amdgcn_cvt_pk_f32_fp8(w, true);
  o4[0] = lo[0]; o4[1] = lo[1]; o4[2] = hi[0]; o4[3] = hi[1];
#else
#pragma unroll
  for (int t = 0; t < 4; ++t) {
    unsigned int b = (w >> (8 * t)) & 0xFFu;
    unsigned short h = (unsigned short)(((b & 0x80u) << 8) | ((b & 0x7Fu) << 7));
    __half hv = *(__half*)&h;
    o4[t] = (float)hv * 256.0f;
  }
#endif
}

__device__ __forceinline__ unsigned int fp8_pack2_sw(float a, float b) {
  unsigned int r = 0;
#pragma unroll
  for (int t = 0; t < 2; ++t) {
    float f = t ? b : a;
    __half h = __float2half(f * (1.0f / 256.0f));
    unsigned short hb = *(unsigned short*)&h;
    unsigned int sign = (hb >> 8) & 0x80u;
    unsigned int mag = (hb & 0x7FFFu) + 0x40u;  // round
    unsigned int e = (mag >> 7) & 0x7Fu;
    if ((mag >> 7) > 0x7Eu) e = 0x7Eu;          // clamp below NaN pattern
    r |= (sign | e) << (8 * t);
  }
  return r;
}

__device__ __forceinline__ uint2 fp8_pack8(const float* f) {
#if __has_builtin(__builtin_amdgcn_cvt_pk_fp8_f32)
  int w0 = __builtin_amdgcn_cvt_pk_fp8_f32(f[0], f[1], 0, false);
  w0 = __builtin_amdgcn_cvt_pk_fp8_f32(f[2], f[3], w0, true);
  int w1 = __builtin_amdgcn_cvt_pk_fp8_f32(f[4], f[5], 0, false);
  w1 = __builtin_amdgcn_cvt_pk_fp8_f32(f[6], f[7], w1, true);
  uint2 r; r.x = (unsigned)w0; r.y = (unsigned)w1; return r;
#else
  uint2 r;
  r.x = fp8_pack2_sw(f[0], f[1]) | (fp8_pack2_sw(f[2], f[3]) << 16);
  r.y = fp8_pack2_sw(f[4], f[5]) | (fp8_pack2_sw(f[6], f[7]) << 16);
  return r;
#endif
}

// ---------------- CSR build ----------------
__global__ void zero_misc_kernel(int* __restrict__ deg, __half* __restrict__ H,
                                 int N, int Npad) {
  int t = blockIdx.x * 256 + threadIdx.x;
  if (t < N) deg[t] = 0;
  int nz = (Npad - N) * 512 / 8;
  if (t < nz) {
    f16x8 z = {};
    *(f16x8*)(H + (size_t)N * 512 + (size_t)t * 8) = z;
  }
}

__global__ void degree_kernel(const int* __restrict__ dst, int* __restrict__ deg, int E) {
  int e = blockIdx.x * blockDim.x + threadIdx.x;
  if (e < E) atomicAdd(&deg[dst[e]], 1);
}

__global__ __launch_bounds__(256)
void scan_a_kernel(const int* __restrict__ deg, int* __restrict__ rowptr,
                   int* __restrict__ bsum, int n) {
  __shared__ int tmp[256];
  int t = threadIdx.x;
  int i = blockIdx.x * 256 + t;
  int v = (i < n) ? deg[i] : 0;
  tmp[t] = v;
  __syncthreads();
#pragma unroll
  for (int off = 1; off < 256; off <<= 1) {
    int u = (t >= off) ? tmp[t - off] : 0;
    __syncthreads();
    tmp[t] += u;
    __syncthreads();
  }
  if (i < n) rowptr[i + 1] = tmp[t];
  if (t == 255) bsum[blockIdx.x] = tmp[255];
}

__global__ __launch_bounds__(256)
void scan_b_kernel(int* __restrict__ bsum, int nb) {
  __shared__ int tmp[256];
  int t = threadIdx.x;
  int v = (t < nb) ? bsum[t] : 0;
  tmp[t] = v;
  __syncthreads();
#pragma unroll
  for (int off = 1; off < 256; off <<= 1) {
    int u = (t >= off) ? tmp[t - off] : 0;
    __syncthreads();
    tmp[t] += u;
    __syncthreads();
  }
  if (t < nb) bsum[t] = tmp[t] - v;  // exclusive
}

__global__ __launch_bounds__(256)
void scan_c_kernel(int* __restrict__ rowptr, int* __restrict__ cursor,
                   const int* __restrict__ bsum, int n) {
  int i = blockIdx.x * 256 + threadIdx.x;
  if (i < n) {
    int r = rowptr[i + 1] + bsum[blockIdx.x];
    rowptr[i + 1] = r;
    cursor[i + 1] = r;
  }
  if (i == 0) { rowptr[0] = 0; cursor[0] = 0; }
}

__global__ void scatter_kernel(const int* __restrict__ src, const int* __restrict__ dst,
                               int* __restrict__ cursor, int* __restrict__ col, int E) {
  int e = blockIdx.x * blockDim.x + threadIdx.x;
  if (e < E) {
    int pos = atomicAdd(&cursor[dst[e]], 1);
    col[pos] = src[e];
  }
}

// ---------------- prep: weights/biases ----------------
__global__ __launch_bounds__(256)
void transpose_all_kernel(
    const float* __restrict__ Wq0, const float* __restrict__ Wk0,
    const float* __restrict__ Wv0, const float* __restrict__ Ws0,
    const float* __restrict__ Wq1, const float* __restrict__ Wk1,
    const float* __restrict__ Wv1, const float* __restrict__ Ws1,
    const float* __restrict__ Wq2, const float* __restrict__ Wk2,
    const float* __restrict__ Wv2, const float* __restrict__ Ws2,
    __half* __restrict__ Wt) {
  int z = blockIdx.z;
  int layer = z >> 2, m = z & 3;
  int K = (layer == 0) ? 128 : 512;
  int D = (layer == 2) ? 64 : 512;
  int c0 = blockIdx.x * 32, k0 = blockIdx.y * 32;
  if (c0 >= D || k0 >= K) return;
  const float* W;
  switch (z) {
    case 0: W = Wq0; break; case 1: W = Wk0; break;
    case 2: W = Wv0; break; case 3: W = Ws0; break;
    case 4: W = Wq1; break; case 5: W = Wk1; break;
    case 6: W = Wv1; break; case 7: W = Ws1; break;
    case 8: W = Wq2; break; case 9: W = Wk2; break;
    case 10: W = Wv2; break; default: W = Ws2; break;
  }
  __half* dstBase = Wt + ((layer == 0) ? 0 : (layer == 1) ? 262144 : 1310720);
  __shared__ float t[32][33];
  int tx = threadIdx.x & 31, ty = threadIdx.x >> 5;  // (32,8)
#pragma unroll
  for (int r = 0; r < 4; ++r)
    t[ty + 8 * r][tx] = W[(size_t)(k0 + ty + 8 * r) * D + c0 + tx];
  __syncthreads();
#pragma unroll
  for (int r = 0; r < 4; ++r)
    dstBase[(size_t)(m * D + c0 + ty + 8 * r) * K + k0 + tx] =
        __float2half(t[tx][ty + 8 * r]);
}

__global__ void bias_all_kernel(
    const float* __restrict__ b0, const float* __restrict__ b1,
    const float* __restrict__ b2, const float* __restrict__ b3,
    const float* __restrict__ b4, const float* __restrict__ b5,
    const float* __restrict__ b6, const float* __restrict__ b7,
    const float* __restrict__ b8, const float* __restrict__ b9,
    const float* __restrict__ b10, const float* __restrict__ b11,
    float* __restrict__ bias_arena) {
  int z = blockIdx.x;
  int layer = z >> 2, m = z & 3;
  int D = (layer == 2) ? 64 : 512;
  const float* b;
  switch (z) {
    case 0: b = b0; break; case 1: b = b1; break;
    case 2: b = b2; break; case 3: b = b3; break;
    case 4: b = b4; break; case 5: b = b5; break;
    case 6: b = b6; break; case 7: b = b7; break;
    case 8: b = b8; break; case 9: b = b9; break;
    case 10: b = b10; break; default: b = b11; break;
  }
  float* dst = bias_arena + ((layer == 0) ? 0 : (layer == 1) ? 2048 : 4096) + m * D;
  for (int c = threadIdx.x; c < D; c += 256) dst[c] = b[c];
}

// ---------------- MFMA GEMM: 128x256 block tile, 64x128 wave tile ----------------
// LDS rows = 64 halves (128B). Slot s (16B) of row r holds k-chunk s^(r&7).
// Epilogue: LDS-staged coalesced stores. Per block (layers 0/1) the 256-col
// range lies in ONE mseg: fp16 tiles (Q,S) staged [64][264] halves, stored as
// 16B rows; K/V staged as f32 [32][260], packed fp8 (from f32), stored 8B.
template <int LAYER>
__global__ __launch_bounds__(256, 3)
void gemm_mfma_kernel(const void* __restrict__ Avoid,
                      const __half* __restrict__ Wt,
                      const float* __restrict__ bias,
                      __half* __restrict__ QS, __half* __restrict__ KV,
                      int Nrows) {
  constexpr int K = (LAYER == 0) ? 128 : 512;
  constexpr int lda = (LAYER == 0) ? 128 : 512;
  constexpr int NT = (LAYER == 2) ? 1 : 8;  // 256-wide n-tiles
  __shared__ __align__(16) char smem_raw[49152];
  __half* As = (__half*)smem_raw;          // 128*64 halves = 16 KB
  __half* Bs = (__half*)smem_raw + 8192;   // 256*64 halves = 32 KB
  int tid = threadIdx.x;
  int wave = tid >> 6, lane = tid & 63;
  int wr = wave >> 1, wc = wave & 1;
  int bid = blockIdx.x;
  int xcd = bid & 7;
  int r = bid >> 3;
  int n0 = (r % NT) * 256;
  int m0 = ((r / NT) * 8 + xcd) * 128;
  // staging decomposition: lane -> (row-in-8, slot)
  int srow = lane >> 3;
  int sslot = lane & 7;
  int skc = (sslot ^ srow) << 3;  // swizzled k offset (halves)
  // fragment read decomposition
  int quad = lane >> 4, rr = lane & 15;

  f32x4 acc[4][8] = {};

  for (int kt = 0; kt < K; kt += 64) {
    // stage A: wave covers rows [wave*32, +32): 4 calls x 8 rows
#pragma unroll
    for (int p = 0; p < 4; ++p) {
      int rbase = wave * 32 + p * 8;
      if constexpr (LAYER == 0) {
        int row = m0 + rbase + srow;
        const float* ga = (const float*)Avoid + (size_t)row * lda + kt + skc;
        f16x8 hv = {};
        if (row < Nrows) {
          float4 f0 = *(const float4*)ga;
          float4 f1 = *(const float4*)(ga + 4);
          hv[0] = (_Float16)f0.x; hv[1] = (_Float16)f0.y;
          hv[2] = (_Float16)f0.z; hv[3] = (_Float16)f0.w;
          hv[4] = (_Float16)f1.x; hv[5] = (_Float16)f1.y;
          hv[6] = (_Float16)f1.z; hv[7] = (_Float16)f1.w;
        }
        *(f16x8*)&As[(rbase + srow) * 64 + sslot * 8] = hv;
      } else {
        const __half* ga = (const __half*)Avoid +
                           (size_t)(m0 + rbase + srow) * lda + kt + skc;
        load_lds16(ga, &As[rbase * 64]);
      }
    }
    // stage B: wave covers rows [wave*64, +64): 8 calls x 8 rows
#pragma unroll
    for (int p = 0; p < 8; ++p) {
      int rbase = wave * 64 + p * 8;
      const __half* gb = Wt + (size_t)(n0 + rbase + srow) * K + kt + skc;
      load_lds16(gb, &Bs[rbase * 64]);
    }
    __syncthreads();
#pragma unroll
    for (int h = 0; h < 2; ++h) {
      int c = h * 4 + quad;  // k-chunk 0..7
      f16x8 a[4], b[8];
#pragma unroll
      for (int i = 0; i < 4; ++i) {
        int row = wr * 64 + i * 16 + rr;
        a[i] = *(const f16x8*)&As[row * 64 + ((c ^ (row & 7)) << 3)];
      }
#pragma unroll
      for (int j = 0; j < 8; ++j) {
        int row = wc * 128 + j * 16 + rr;
        b[j] = *(const f16x8*)&Bs[row * 64 + ((c ^ (row & 7)) << 3)];
      }
#pragma unroll
      for (int i = 0; i < 4; ++i)
#pragma unroll
        for (int j = 0; j < 8; ++j)
          acc[i][j] = __builtin_amdgcn_mfma_f32_16x16x32_f16(a[i], b[j], acc[i][j], 0, 0, 0);
    }
    __syncthreads();
  }

  // ---- epilogue: LDS-staged coalesced stores ----
  // C/D frag layout: col = lane&15, row = (lane>>4)*4 + reg
  int cl = lane & 15, rb = (lane >> 4) * 4;

  if constexpr (LAYER == 2) {
    // all fp16; 2 rounds of 64 rows; per-chunk seg routing (4 segs x 64 cols)
    __half* S = (__half*)smem_raw;  // [64][264] halves
#pragma unroll
    for (int round = 0; round < 2; ++round) {
      if (wr == round) {
#pragma unroll
        for (int i = 0; i < 4; ++i)
#pragma unroll
          for (int j = 0; j < 8; ++j) {
            int colL = wc * 128 + j * 16 + cl;
            float bj = bias[colL];
#pragma unroll
            for (int rg = 0; rg < 4; ++rg) {
              int rowL = i * 16 + rb + rg;
              S[rowL * 264 + colL] = __float2half(acc[i][j][rg] + bj);
            }
          }
      }
      __syncthreads();
#pragma unroll
      for (int it = 0; it < 8; ++it) {
        int id = it * 256 + tid;
        int rowL = id >> 5, ch = id & 31;
        int grow = m0 + round * 64 + rowL;
        int colb = ch * 8;
        int seg = colb >> 6, c = colb & 63;
        __half* base = (seg == 0) ? QS + (size_t)grow * 128 + c
                     : (seg == 3) ? QS + (size_t)grow * 128 + 64 + c
                     : (seg == 1) ? KV + (size_t)grow * 128 + c
                                  : KV + (size_t)grow * 128 + 64 + c;
        *(f16x8*)base = *(const f16x8*)&S[rowL * 264 + colb];
      }
      __syncthreads();
    }
  } else {
    const int msegB = n0 >> 9;   // block-uniform mseg (0=Q,1=K,2=V,3=S)
    const int cb = n0 & 511;     // col base within the 512-wide matrix
    if (msegB == 0 || msegB == 3) {
      // fp16 path -> QS
      __half* S = (__half*)smem_raw;  // [64][264] halves
      const int coff = (msegB == 3) ? 512 : 0;
#pragma unroll
      for (int round = 0; round < 2; ++round) {
        if (wr == round) {
#pragma unroll
          for (int i = 0; i < 4; ++i)
#pragma unroll
            for (int j = 0; j < 8; ++j) {
              int colL = wc * 128 + j * 16 + cl;
              float bj = bias[n0 + colL];
#pragma unroll
              for (int rg = 0; rg < 4; ++rg) {
                int rowL = i * 16 + rb + rg;
                S[rowL * 264 + colL] = __float2half(acc[i][j][rg] + bj);
              }
            }
        }
        __syncthreads();
#pragma unroll
        for (int it = 0; it < 8; ++it) {
          int id = it * 256 + tid;
          int rowL = id >> 5, ch = id & 31;
          int grow = m0 + round * 64 + rowL;
          int colb = ch * 8;
          *(f16x8*)(QS + (size_t)grow * 1024 + coff + cb + colb) =
              *(const f16x8*)&S[rowL * 264 + colb];
        }
        __syncthreads();
      }
    } else {
      // fp8 path -> KV8 interleaved [K 8B | V 8B] per 8-col group
      float* S = (float*)smem_raw;  // [32][260] floats
      unsigned char* KV8 = (unsigned char*)KV;
      const int koff = (msegB == 2) ? 8 : 0;
#pragma unroll
      for (int round = 0; round < 4; ++round) {
        if (wr == (round >> 1)) {
          constexpr int dummy = 0; (void)dummy;
#pragma unroll
          for (int ii = 0; ii < 2; ++ii) {
#pragma unroll
            for (int j = 0; j < 8; ++j) {
              int colL = wc * 128 + j * 16 + cl;
              float bj = bias[n0 + colL];
#pragma unroll
              for (int rg = 0; rg < 4; ++rg) {
                int rowL = ii * 16 + rb + rg;
                // i index must be compile-time: round and ii are unrolled
                S[rowL * 260 + colL] = acc[(round & 1) * 2 + ii][j][rg] + bj;
              }
            }
          }
        }
        __syncthreads();
#pragma unroll
        for (int it = 0; it < 4; ++it) {
          int id = it * 256 + tid;
          int rowL = id >> 5, ch = id & 31;
          int grow = m0 + round * 32 + rowL;
          int colb = ch * 8;
          float f[8];
          f32x4 lo = *(const f32x4*)&S[rowL * 260 + colb];
          f32x4 hi = *(const f32x4*)&S[rowL * 260 + colb + 4];
          f[0] = lo[0]; f[1] = lo[1]; f[2] = lo[2]; f[3] = lo[3];
          f[4] = hi[0]; f[5] = hi[1]; f[6] = hi[2]; f[7] = hi[3];
          uint2 pk = fp8_pack8(f);
          *(uint2*)(KV8 + (size_t)grow * 1024 + ((cb + colb) >> 3) * 16 + koff) = pk;
        }
        __syncthreads();
      }
    }
  }
}

// ---------------- attention H=8 C=64: one WAVE per node, fp8 KV, 2-pair pipeline ----------------
__global__ __launch_bounds__(256)
void attn_h8_kernel(const __half* __restrict__ QS, const unsigned char* __restrict__ KV8,
                    const int* __restrict__ rowptr, const int* __restrict__ col,
                    __half* __restrict__ Hout, int N) {
  int n = blockIdx.x * 4 + (threadIdx.x >> 6);
  if (n >= N) return;
  int lane = threadIdx.x & 63;
  size_t rbase = (size_t)n * 1024 + lane * 8;

  f16x8 qv = __builtin_nontemporal_load((const f16x8*)(QS + rbase));
  float qf[8];
#pragma unroll
  for (int j = 0; j < 8; ++j) qf[j] = (float)qv[j];

  int e0 = rowptr[n], e1 = rowptr[n + 1];
  float m = -INFINITY, l = 0.f;
  float o[8] = {};

  const uint4* KVL = (const uint4*)KV8;  // one row = 64 uint4 (lane-interleaved K|V)
  uint4 ea = {}, eb = {};
  int i = e0;
  if (i < e1)     ea = KVL[(size_t)col[i] * 64 + lane];
  if (i + 1 < e1) eb = KVL[(size_t)col[i + 1] * 64 + lane];

  while (i < e1) {
    int rem = e1 - i;
    uint4 ec = {}, ed = {};
    if (rem > 2) ec = KVL[(size_t)col[i + 2] * 64 + lane];
    if (rem > 3) ed = KVL[(size_t)col[i + 3] * 64 + lane];
    float ka[8], kb[8];
    fp8x4_to_f32(ea.x, ka); fp8x4_to_f32(ea.y, ka + 4);
    fp8x4_to_f32(eb.x, kb); fp8x4_to_f32(eb.y, kb + 4);
    float pa = 0.f, pb = 0.f;
#pragma unroll
    for (int j = 0; j < 8; ++j) { pa += ka[j] * qf[j]; pb += kb[j] * qf[j]; }
    pa += __shfl_xor(pa, 1, 64); pb += __shfl_xor(pb, 1, 64);
    pa += __shfl_xor(pa, 2, 64); pb += __shfl_xor(pb, 2, 64);
    pa += __shfl_xor(pa, 4, 64); pb += __shfl_xor(pb, 4, 64);
    float a0 = pa * 0.125f;
    float va[8];
    fp8x4_to_f32(ea.z, va); fp8x4_to_f32(ea.w, va + 4);
    if (rem > 1) {
      float vb[8];
      fp8x4_to_f32(eb.z, vb); fp8x4_to_f32(eb.w, vb + 4);
      float a1 = pb * 0.125f;
      float mn = fmaxf(m, fmaxf(a0, a1));
      float sc = __expf(m - mn);
      float ex0 = __expf(a0 - mn), ex1 = __expf(a1 - mn);
      l = l * sc + ex0 + ex1;
#pragma unroll
      for (int c = 0; c < 8; ++c)
        o[c] = o[c] * sc + ex0 * va[c] + ex1 * vb[c];
      m = mn;
    } else {
      float mn = fmaxf(m, a0);
      float sc = __expf(m - mn);
      float ex0 = __expf(a0 - mn);
      l = l * sc + ex0;
#pragma unroll
      for (int c = 0; c < 8; ++c) o[c] = o[c] * sc + ex0 * va[c];
      m = mn;
    }
    ea = ec; eb = ed;
    i += 2;
  }

  float inv = 1.f / (l + 1e-16f);
  f16x8 sv = __builtin_nontemporal_load((const f16x8*)(QS + rbase + 512));
  f16x8 hv;
#pragma unroll
  for (int c = 0; c < 8; ++c) {
    float r = o[c] * inv + (float)sv[c];
    hv[c] = (_Float16)fmaxf(r, 0.f);
  }
  __builtin_nontemporal_store(hv, (f16x8*)(Hout + (size_t)n * 512 + lane * 8));
}

// ---------------- attention H=1 C=64: 8-lane group per node, fp16 KV ----------------
__global__ __launch_bounds__(256)
void attn_h1_kernel(const __half* __restrict__ QS, const __half* __restrict__ KV,
                    const int* __restrict__ rowptr, const int* __restrict__ col,
                    float* __restrict__ out, int N) {
  int n = (blockIdx.x * 256 + threadIdx.x) >> 3;
  if (n >= N) return;
  int gl = threadIdx.x & 7;
  size_t rbase = (size_t)n * 128 + gl * 8;

  f16x8 qv = __builtin_nontemporal_load((const f16x8*)(QS + rbase));
  float qf[8];
#pragma unroll
  for (int j = 0; j < 8; ++j) qf[j] = (float)qv[j];

  int e0 = rowptr[n], e1 = rowptr[n + 1];
  float m = -INFINITY, l = 0.f;
  float o[8] = {};

  f16x8 ka = {}, va = {}, kb = {}, vb = {};
  int i = e0;
  if (i < e1) {
    const __half* p = KV + (size_t)col[i] * 128 + gl * 8;
    ka = *(const f16x8*)p; va = *(const f16x8*)(p + 64);
  }
  if (i + 1 < e1) {
    const __half* p = KV + (size_t)col[i + 1] * 128 + gl * 8;
    kb = *(const f16x8*)p; vb = *(const f16x8*)(p + 64);
  }

  while (i < e1) {
    int rem = e1 - i;
    f16x8 kc = {}, vc = {}, kd = {}, vd = {};
    if (rem > 2) {
      const __half* p = KV + (size_t)col[i + 2] * 128 + gl * 8;
      kc = *(const f16x8*)p; vc = *(const f16x8*)(p + 64);
    }
    if (rem > 3) {
      const __half* p = KV + (size_t)col[i + 3] * 128 + gl * 8;
      kd = *(const f16x8*)p; vd = *(const f16x8*)(p + 64);
    }
    float pa = 0.f, pb = 0.f;
#pragma unroll
    for (int j = 0; j < 8; ++j) { pa += (float)ka[j] * qf[j]; pb += (float)kb[j] * qf[j]; }
    pa += __shfl_xor(pa, 1, 64); pb += __shfl_xor(pb, 1, 64);
    pa += __shfl_xor(pa, 2, 64); pb += __shfl_xor(pb, 2, 64);
    pa += __shfl_xor(pa, 4, 64); pb += __shfl_xor(pb, 4, 64);
    float a0 = pa * 0.125f;
    if (rem > 1) {
      float a1 = pb * 0.125f;
      float mn = fmaxf(m, fmaxf(a0, a1));
      float sc = __expf(m - mn);
      float ea = __expf(a0 - mn), eb = __expf(a1 - mn);
      l = l * sc + ea + eb;
#pragma unroll
      for (int c = 0; c < 8; ++c)
        o[c] = o[c] * sc + ea * (float)va[c] + eb * (float)vb[c];
      m = mn;
    } else {
      float mn = fmaxf(m, a0);
      float sc = __expf(m - mn);
      float ea = __expf(a0 - mn);
      l = l * sc + ea;
#pragma unroll
      for (int c = 0; c < 8; ++c) o[c] = o[c] * sc + ea * (float)va[c];
      m = mn;
    }
    ka = kc; va = vc; kb = kd; vb = vd;
    i += 2;
  }

  float inv = 1.f / (l + 1e-16f);
  f16x8 sv = __builtin_nontemporal_load((const f16x8*)(QS + rbase + 64));
  f32x4 r0, r1;
#pragma unroll
  for (int c = 0; c < 4; ++c) r0[c] = o[c] * inv + (float)sv[c];
#pragma unroll
  for (int c = 0; c < 4; ++c) r1[c] = o[c + 4] * inv + (float)sv[c + 4];
  float* op = out + (size_t)n * 64 + gl * 8;
  *(f32x4*)op = r0;
  *(f32x4*)(op + 4) = r1;
}

extern "C" void kernel_launch(void* const* d_in, const int* in_sizes, int n_in,
                              void* d_out, int out_size, void* d_ws, size_t ws_size,
                              hipStream_t stream) {
  const float* x = (const float*)d_in[0];
  const int* ei = (const int*)d_in[1];
  const int N = in_sizes[0] / 128;
  const int E = in_sizes[1] / 2;
  // pad M so mtiles is a multiple of 8 (XCD striping)
  const int Npad = ((N + 1023) / 1024) * 1024;
  const int mtiles = Npad / 128;
  const int* srcp = ei;
  const int* dstp = ei + E;

  const float* Wq0 = (const float*)d_in[2];  const float* bq0 = (const float*)d_in[3];
  const float* Wk0 = (const float*)d_in[4];  const float* bk0 = (const float*)d_in[5];
  const float* Wv0 = (const float*)d_in[6];  const float* bv0 = (const float*)d_in[7];
  const float* Ws0 = (const float*)d_in[8];  const float* bs0 = (const float*)d_in[9];
  const float* Wq1 = (const float*)d_in[10]; const float* bq1 = (const float*)d_in[11];
  const float* Wk1 = (const float*)d_in[12]; const float* bk1 = (const float*)d_in[13];
  const float* Wv1 = (const float*)d_in[14]; const float* bv1 = (const float*)d_in[15];
  const float* Ws1 = (const float*)d_in[16]; const float* bs1 = (const float*)d_in[17];
  const float* Wq2 = (const float*)d_in[18]; const float* bq2 = (const float*)d_in[19];
  const float* Wk2 = (const float*)d_in[20]; const float* bk2 = (const float*)d_in[21];
  const float* Wv2 = (const float*)d_in[22]; const float* bv2 = (const float*)d_in[23];
  const float* Ws2 = (const float*)d_in[24]; const float* bs2 = (const float*)d_in[25];

  // ---- workspace layout ----
  char* p = (char*)d_ws;
  __half* QS = (__half*)p;               p += (size_t)Npad * 1024 * 2;  // 102.8 MB
  __half* KV = (__half*)p;               p += (size_t)Npad * 1024;      // fp8 rows (1KB); layer2 reuses as fp16 (256B rows)
  __half* H  = (__half*)p;               p += (size_t)Npad * 512 * 2;   // 51.4 MB
  __half* Wt = (__half*)p;               p += (size_t)1441792 * 2;      // 2.88 MB
  float* bias_arena = (float*)p;         p += 4352 * 4;
  int* deg    = (int*)p;                 p += (size_t)N * 4;
  int* rowptr = (int*)p;                 p += (size_t)(N + 1) * 4;
  int* cursor = (int*)p;                 p += (size_t)(N + 1) * 4;
  int* colv   = (int*)p;                 p += (size_t)E * 4;
  int* bsum   = (int*)p;                 p += 256 * 4;
  size_t need = p - (char*)d_ws;
  if (ws_size < need) {
    fprintf(stderr, "kernel_launch: ws_size=%zu < need=%zu — aborting cleanly\n",
            ws_size, need);
    return;
  }

  const int nscan = (N + 255) / 256;

  // ---- prep ----
  transpose_all_kernel<<<dim3(16, 16, 12), 256, 0, stream>>>(
      Wq0, Wk0, Wv0, Ws0, Wq1, Wk1, Wv1, Ws1, Wq2, Wk2, Wv2, Ws2, Wt);
  bias_all_kernel<<<12, 256, 0, stream>>>(
      bq0, bk0, bv0, bs0, bq1, bk1, bv1, bs1, bq2, bk2, bv2, bs2, bias_arena);
  zero_misc_kernel<<<((Npad - N) * 512 / 8 + 255) / 256 > (N + 255) / 256
                         ? ((Npad - N) * 512 / 8 + 255) / 256
                         : (N + 255) / 256,
                    256, 0, stream>>>(deg, H, N, Npad);

  // ---- CSR build ----
  degree_kernel<<<(E + 255) / 256, 256, 0, stream>>>(dstp, deg, E);
  scan_a_kernel<<<nscan, 256, 0, stream>>>(deg, rowptr, bsum, N);
  scan_b_kernel<<<1, 256, 0, stream>>>(bsum, nscan);
  scan_c_kernel<<<nscan, 256, 0, stream>>>(rowptr, cursor, bsum, N);
  scatter_kernel<<<(E + 255) / 256, 256, 0, stream>>>(srcp, dstp, cursor, colv, E);

  __half* Wt0 = Wt;
  __half* Wt1 = Wt + 262144;
  __half* Wt2 = Wt + 1310720;

  // ---- layer 0: K=128, D=512, n-tiles 8 ----
  gemm_mfma_kernel<0><<<mtiles * 8, 256, 0, stream>>>(
      x, Wt0, bias_arena, QS, KV, N);
  attn_h8_kernel<<<(N + 3) / 4, 256, 0, stream>>>(QS, (const unsigned char*)KV,
                                                  rowptr, colv, H, N);

  // ---- layer 1: K=512, D=512, n-tiles 8 ----
  gemm_mfma_kernel<1><<<mtiles * 8, 256, 0, stream>>>(
      H, Wt1, bias_arena + 2048, QS, KV, Npad);
  attn_h8_kernel<<<(N + 3) / 4, 256, 0, stream>>>(QS, (const unsigned char*)KV,
                                                  rowptr, colv, H, N);

  // ---- layer 2: K=512, D=64, n-tiles 1 ----
  gemm_mfma_kernel<2><<<mtiles, 256, 0, stream>>>(
      H, Wt2, bias_arena + 4096, QS, KV, Npad);
  attn_h1_kernel<<<(N + 31) / 32, 256, 0, stream>>>(QS, KV, rowptr, colv,
                                                    (float*)d_out, N);
}

// Round 5
// 747.803 us; speedup vs baseline: 1.7553x; 1.7553x over previous
//
#include <hip/hip_runtime.h>
#include <hip/hip_fp16.h>
#include <math.h>
#include <stdio.h>

// N=50000, E=800000, IN=128, C=64, H=8, H*C=512
// R4: revert launch_bounds(256,3) -> (256,2). R3 evidence: VGPR 108->84 +
// hbm_bytes 1.9GB/dispatch (WRITE 1.2GB) + MfmaUtil 8% = acc[4][8] spilled
// to scratch under the 3-wave/SIMD VGPR cap (~170 < ~200 needed). Keep the
// R3 LDS-staged coalesced epilogue (validated: absmax unchanged 0.0088).
// attn: fp8 KV from R2 (attn_h8 ~<150us each).

using f16x8 = __attribute__((ext_vector_type(8))) _Float16;
using f32x4 = __attribute__((ext_vector_type(4))) float;

__device__ __forceinline__ void load_lds16(const void* g, void* l) {
  __builtin_amdgcn_global_load_lds((const __attribute__((address_space(1))) void*)g,
                                   (__attribute__((address_space(3))) void*)l,
                                   16, 0, 0);
}

// ---- fp8 e4m3 helpers (HW cvt on gfx950; software fallback kept for safety) ----
__device__ __forceinline__ void fp8x4_to_f32(unsigned int w, float* o4) {
#if __has_builtin(__builtin_amdgcn_cvt_pk_f32_fp8)
  auto lo = __builtin_amdgcn_cvt_pk_f32_fp8(w, false);
  auto hi = __builtin_amdgcn_cvt_pk_f32_fp8(w, true);
  o4[0] = lo[0]; o4[1] = lo[1]; o4[2] = hi[0]; o4[3] = hi[1];
#else
#pragma unroll
  for (int t = 0; t < 4; ++t) {
    unsigned int b = (w >> (8 * t)) & 0xFFu;
    unsigned short h = (unsigned short)(((b & 0x80u) << 8) | ((b & 0x7Fu) << 7));
    __half hv = *(__half*)&h;
    o4[t] = (float)hv * 256.0f;
  }
#endif
}

__device__ __forceinline__ unsigned int fp8_pack2_sw(float a, float b) {
  unsigned int r = 0;
#pragma unroll
  for (int t = 0; t < 2; ++t) {
    float f = t ? b : a;
    __half h = __float2half(f * (1.0f / 256.0f));
    unsigned short hb = *(unsigned short*)&h;
    unsigned int sign = (hb >> 8) & 0x80u;
    unsigned int mag = (hb & 0x7FFFu) + 0x40u;  // round
    unsigned int e = (mag >> 7) & 0x7Fu;
    if ((mag >> 7) > 0x7Eu) e = 0x7Eu;          // clamp below NaN pattern
    r |= (sign | e) << (8 * t);
  }
  return r;
}

__device__ __forceinline__ uint2 fp8_pack8(const float* f) {
#if __has_builtin(__builtin_amdgcn_cvt_pk_fp8_f32)
  int w0 = __builtin_amdgcn_cvt_pk_fp8_f32(f[0], f[1], 0, false);
  w0 = __builtin_amdgcn_cvt_pk_fp8_f32(f[2], f[3], w0, true);
  int w1 = __builtin_amdgcn_cvt_pk_fp8_f32(f[4], f[5], 0, false);
  w1 = __builtin_amdgcn_cvt_pk_fp8_f32(f[6], f[7], w1, true);
  uint2 r; r.x = (unsigned)w0; r.y = (unsigned)w1; return r;
#else
  uint2 r;
  r.x = fp8_pack2_sw(f[0], f[1]) | (fp8_pack2_sw(f[2], f[3]) << 16);
  r.y = fp8_pack2_sw(f[4], f[5]) | (fp8_pack2_sw(f[6], f[7]) << 16);
  return r;
#endif
}

// ---------------- CSR build ----------------
__global__ void zero_misc_kernel(int* __restrict__ deg, __half* __restrict__ H,
                                 int N, int Npad) {
  int t = blockIdx.x * 256 + threadIdx.x;
  if (t < N) deg[t] = 0;
  int nz = (Npad - N) * 512 / 8;
  if (t < nz) {
    f16x8 z = {};
    *(f16x8*)(H + (size_t)N * 512 + (size_t)t * 8) = z;
  }
}

__global__ void degree_kernel(const int* __restrict__ dst, int* __restrict__ deg, int E) {
  int e = blockIdx.x * blockDim.x + threadIdx.x;
  if (e < E) atomicAdd(&deg[dst[e]], 1);
}

__global__ __launch_bounds__(256)
void scan_a_kernel(const int* __restrict__ deg, int* __restrict__ rowptr,
                   int* __restrict__ bsum, int n) {
  __shared__ int tmp[256];
  int t = threadIdx.x;
  int i = blockIdx.x * 256 + t;
  int v = (i < n) ? deg[i] : 0;
  tmp[t] = v;
  __syncthreads();
#pragma unroll
  for (int off = 1; off < 256; off <<= 1) {
    int u = (t >= off) ? tmp[t - off] : 0;
    __syncthreads();
    tmp[t] += u;
    __syncthreads();
  }
  if (i < n) rowptr[i + 1] = tmp[t];
  if (t == 255) bsum[blockIdx.x] = tmp[255];
}

__global__ __launch_bounds__(256)
void scan_b_kernel(int* __restrict__ bsum, int nb) {
  __shared__ int tmp[256];
  int t = threadIdx.x;
  int v = (t < nb) ? bsum[t] : 0;
  tmp[t] = v;
  __syncthreads();
#pragma unroll
  for (int off = 1; off < 256; off <<= 1) {
    int u = (t >= off) ? tmp[t - off] : 0;
    __syncthreads();
    tmp[t] += u;
    __syncthreads();
  }
  if (t < nb) bsum[t] = tmp[t] - v;  // exclusive
}

__global__ __launch_bounds__(256)
void scan_c_kernel(int* __restrict__ rowptr, int* __restrict__ cursor,
                   const int* __restrict__ bsum, int n) {
  int i = blockIdx.x * 256 + threadIdx.x;
  if (i < n) {
    int r = rowptr[i + 1] + bsum[blockIdx.x];
    rowptr[i + 1] = r;
    cursor[i + 1] = r;
  }
  if (i == 0) { rowptr[0] = 0; cursor[0] = 0; }
}

__global__ void scatter_kernel(const int* __restrict__ src, const int* __restrict__ dst,
                               int* __restrict__ cursor, int* __restrict__ col, int E) {
  int e = blockIdx.x * blockDim.x + threadIdx.x;
  if (e < E) {
    int pos = atomicAdd(&cursor[dst[e]], 1);
    col[pos] = src[e];
  }
}

// ---------------- prep: weights/biases ----------------
__global__ __launch_bounds__(256)
void transpose_all_kernel(
    const float* __restrict__ Wq0, const float* __restrict__ Wk0,
    const float* __restrict__ Wv0, const float* __restrict__ Ws0,
    const float* __restrict__ Wq1, const float* __restrict__ Wk1,
    const float* __restrict__ Wv1, const float* __restrict__ Ws1,
    const float* __restrict__ Wq2, const float* __restrict__ Wk2,
    const float* __restrict__ Wv2, const float* __restrict__ Ws2,
    __half* __restrict__ Wt) {
  int z = blockIdx.z;
  int layer = z >> 2, m = z & 3;
  int K = (layer == 0) ? 128 : 512;
  int D = (layer == 2) ? 64 : 512;
  int c0 = blockIdx.x * 32, k0 = blockIdx.y * 32;
  if (c0 >= D || k0 >= K) return;
  const float* W;
  switch (z) {
    case 0: W = Wq0; break; case 1: W = Wk0; break;
    case 2: W = Wv0; break; case 3: W = Ws0; break;
    case 4: W = Wq1; break; case 5: W = Wk1; break;
    case 6: W = Wv1; break; case 7: W = Ws1; break;
    case 8: W = Wq2; break; case 9: W = Wk2; break;
    case 10: W = Wv2; break; default: W = Ws2; break;
  }
  __half* dstBase = Wt + ((layer == 0) ? 0 : (layer == 1) ? 262144 : 1310720);
  __shared__ float t[32][33];
  int tx = threadIdx.x & 31, ty = threadIdx.x >> 5;  // (32,8)
#pragma unroll
  for (int r = 0; r < 4; ++r)
    t[ty + 8 * r][tx] = W[(size_t)(k0 + ty + 8 * r) * D + c0 + tx];
  __syncthreads();
#pragma unroll
  for (int r = 0; r < 4; ++r)
    dstBase[(size_t)(m * D + c0 + ty + 8 * r) * K + k0 + tx] =
        __float2half(t[tx][ty + 8 * r]);
}

__global__ void bias_all_kernel(
    const float* __restrict__ b0, const float* __restrict__ b1,
    const float* __restrict__ b2, const float* __restrict__ b3,
    const float* __restrict__ b4, const float* __restrict__ b5,
    const float* __restrict__ b6, const float* __restrict__ b7,
    const float* __restrict__ b8, const float* __restrict__ b9,
    const float* __restrict__ b10, const float* __restrict__ b11,
    float* __restrict__ bias_arena) {
  int z = blockIdx.x;
  int layer = z >> 2, m = z & 3;
  int D = (layer == 2) ? 64 : 512;
  const float* b;
  switch (z) {
    case 0: b = b0; break; case 1: b = b1; break;
    case 2: b = b2; break; case 3: b = b3; break;
    case 4: b = b4; break; case 5: b = b5; break;
    case 6: b = b6; break; case 7: b = b7; break;
    case 8: b = b8; break; case 9: b = b9; break;
    case 10: b = b10; break; default: b = b11; break;
  }
  float* dst = bias_arena + ((layer == 0) ? 0 : (layer == 1) ? 2048 : 4096) + m * D;
  for (int c = threadIdx.x; c < D; c += 256) dst[c] = b[c];
}

// ---------------- MFMA GEMM: 128x256 block tile, 64x128 wave tile ----------------
// LDS rows = 64 halves (128B). Slot s (16B) of row r holds k-chunk s^(r&7).
// Epilogue: LDS-staged coalesced stores (R3, validated). launch_bounds(256,2)
// — do NOT raise: 3 waves/SIMD caps VGPR ~170 and spills acc[4][8] (R3 bug).
template <int LAYER>
__global__ __launch_bounds__(256, 2)
void gemm_mfma_kernel(const void* __restrict__ Avoid,
                      const __half* __restrict__ Wt,
                      const float* __restrict__ bias,
                      __half* __restrict__ QS, __half* __restrict__ KV,
                      int Nrows) {
  constexpr int K = (LAYER == 0) ? 128 : 512;
  constexpr int lda = (LAYER == 0) ? 128 : 512;
  constexpr int NT = (LAYER == 2) ? 1 : 8;  // 256-wide n-tiles
  __shared__ __align__(16) char smem_raw[49152];
  __half* As = (__half*)smem_raw;          // 128*64 halves = 16 KB
  __half* Bs = (__half*)smem_raw + 8192;   // 256*64 halves = 32 KB
  int tid = threadIdx.x;
  int wave = tid >> 6, lane = tid & 63;
  int wr = wave >> 1, wc = wave & 1;
  int bid = blockIdx.x;
  int xcd = bid & 7;
  int r = bid >> 3;
  int n0 = (r % NT) * 256;
  int m0 = ((r / NT) * 8 + xcd) * 128;
  // staging decomposition: lane -> (row-in-8, slot)
  int srow = lane >> 3;
  int sslot = lane & 7;
  int skc = (sslot ^ srow) << 3;  // swizzled k offset (halves)
  // fragment read decomposition
  int quad = lane >> 4, rr = lane & 15;

  f32x4 acc[4][8] = {};

  for (int kt = 0; kt < K; kt += 64) {
    // stage A: wave covers rows [wave*32, +32): 4 calls x 8 rows
#pragma unroll
    for (int p = 0; p < 4; ++p) {
      int rbase = wave * 32 + p * 8;
      if constexpr (LAYER == 0) {
        int row = m0 + rbase + srow;
        const float* ga = (const float*)Avoid + (size_t)row * lda + kt + skc;
        f16x8 hv = {};
        if (row < Nrows) {
          float4 f0 = *(const float4*)ga;
          float4 f1 = *(const float4*)(ga + 4);
          hv[0] = (_Float16)f0.x; hv[1] = (_Float16)f0.y;
          hv[2] = (_Float16)f0.z; hv[3] = (_Float16)f0.w;
          hv[4] = (_Float16)f1.x; hv[5] = (_Float16)f1.y;
          hv[6] = (_Float16)f1.z; hv[7] = (_Float16)f1.w;
        }
        *(f16x8*)&As[(rbase + srow) * 64 + sslot * 8] = hv;
      } else {
        const __half* ga = (const __half*)Avoid +
                           (size_t)(m0 + rbase + srow) * lda + kt + skc;
        load_lds16(ga, &As[rbase * 64]);
      }
    }
    // stage B: wave covers rows [wave*64, +64): 8 calls x 8 rows
#pragma unroll
    for (int p = 0; p < 8; ++p) {
      int rbase = wave * 64 + p * 8;
      const __half* gb = Wt + (size_t)(n0 + rbase + srow) * K + kt + skc;
      load_lds16(gb, &Bs[rbase * 64]);
    }
    __syncthreads();
#pragma unroll
    for (int h = 0; h < 2; ++h) {
      int c = h * 4 + quad;  // k-chunk 0..7
      f16x8 a[4], b[8];
#pragma unroll
      for (int i = 0; i < 4; ++i) {
        int row = wr * 64 + i * 16 + rr;
        a[i] = *(const f16x8*)&As[row * 64 + ((c ^ (row & 7)) << 3)];
      }
#pragma unroll
      for (int j = 0; j < 8; ++j) {
        int row = wc * 128 + j * 16 + rr;
        b[j] = *(const f16x8*)&Bs[row * 64 + ((c ^ (row & 7)) << 3)];
      }
#pragma unroll
      for (int i = 0; i < 4; ++i)
#pragma unroll
        for (int j = 0; j < 8; ++j)
          acc[i][j] = __builtin_amdgcn_mfma_f32_16x16x32_f16(a[i], b[j], acc[i][j], 0, 0, 0);
    }
    __syncthreads();
  }

  // ---- epilogue: LDS-staged coalesced stores ----
  // C/D frag layout: col = lane&15, row = (lane>>4)*4 + reg
  int cl = lane & 15, rb = (lane >> 4) * 4;

  if constexpr (LAYER == 2) {
    // all fp16; 2 rounds of 64 rows; per-chunk seg routing (4 segs x 64 cols)
    __half* S = (__half*)smem_raw;  // [64][264] halves
#pragma unroll
    for (int round = 0; round < 2; ++round) {
      if (wr == round) {
#pragma unroll
        for (int i = 0; i < 4; ++i)
#pragma unroll
          for (int j = 0; j < 8; ++j) {
            int colL = wc * 128 + j * 16 + cl;
            float bj = bias[colL];
#pragma unroll
            for (int rg = 0; rg < 4; ++rg) {
              int rowL = i * 16 + rb + rg;
              S[rowL * 264 + colL] = __float2half(acc[i][j][rg] + bj);
            }
          }
      }
      __syncthreads();
#pragma unroll
      for (int it = 0; it < 8; ++it) {
        int id = it * 256 + tid;
        int rowL = id >> 5, ch = id & 31;
        int grow = m0 + round * 64 + rowL;
        int colb = ch * 8;
        int seg = colb >> 6, c = colb & 63;
        __half* base = (seg == 0) ? QS + (size_t)grow * 128 + c
                     : (seg == 3) ? QS + (size_t)grow * 128 + 64 + c
                     : (seg == 1) ? KV + (size_t)grow * 128 + c
                                  : KV + (size_t)grow * 128 + 64 + c;
        *(f16x8*)base = *(const f16x8*)&S[rowL * 264 + colb];
      }
      __syncthreads();
    }
  } else {
    const int msegB = n0 >> 9;   // block-uniform mseg (0=Q,1=K,2=V,3=S)
    const int cb = n0 & 511;     // col base within the 512-wide matrix
    if (msegB == 0 || msegB == 3) {
      // fp16 path -> QS
      __half* S = (__half*)smem_raw;  // [64][264] halves
      const int coff = (msegB == 3) ? 512 : 0;
#pragma unroll
      for (int round = 0; round < 2; ++round) {
        if (wr == round) {
#pragma unroll
          for (int i = 0; i < 4; ++i)
#pragma unroll
            for (int j = 0; j < 8; ++j) {
              int colL = wc * 128 + j * 16 + cl;
              float bj = bias[n0 + colL];
#pragma unroll
              for (int rg = 0; rg < 4; ++rg) {
                int rowL = i * 16 + rb + rg;
                S[rowL * 264 + colL] = __float2half(acc[i][j][rg] + bj);
              }
            }
        }
        __syncthreads();
#pragma unroll
        for (int it = 0; it < 8; ++it) {
          int id = it * 256 + tid;
          int rowL = id >> 5, ch = id & 31;
          int grow = m0 + round * 64 + rowL;
          int colb = ch * 8;
          *(f16x8*)(QS + (size_t)grow * 1024 + coff + cb + colb) =
              *(const f16x8*)&S[rowL * 264 + colb];
        }
        __syncthreads();
      }
    } else {
      // fp8 path -> KV8 interleaved [K 8B | V 8B] per 8-col group
      float* S = (float*)smem_raw;  // [32][260] floats
      unsigned char* KV8 = (unsigned char*)KV;
      const int koff = (msegB == 2) ? 8 : 0;
#pragma unroll
      for (int round = 0; round < 4; ++round) {
        if (wr == (round >> 1)) {
#pragma unroll
          for (int ii = 0; ii < 2; ++ii) {
#pragma unroll
            for (int j = 0; j < 8; ++j) {
              int colL = wc * 128 + j * 16 + cl;
              float bj = bias[n0 + colL];
#pragma unroll
              for (int rg = 0; rg < 4; ++rg) {
                int rowL = ii * 16 + rb + rg;
                S[rowL * 260 + colL] = acc[(round & 1) * 2 + ii][j][rg] + bj;
              }
            }
          }
        }
        __syncthreads();
#pragma unroll
        for (int it = 0; it < 4; ++it) {
          int id = it * 256 + tid;
          int rowL = id >> 5, ch = id & 31;
          int grow = m0 + round * 32 + rowL;
          int colb = ch * 8;
          float f[8];
          f32x4 lo = *(const f32x4*)&S[rowL * 260 + colb];
          f32x4 hi = *(const f32x4*)&S[rowL * 260 + colb + 4];
          f[0] = lo[0]; f[1] = lo[1]; f[2] = lo[2]; f[3] = lo[3];
          f[4] = hi[0]; f[5] = hi[1]; f[6] = hi[2]; f[7] = hi[3];
          uint2 pk = fp8_pack8(f);
          *(uint2*)(KV8 + (size_t)grow * 1024 + ((cb + colb) >> 3) * 16 + koff) = pk;
        }
        __syncthreads();
      }
    }
  }
}

// ---------------- attention H=8 C=64: one WAVE per node, fp8 KV, 2-pair pipeline ----------------
__global__ __launch_bounds__(256)
void attn_h8_kernel(const __half* __restrict__ QS, const unsigned char* __restrict__ KV8,
                    const int* __restrict__ rowptr, const int* __restrict__ col,
                    __half* __restrict__ Hout, int N) {
  int n = blockIdx.x * 4 + (threadIdx.x >> 6);
  if (n >= N) return;
  int lane = threadIdx.x & 63;
  size_t rbase = (size_t)n * 1024 + lane * 8;

  f16x8 qv = __builtin_nontemporal_load((const f16x8*)(QS + rbase));
  float qf[8];
#pragma unroll
  for (int j = 0; j < 8; ++j) qf[j] = (float)qv[j];

  int e0 = rowptr[n], e1 = rowptr[n + 1];
  float m = -INFINITY, l = 0.f;
  float o[8] = {};

  const uint4* KVL = (const uint4*)KV8;  // one row = 64 uint4 (lane-interleaved K|V)
  uint4 ea = {}, eb = {};
  int i = e0;
  if (i < e1)     ea = KVL[(size_t)col[i] * 64 + lane];
  if (i + 1 < e1) eb = KVL[(size_t)col[i + 1] * 64 + lane];

  while (i < e1) {
    int rem = e1 - i;
    uint4 ec = {}, ed = {};
    if (rem > 2) ec = KVL[(size_t)col[i + 2] * 64 + lane];
    if (rem > 3) ed = KVL[(size_t)col[i + 3] * 64 + lane];
    float ka[8], kb[8];
    fp8x4_to_f32(ea.x, ka); fp8x4_to_f32(ea.y, ka + 4);
    fp8x4_to_f32(eb.x, kb); fp8x4_to_f32(eb.y, kb + 4);
    float pa = 0.f, pb = 0.f;
#pragma unroll
    for (int j = 0; j < 8; ++j) { pa += ka[j] * qf[j]; pb += kb[j] * qf[j]; }
    pa += __shfl_xor(pa, 1, 64); pb += __shfl_xor(pb, 1, 64);
    pa += __shfl_xor(pa, 2, 64); pb += __shfl_xor(pb, 2, 64);
    pa += __shfl_xor(pa, 4, 64); pb += __shfl_xor(pb, 4, 64);
    float a0 = pa * 0.125f;
    float va[8];
    fp8x4_to_f32(ea.z, va); fp8x4_to_f32(ea.w, va + 4);
    if (rem > 1) {
      float vb[8];
      fp8x4_to_f32(eb.z, vb); fp8x4_to_f32(eb.w, vb + 4);
      float a1 = pb * 0.125f;
      float mn = fmaxf(m, fmaxf(a0, a1));
      float sc = __expf(m - mn);
      float ex0 = __expf(a0 - mn), ex1 = __expf(a1 - mn);
      l = l * sc + ex0 + ex1;
#pragma unroll
      for (int c = 0; c < 8; ++c)
        o[c] = o[c] * sc + ex0 * va[c] + ex1 * vb[c];
      m = mn;
    } else {
      float mn = fmaxf(m, a0);
      float sc = __expf(m - mn);
      float ex0 = __expf(a0 - mn);
      l = l * sc + ex0;
#pragma unroll
      for (int c = 0; c < 8; ++c) o[c] = o[c] * sc + ex0 * va[c];
      m = mn;
    }
    ea = ec; eb = ed;
    i += 2;
  }

  float inv = 1.f / (l + 1e-16f);
  f16x8 sv = __builtin_nontemporal_load((const f16x8*)(QS + rbase + 512));
  f16x8 hv;
#pragma unroll
  for (int c = 0; c < 8; ++c) {
    float r = o[c] * inv + (float)sv[c];
    hv[c] = (_Float16)fmaxf(r, 0.f);
  }
  __builtin_nontemporal_store(hv, (f16x8*)(Hout + (size_t)n * 512 + lane * 8));
}

// ---------------- attention H=1 C=64: 8-lane group per node, fp16 KV ----------------
__global__ __launch_bounds__(256)
void attn_h1_kernel(const __half* __restrict__ QS, const __half* __restrict__ KV,
                    const int* __restrict__ rowptr, const int* __restrict__ col,
                    float* __restrict__ out, int N) {
  int n = (blockIdx.x * 256 + threadIdx.x) >> 3;
  if (n >= N) return;
  int gl = threadIdx.x & 7;
  size_t rbase = (size_t)n * 128 + gl * 8;

  f16x8 qv = __builtin_nontemporal_load((const f16x8*)(QS + rbase));
  float qf[8];
#pragma unroll
  for (int j = 0; j < 8; ++j) qf[j] = (float)qv[j];

  int e0 = rowptr[n], e1 = rowptr[n + 1];
  float m = -INFINITY, l = 0.f;
  float o[8] = {};

  f16x8 ka = {}, va = {}, kb = {}, vb = {};
  int i = e0;
  if (i < e1) {
    const __half* p = KV + (size_t)col[i] * 128 + gl * 8;
    ka = *(const f16x8*)p; va = *(const f16x8*)(p + 64);
  }
  if (i + 1 < e1) {
    const __half* p = KV + (size_t)col[i + 1] * 128 + gl * 8;
    kb = *(const f16x8*)p; vb = *(const f16x8*)(p + 64);
  }

  while (i < e1) {
    int rem = e1 - i;
    f16x8 kc = {}, vc = {}, kd = {}, vd = {};
    if (rem > 2) {
      const __half* p = KV + (size_t)col[i + 2] * 128 + gl * 8;
      kc = *(const f16x8*)p; vc = *(const f16x8*)(p + 64);
    }
    if (rem > 3) {
      const __half* p = KV + (size_t)col[i + 3] * 128 + gl * 8;
      kd = *(const f16x8*)p; vd = *(const f16x8*)(p + 64);
    }
    float pa = 0.f, pb = 0.f;
#pragma unroll
    for (int j = 0; j < 8; ++j) { pa += (float)ka[j] * qf[j]; pb += (float)kb[j] * qf[j]; }
    pa += __shfl_xor(pa, 1, 64); pb += __shfl_xor(pb, 1, 64);
    pa += __shfl_xor(pa, 2, 64); pb += __shfl_xor(pb, 2, 64);
    pa += __shfl_xor(pa, 4, 64); pb += __shfl_xor(pb, 4, 64);
    float a0 = pa * 0.125f;
    if (rem > 1) {
      float a1 = pb * 0.125f;
      float mn = fmaxf(m, fmaxf(a0, a1));
      float sc = __expf(m - mn);
      float ea = __expf(a0 - mn), eb = __expf(a1 - mn);
      l = l * sc + ea + eb;
#pragma unroll
      for (int c = 0; c < 8; ++c)
        o[c] = o[c] * sc + ea * (float)va[c] + eb * (float)vb[c];
      m = mn;
    } else {
      float mn = fmaxf(m, a0);
      float sc = __expf(m - mn);
      float ea = __expf(a0 - mn);
      l = l * sc + ea;
#pragma unroll
      for (int c = 0; c < 8; ++c) o[c] = o[c] * sc + ea * (float)va[c];
      m = mn;
    }
    ka = kc; va = vc; kb = kd; vb = vd;
    i += 2;
  }

  float inv = 1.f / (l + 1e-16f);
  f16x8 sv = __builtin_nontemporal_load((const f16x8*)(QS + rbase + 64));
  f32x4 r0, r1;
#pragma unroll
  for (int c = 0; c < 4; ++c) r0[c] = o[c] * inv + (float)sv[c];
#pragma unroll
  for (int c = 0; c < 4; ++c) r1[c] = o[c + 4] * inv + (float)sv[c + 4];
  float* op = out + (size_t)n * 64 + gl * 8;
  *(f32x4*)op = r0;
  *(f32x4*)(op + 4) = r1;
}

extern "C" void kernel_launch(void* const* d_in, const int* in_sizes, int n_in,
                              void* d_out, int out_size, void* d_ws, size_t ws_size,
                              hipStream_t stream) {
  const float* x = (const float*)d_in[0];
  const int* ei = (const int*)d_in[1];
  const int N = in_sizes[0] / 128;
  const int E = in_sizes[1] / 2;
  // pad M so mtiles is a multiple of 8 (XCD striping)
  const int Npad = ((N + 1023) / 1024) * 1024;
  const int mtiles = Npad / 128;
  const int* srcp = ei;
  const int* dstp = ei + E;

  const float* Wq0 = (const float*)d_in[2];  const float* bq0 = (const float*)d_in[3];
  const float* Wk0 = (const float*)d_in[4];  const float* bk0 = (const float*)d_in[5];
  const float* Wv0 = (const float*)d_in[6];  const float* bv0 = (const float*)d_in[7];
  const float* Ws0 = (const float*)d_in[8];  const float* bs0 = (const float*)d_in[9];
  const float* Wq1 = (const float*)d_in[10]; const float* bq1 = (const float*)d_in[11];
  const float* Wk1 = (const float*)d_in[12]; const float* bk1 = (const float*)d_in[13];
  const float* Wv1 = (const float*)d_in[14]; const float* bv1 = (const float*)d_in[15];
  const float* Ws1 = (const float*)d_in[16]; const float* bs1 = (const float*)d_in[17];
  const float* Wq2 = (const float*)d_in[18]; const float* bq2 = (const float*)d_in[19];
  const float* Wk2 = (const float*)d_in[20]; const float* bk2 = (const float*)d_in[21];
  const float* Wv2 = (const float*)d_in[22]; const float* bv2 = (const float*)d_in[23];
  const float* Ws2 = (const float*)d_in[24]; const float* bs2 = (const float*)d_in[25];

  // ---- workspace layout ----
  char* p = (char*)d_ws;
  __half* QS = (__half*)p;               p += (size_t)Npad * 1024 * 2;  // 102.8 MB
  __half* KV = (__half*)p;               p += (size_t)Npad * 1024;      // fp8 rows (1KB); layer2 reuses as fp16 (256B rows)
  __half* H  = (__half*)p;               p += (size_t)Npad * 512 * 2;   // 51.4 MB
  __half* Wt = (__half*)p;               p += (size_t)1441792 * 2;      // 2.88 MB
  float* bias_arena = (float*)p;         p += 4352 * 4;
  int* deg    = (int*)p;                 p += (size_t)N * 4;
  int* rowptr = (int*)p;                 p += (size_t)(N + 1) * 4;
  int* cursor = (int*)p;                 p += (size_t)(N + 1) * 4;
  int* colv   = (int*)p;                 p += (size_t)E * 4;
  int* bsum   = (int*)p;                 p += 256 * 4;
  size_t need = p - (char*)d_ws;
  if (ws_size < need) {
    fprintf(stderr, "kernel_launch: ws_size=%zu < need=%zu — aborting cleanly\n",
            ws_size, need);
    return;
  }

  const int nscan = (N + 255) / 256;

  // ---- prep ----
  transpose_all_kernel<<<dim3(16, 16, 12), 256, 0, stream>>>(
      Wq0, Wk0, Wv0, Ws0, Wq1, Wk1, Wv1, Ws1, Wq2, Wk2, Wv2, Ws2, Wt);
  bias_all_kernel<<<12, 256, 0, stream>>>(
      bq0, bk0, bv0, bs0, bq1, bk1, bv1, bs1, bq2, bk2, bv2, bs2, bias_arena);
  zero_misc_kernel<<<((Npad - N) * 512 / 8 + 255) / 256 > (N + 255) / 256
                         ? ((Npad - N) * 512 / 8 + 255) / 256
                         : (N + 255) / 256,
                    256, 0, stream>>>(deg, H, N, Npad);

  // ---- CSR build ----
  degree_kernel<<<(E + 255) / 256, 256, 0, stream>>>(dstp, deg, E);
  scan_a_kernel<<<nscan, 256, 0, stream>>>(deg, rowptr, bsum, N);
  scan_b_kernel<<<1, 256, 0, stream>>>(bsum, nscan);
  scan_c_kernel<<<nscan, 256, 0, stream>>>(rowptr, cursor, bsum, N);
  scatter_kernel<<<(E + 255) / 256, 256, 0, stream>>>(srcp, dstp, cursor, colv, E);

  __half* Wt0 = Wt;
  __half* Wt1 = Wt + 262144;
  __half* Wt2 = Wt + 1310720;

  // ---- layer 0: K=128, D=512, n-tiles 8 ----
  gemm_mfma_kernel<0><<<mtiles * 8, 256, 0, stream>>>(
      x, Wt0, bias_arena, QS, KV, N);
  attn_h8_kernel<<<(N + 3) / 4, 256, 0, stream>>>(QS, (const unsigned char*)KV,
                                                  rowptr, colv, H, N);

  // ---- layer 1: K=512, D=512, n-tiles 8 ----
  gemm_mfma_kernel<1><<<mtiles * 8, 256, 0, stream>>>(
      H, Wt1, bias_arena + 2048, QS, KV, Npad);
  attn_h8_kernel<<<(N + 3) / 4, 256, 0, stream>>>(QS, (const unsigned char*)KV,
                                                  rowptr, colv, H, N);

  // ---- layer 2: K=512, D=64, n-tiles 1 ----
  gemm_mfma_kernel<2><<<mtiles, 256, 0, stream>>>(
      H, Wt2, bias_arena + 4096, QS, KV, Npad);
  attn_h1_kernel<<<(N + 31) / 32, 256, 0, stream>>>(QS, KV, rowptr, colv,
                                                    (float*)d_out, N);
}

// Round 6
// 747.092 us; speedup vs baseline: 1.7570x; 1.0010x over previous
//
#include <hip/hip_runtime.h>
#include <hip/hip_fp16.h>
#include <math.h>
#include <stdio.h>

// N=50000, E=800000, IN=128, C=64, H=8, H*C=512
// R5: GEMM K-loop pipelined — T3 minimal 2-phase. BK 64->32, double-buffered
// LDS (2x24KB=48KB, same footprint). Per step: issue stage(t+1) into buf^1,
// compute buf[t] (12 ds_read_b128 + 32 MFMA), one __syncthreads (vmcnt0 drain
// = the 2ph wait). Swizzle for 64B rows: slot = quad ^ ((row>>1)&3) -> 2-way
// bank (free). Evidence: R4 L1 GEMM 146us @ MfmaUtil 30%, mem 24% — 2-barrier
// drain exposes full load latency each step. Epilogue (R3/R4) unchanged.
// attn: fp8 KV (R2). launch_bounds(256,2) — (256,3) spills acc (R3 bug).

using f16x8 = __attribute__((ext_vector_type(8))) _Float16;
using f32x4 = __attribute__((ext_vector_type(4))) float;

__device__ __forceinline__ void load_lds16(const void* g, void* l) {
  __builtin_amdgcn_global_load_lds((const __attribute__((address_space(1))) void*)g,
                                   (__attribute__((address_space(3))) void*)l,
                                   16, 0, 0);
}

// ---- fp8 e4m3 helpers (HW cvt on gfx950; software fallback kept for safety) ----
__device__ __forceinline__ void fp8x4_to_f32(unsigned int w, float* o4) {
#if __has_builtin(__builtin_amdgcn_cvt_pk_f32_fp8)
  auto lo = __builtin_amdgcn_cvt_pk_f32_fp8(w, false);
  auto hi = __builtin_amdgcn_cvt_pk_f32_fp8(w, true);
  o4[0] = lo[0]; o4[1] = lo[1]; o4[2] = hi[0]; o4[3] = hi[1];
#else
#pragma unroll
  for (int t = 0; t < 4; ++t) {
    unsigned int b = (w >> (8 * t)) & 0xFFu;
    unsigned short h = (unsigned short)(((b & 0x80u) << 8) | ((b & 0x7Fu) << 7));
    __half hv = *(__half*)&h;
    o4[t] = (float)hv * 256.0f;
  }
#endif
}

__device__ __forceinline__ unsigned int fp8_pack2_sw(float a, float b) {
  unsigned int r = 0;
#pragma unroll
  for (int t = 0; t < 2; ++t) {
    float f = t ? b : a;
    __half h = __float2half(f * (1.0f / 256.0f));
    unsigned short hb = *(unsigned short*)&h;
    unsigned int sign = (hb >> 8) & 0x80u;
    unsigned int mag = (hb & 0x7FFFu) + 0x40u;  // round
    unsigned int e = (mag >> 7) & 0x7Fu;
    if ((mag >> 7) > 0x7Eu) e = 0x7Eu;          // clamp below NaN pattern
    r |= (sign | e) << (8 * t);
  }
  return r;
}

__device__ __forceinline__ uint2 fp8_pack8(const float* f) {
#if __has_builtin(__builtin_amdgcn_cvt_pk_fp8_f32)
  int w0 = __builtin_amdgcn_cvt_pk_fp8_f32(f[0], f[1], 0, false);
  w0 = __builtin_amdgcn_cvt_pk_fp8_f32(f[2], f[3], w0, true);
  int w1 = __builtin_amdgcn_cvt_pk_fp8_f32(f[4], f[5], 0, false);
  w1 = __builtin_amdgcn_cvt_pk_fp8_f32(f[6], f[7], w1, true);
  uint2 r; r.x = (unsigned)w0; r.y = (unsigned)w1; return r;
#else
  uint2 r;
  r.x = fp8_pack2_sw(f[0], f[1]) | (fp8_pack2_sw(f[2], f[3]) << 16);
  r.y = fp8_pack2_sw(f[4], f[5]) | (fp8_pack2_sw(f[6], f[7]) << 16);
  return r;
#endif
}

// ---------------- CSR build ----------------
__global__ void zero_misc_kernel(int* __restrict__ deg, __half* __restrict__ H,
                                 int N, int Npad) {
  int t = blockIdx.x * 256 + threadIdx.x;
  if (t < N) deg[t] = 0;
  int nz = (Npad - N) * 512 / 8;
  if (t < nz) {
    f16x8 z = {};
    *(f16x8*)(H + (size_t)N * 512 + (size_t)t * 8) = z;
  }
}

__global__ void degree_kernel(const int* __restrict__ dst, int* __restrict__ deg, int E) {
  int e = blockIdx.x * blockDim.x + threadIdx.x;
  if (e < E) atomicAdd(&deg[dst[e]], 1);
}

__global__ __launch_bounds__(256)
void scan_a_kernel(const int* __restrict__ deg, int* __restrict__ rowptr,
                   int* __restrict__ bsum, int n) {
  __shared__ int tmp[256];
  int t = threadIdx.x;
  int i = blockIdx.x * 256 + t;
  int v = (i < n) ? deg[i] : 0;
  tmp[t] = v;
  __syncthreads();
#pragma unroll
  for (int off = 1; off < 256; off <<= 1) {
    int u = (t >= off) ? tmp[t - off] : 0;
    __syncthreads();
    tmp[t] += u;
    __syncthreads();
  }
  if (i < n) rowptr[i + 1] = tmp[t];
  if (t == 255) bsum[blockIdx.x] = tmp[255];
}

__global__ __launch_bounds__(256)
void scan_b_kernel(int* __restrict__ bsum, int nb) {
  __shared__ int tmp[256];
  int t = threadIdx.x;
  int v = (t < nb) ? bsum[t] : 0;
  tmp[t] = v;
  __syncthreads();
#pragma unroll
  for (int off = 1; off < 256; off <<= 1) {
    int u = (t >= off) ? tmp[t - off] : 0;
    __syncthreads();
    tmp[t] += u;
    __syncthreads();
  }
  if (t < nb) bsum[t] = tmp[t] - v;  // exclusive
}

__global__ __launch_bounds__(256)
void scan_c_kernel(int* __restrict__ rowptr, int* __restrict__ cursor,
                   const int* __restrict__ bsum, int n) {
  int i = blockIdx.x * 256 + threadIdx.x;
  if (i < n) {
    int r = rowptr[i + 1] + bsum[blockIdx.x];
    rowptr[i + 1] = r;
    cursor[i + 1] = r;
  }
  if (i == 0) { rowptr[0] = 0; cursor[0] = 0; }
}

__global__ void scatter_kernel(const int* __restrict__ src, const int* __restrict__ dst,
                               int* __restrict__ cursor, int* __restrict__ col, int E) {
  int e = blockIdx.x * blockDim.x + threadIdx.x;
  if (e < E) {
    int pos = atomicAdd(&cursor[dst[e]], 1);
    col[pos] = src[e];
  }
}

// ---------------- prep: weights/biases ----------------
__global__ __launch_bounds__(256)
void transpose_all_kernel(
    const float* __restrict__ Wq0, const float* __restrict__ Wk0,
    const float* __restrict__ Wv0, const float* __restrict__ Ws0,
    const float* __restrict__ Wq1, const float* __restrict__ Wk1,
    const float* __restrict__ Wv1, const float* __restrict__ Ws1,
    const float* __restrict__ Wq2, const float* __restrict__ Wk2,
    const float* __restrict__ Wv2, const float* __restrict__ Ws2,
    __half* __restrict__ Wt) {
  int z = blockIdx.z;
  int layer = z >> 2, m = z & 3;
  int K = (layer == 0) ? 128 : 512;
  int D = (layer == 2) ? 64 : 512;
  int c0 = blockIdx.x * 32, k0 = blockIdx.y * 32;
  if (c0 >= D || k0 >= K) return;
  const float* W;
  switch (z) {
    case 0: W = Wq0; break; case 1: W = Wk0; break;
    case 2: W = Wv0; break; case 3: W = Ws0; break;
    case 4: W = Wq1; break; case 5: W = Wk1; break;
    case 6: W = Wv1; break; case 7: W = Ws1; break;
    case 8: W = Wq2; break; case 9: W = Wk2; break;
    case 10: W = Wv2; break; default: W = Ws2; break;
  }
  __half* dstBase = Wt + ((layer == 0) ? 0 : (layer == 1) ? 262144 : 1310720);
  __shared__ float t[32][33];
  int tx = threadIdx.x & 31, ty = threadIdx.x >> 5;  // (32,8)
#pragma unroll
  for (int r = 0; r < 4; ++r)
    t[ty + 8 * r][tx] = W[(size_t)(k0 + ty + 8 * r) * D + c0 + tx];
  __syncthreads();
#pragma unroll
  for (int r = 0; r < 4; ++r)
    dstBase[(size_t)(m * D + c0 + ty + 8 * r) * K + k0 + tx] =
        __float2half(t[tx][ty + 8 * r]);
}

__global__ void bias_all_kernel(
    const float* __restrict__ b0, const float* __restrict__ b1,
    const float* __restrict__ b2, const float* __restrict__ b3,
    const float* __restrict__ b4, const float* __restrict__ b5,
    const float* __restrict__ b6, const float* __restrict__ b7,
    const float* __restrict__ b8, const float* __restrict__ b9,
    const float* __restrict__ b10, const float* __restrict__ b11,
    float* __restrict__ bias_arena) {
  int z = blockIdx.x;
  int layer = z >> 2, m = z & 3;
  int D = (layer == 2) ? 64 : 512;
  const float* b;
  switch (z) {
    case 0: b = b0; break; case 1: b = b1; break;
    case 2: b = b2; break; case 3: b = b3; break;
    case 4: b = b4; break; case 5: b = b5; break;
    case 6: b = b6; break; case 7: b = b7; break;
    case 8: b = b8; break; case 9: b = b9; break;
    case 10: b = b10; break; default: b = b11; break;
  }
  float* dst = bias_arena + ((layer == 0) ? 0 : (layer == 1) ? 2048 : 4096) + m * D;
  for (int c = threadIdx.x; c < D; c += 256) dst[c] = b[c];
}

// ---------------- MFMA GEMM: 128x256 block tile, 64x128 wave tile ----------------
// BK=32, double-buffered LDS. Row = 32 halves (64B) = 4x16B slots; slot s of
// row r holds k-chunk s ^ ((r>>1)&3) (2-way bank = free). Per K-step:
// issue stage(t+1) -> buf^1, compute buf[t], one __syncthreads (vmcnt0 drain).
// Epilogue: LDS-staged coalesced stores (reuses the 48KB buffer).
template <int LAYER>
__global__ __launch_bounds__(256, 2)
void gemm_mfma_kernel(const void* __restrict__ Avoid,
                      const __half* __restrict__ Wt,
                      const float* __restrict__ bias,
                      __half* __restrict__ QS, __half* __restrict__ KV,
                      int Nrows) {
  constexpr int K = (LAYER == 0) ? 128 : 512;
  constexpr int lda = (LAYER == 0) ? 128 : 512;
  constexpr int NT = (LAYER == 2) ? 1 : 8;  // 256-wide n-tiles
  constexpr int NSTEP = K / 32;
  __shared__ __align__(16) char smem_raw[49152];
  // buffer b: A at b*12288 (4096 halves), B at b*12288+4096 (8192 halves)
  __half* sm = (__half*)smem_raw;
  int tid = threadIdx.x;
  int wave = tid >> 6, lane = tid & 63;
  int wr = wave >> 1, wc = wave & 1;
  int bid = blockIdx.x;
  int xcd = bid & 7;
  int r = bid >> 3;
  int n0 = (r % NT) * 256;
  int m0 = ((r / NT) * 8 + xcd) * 128;
  // staging decomposition: lane -> (row-in-16, slot-in-4)
  int srow = lane >> 2;
  int sslot = lane & 3;
  int skc = (sslot ^ ((srow >> 1) & 3)) << 3;  // swizzled k offset (halves)
  // fragment read decomposition
  int quad = lane >> 4, rr = lane & 15;
  int rslot = (quad ^ ((rr >> 1) & 3)) << 3;   // read k offset within row

  f32x4 acc[4][8] = {};

  // ---- staging lambda-ish macro via helper ----
  auto stage = [&](int buf, int kt) {
    __half* As = sm + buf * 12288;
    __half* Bs = As + 4096;
    // A: 128 rows, 2 calls x 16 rows per wave
#pragma unroll
    for (int p = 0; p < 2; ++p) {
      int rbase = wave * 32 + p * 16;
      if constexpr (LAYER == 0) {
        int row = m0 + rbase + srow;
        const float* ga = (const float*)Avoid + (size_t)row * lda + kt + skc;
        f16x8 hv = {};
        if (row < Nrows) {
          float4 f0 = *(const float4*)ga;
          float4 f1 = *(const float4*)(ga + 4);
          hv[0] = (_Float16)f0.x; hv[1] = (_Float16)f0.y;
          hv[2] = (_Float16)f0.z; hv[3] = (_Float16)f0.w;
          hv[4] = (_Float16)f1.x; hv[5] = (_Float16)f1.y;
          hv[6] = (_Float16)f1.z; hv[7] = (_Float16)f1.w;
        }
        *(f16x8*)&As[(rbase + srow) * 32 + sslot * 8] = hv;
      } else {
        const __half* ga = (const __half*)Avoid +
                           (size_t)(m0 + rbase + srow) * lda + kt + skc;
        load_lds16(ga, &As[rbase * 32]);
      }
    }
    // B: 256 rows, 4 calls x 16 rows per wave
#pragma unroll
    for (int p = 0; p < 4; ++p) {
      int rbase = wave * 64 + p * 16;
      const __half* gb = Wt + (size_t)(n0 + rbase + srow) * K + kt + skc;
      load_lds16(gb, &Bs[rbase * 32]);
    }
  };

  stage(0, 0);
  __syncthreads();

  for (int t = 0; t < NSTEP; ++t) {
    if (t + 1 < NSTEP) stage((t + 1) & 1, (t + 1) * 32);
    const __half* As = sm + (t & 1) * 12288;
    const __half* Bs = As + 4096;
    f16x8 a[4], b[8];
#pragma unroll
    for (int i = 0; i < 4; ++i) {
      int row = wr * 64 + i * 16 + rr;
      a[i] = *(const f16x8*)&As[row * 32 + rslot];
    }
#pragma unroll
    for (int j = 0; j < 8; ++j) {
      int row = wc * 128 + j * 16 + rr;
      b[j] = *(const f16x8*)&Bs[row * 32 + rslot];
    }
#pragma unroll
    for (int i = 0; i < 4; ++i)
#pragma unroll
      for (int j = 0; j < 8; ++j)
        acc[i][j] = __builtin_amdgcn_mfma_f32_16x16x32_f16(a[i], b[j], acc[i][j], 0, 0, 0);
    __syncthreads();
  }

  // ---- epilogue: LDS-staged coalesced stores ----
  // C/D frag layout: col = lane&15, row = (lane>>4)*4 + reg
  int cl = lane & 15, rb = (lane >> 4) * 4;

  if constexpr (LAYER == 2) {
    // all fp16; 2 rounds of 64 rows; per-chunk seg routing (4 segs x 64 cols)
    __half* S = (__half*)smem_raw;  // [64][264] halves
#pragma unroll
    for (int round = 0; round < 2; ++round) {
      if (wr == round) {
#pragma unroll
        for (int i = 0; i < 4; ++i)
#pragma unroll
          for (int j = 0; j < 8; ++j) {
            int colL = wc * 128 + j * 16 + cl;
            float bj = bias[colL];
#pragma unroll
            for (int rg = 0; rg < 4; ++rg) {
              int rowL = i * 16 + rb + rg;
              S[rowL * 264 + colL] = __float2half(acc[i][j][rg] + bj);
            }
          }
      }
      __syncthreads();
#pragma unroll
      for (int it = 0; it < 8; ++it) {
        int id = it * 256 + tid;
        int rowL = id >> 5, ch = id & 31;
        int grow = m0 + round * 64 + rowL;
        int colb = ch * 8;
        int seg = colb >> 6, c = colb & 63;
        __half* base = (seg == 0) ? QS + (size_t)grow * 128 + c
                     : (seg == 3) ? QS + (size_t)grow * 128 + 64 + c
                     : (seg == 1) ? KV + (size_t)grow * 128 + c
                                  : KV + (size_t)grow * 128 + 64 + c;
        *(f16x8*)base = *(const f16x8*)&S[rowL * 264 + colb];
      }
      __syncthreads();
    }
  } else {
    const int msegB = n0 >> 9;   // block-uniform mseg (0=Q,1=K,2=V,3=S)
    const int cb = n0 & 511;     // col base within the 512-wide matrix
    if (msegB == 0 || msegB == 3) {
      // fp16 path -> QS
      __half* S = (__half*)smem_raw;  // [64][264] halves
      const int coff = (msegB == 3) ? 512 : 0;
#pragma unroll
      for (int round = 0; round < 2; ++round) {
        if (wr == round) {
#pragma unroll
          for (int i = 0; i < 4; ++i)
#pragma unroll
            for (int j = 0; j < 8; ++j) {
              int colL = wc * 128 + j * 16 + cl;
              float bj = bias[n0 + colL];
#pragma unroll
              for (int rg = 0; rg < 4; ++rg) {
                int rowL = i * 16 + rb + rg;
                S[rowL * 264 + colL] = __float2half(acc[i][j][rg] + bj);
              }
            }
        }
        __syncthreads();
#pragma unroll
        for (int it = 0; it < 8; ++it) {
          int id = it * 256 + tid;
          int rowL = id >> 5, ch = id & 31;
          int grow = m0 + round * 64 + rowL;
          int colb = ch * 8;
          *(f16x8*)(QS + (size_t)grow * 1024 + coff + cb + colb) =
              *(const f16x8*)&S[rowL * 264 + colb];
        }
        __syncthreads();
      }
    } else {
      // fp8 path -> KV8 interleaved [K 8B | V 8B] per 8-col group
      float* S = (float*)smem_raw;  // [32][260] floats
      unsigned char* KV8 = (unsigned char*)KV;
      const int koff = (msegB == 2) ? 8 : 0;
#pragma unroll
      for (int round = 0; round < 4; ++round) {
        if (wr == (round >> 1)) {
#pragma unroll
          for (int ii = 0; ii < 2; ++ii) {
#pragma unroll
            for (int j = 0; j < 8; ++j) {
              int colL = wc * 128 + j * 16 + cl;
              float bj = bias[n0 + colL];
#pragma unroll
              for (int rg = 0; rg < 4; ++rg) {
                int rowL = ii * 16 + rb + rg;
                S[rowL * 260 + colL] = acc[(round & 1) * 2 + ii][j][rg] + bj;
              }
            }
          }
        }
        __syncthreads();
#pragma unroll
        for (int it = 0; it < 4; ++it) {
          int id = it * 256 + tid;
          int rowL = id >> 5, ch = id & 31;
          int grow = m0 + round * 32 + rowL;
          int colb = ch * 8;
          float f[8];
          f32x4 lo = *(const f32x4*)&S[rowL * 260 + colb];
          f32x4 hi = *(const f32x4*)&S[rowL * 260 + colb + 4];
          f[0] = lo[0]; f[1] = lo[1]; f[2] = lo[2]; f[3] = lo[3];
          f[4] = hi[0]; f[5] = hi[1]; f[6] = hi[2]; f[7] = hi[3];
          uint2 pk = fp8_pack8(f);
          *(uint2*)(KV8 + (size_t)grow * 1024 + ((cb + colb) >> 3) * 16 + koff) = pk;
        }
        __syncthreads();
      }
    }
  }
}

// ---------------- attention H=8 C=64: one WAVE per node, fp8 KV, 2-pair pipeline ----------------
__global__ __launch_bounds__(256)
void attn_h8_kernel(const __half* __restrict__ QS, const unsigned char* __restrict__ KV8,
                    const int* __restrict__ rowptr, const int* __restrict__ col,
                    __half* __restrict__ Hout, int N) {
  int n = blockIdx.x * 4 + (threadIdx.x >> 6);
  if (n >= N) return;
  int lane = threadIdx.x & 63;
  size_t rbase = (size_t)n * 1024 + lane * 8;

  f16x8 qv = __builtin_nontemporal_load((const f16x8*)(QS + rbase));
  float qf[8];
#pragma unroll
  for (int j = 0; j < 8; ++j) qf[j] = (float)qv[j];

  int e0 = rowptr[n], e1 = rowptr[n + 1];
  float m = -INFINITY, l = 0.f;
  float o[8] = {};

  const uint4* KVL = (const uint4*)KV8;  // one row = 64 uint4 (lane-interleaved K|V)
  uint4 ea = {}, eb = {};
  int i = e0;
  if (i < e1)     ea = KVL[(size_t)col[i] * 64 + lane];
  if (i + 1 < e1) eb = KVL[(size_t)col[i + 1] * 64 + lane];

  while (i < e1) {
    int rem = e1 - i;
    uint4 ec = {}, ed = {};
    if (rem > 2) ec = KVL[(size_t)col[i + 2] * 64 + lane];
    if (rem > 3) ed = KVL[(size_t)col[i + 3] * 64 + lane];
    float ka[8], kb[8];
    fp8x4_to_f32(ea.x, ka); fp8x4_to_f32(ea.y, ka + 4);
    fp8x4_to_f32(eb.x, kb); fp8x4_to_f32(eb.y, kb + 4);
    float pa = 0.f, pb = 0.f;
#pragma unroll
    for (int j = 0; j < 8; ++j) { pa += ka[j] * qf[j]; pb += kb[j] * qf[j]; }
    pa += __shfl_xor(pa, 1, 64); pb += __shfl_xor(pb, 1, 64);
    pa += __shfl_xor(pa, 2, 64); pb += __shfl_xor(pb, 2, 64);
    pa += __shfl_xor(pa, 4, 64); pb += __shfl_xor(pb, 4, 64);
    float a0 = pa * 0.125f;
    float va[8];
    fp8x4_to_f32(ea.z, va); fp8x4_to_f32(ea.w, va + 4);
    if (rem > 1) {
      float vb[8];
      fp8x4_to_f32(eb.z, vb); fp8x4_to_f32(eb.w, vb + 4);
      float a1 = pb * 0.125f;
      float mn = fmaxf(m, fmaxf(a0, a1));
      float sc = __expf(m - mn);
      float ex0 = __expf(a0 - mn), ex1 = __expf(a1 - mn);
      l = l * sc + ex0 + ex1;
#pragma unroll
      for (int c = 0; c < 8; ++c)
        o[c] = o[c] * sc + ex0 * va[c] + ex1 * vb[c];
      m = mn;
    } else {
      float mn = fmaxf(m, a0);
      float sc = __expf(m - mn);
      float ex0 = __expf(a0 - mn);
      l = l * sc + ex0;
#pragma unroll
      for (int c = 0; c < 8; ++c) o[c] = o[c] * sc + ex0 * va[c];
      m = mn;
    }
    ea = ec; eb = ed;
    i += 2;
  }

  float inv = 1.f / (l + 1e-16f);
  f16x8 sv = __builtin_nontemporal_load((const f16x8*)(QS + rbase + 512));
  f16x8 hv;
#pragma unroll
  for (int c = 0; c < 8; ++c) {
    float r = o[c] * inv + (float)sv[c];
    hv[c] = (_Float16)fmaxf(r, 0.f);
  }
  __builtin_nontemporal_store(hv, (f16x8*)(Hout + (size_t)n * 512 + lane * 8));
}

// ---------------- attention H=1 C=64: 8-lane group per node, fp16 KV ----------------
__global__ __launch_bounds__(256)
void attn_h1_kernel(const __half* __restrict__ QS, const __half* __restrict__ KV,
                    const int* __restrict__ rowptr, const int* __restrict__ col,
                    float* __restrict__ out, int N) {
  int n = (blockIdx.x * 256 + threadIdx.x) >> 3;
  if (n >= N) return;
  int gl = threadIdx.x & 7;
  size_t rbase = (size_t)n * 128 + gl * 8;

  f16x8 qv = __builtin_nontemporal_load((const f16x8*)(QS + rbase));
  float qf[8];
#pragma unroll
  for (int j = 0; j < 8; ++j) qf[j] = (float)qv[j];

  int e0 = rowptr[n], e1 = rowptr[n + 1];
  float m = -INFINITY, l = 0.f;
  float o[8] = {};

  f16x8 ka = {}, va = {}, kb = {}, vb = {};
  int i = e0;
  if (i < e1) {
    const __half* p = KV + (size_t)col[i] * 128 + gl * 8;
    ka = *(const f16x8*)p; va = *(const f16x8*)(p + 64);
  }
  if (i + 1 < e1) {
    const __half* p = KV + (size_t)col[i + 1] * 128 + gl * 8;
    kb = *(const f16x8*)p; vb = *(const f16x8*)(p + 64);
  }

  while (i < e1) {
    int rem = e1 - i;
    f16x8 kc = {}, vc = {}, kd = {}, vd = {};
    if (rem > 2) {
      const __half* p = KV + (size_t)col[i + 2] * 128 + gl * 8;
      kc = *(const f16x8*)p; vc = *(const f16x8*)(p + 64);
    }
    if (rem > 3) {
      const __half* p = KV + (size_t)col[i + 3] * 128 + gl * 8;
      kd = *(const f16x8*)p; vd = *(const f16x8*)(p + 64);
    }
    float pa = 0.f, pb = 0.f;
#pragma unroll
    for (int j = 0; j < 8; ++j) { pa += (float)ka[j] * qf[j]; pb += (float)kb[j] * qf[j]; }
    pa += __shfl_xor(pa, 1, 64); pb += __shfl_xor(pb, 1, 64);
    pa += __shfl_xor(pa, 2, 64); pb += __shfl_xor(pb, 2, 64);
    pa += __shfl_xor(pa, 4, 64); pb += __shfl_xor(pb, 4, 64);
    float a0 = pa * 0.125f;
    if (rem > 1) {
      float a1 = pb * 0.125f;
      float mn = fmaxf(m, fmaxf(a0, a1));
      float sc = __expf(m - mn);
      float ea = __expf(a0 - mn), eb = __expf(a1 - mn);
      l = l * sc + ea + eb;
#pragma unroll
      for (int c = 0; c < 8; ++c)
        o[c] = o[c] * sc + ea * (float)va[c] + eb * (float)vb[c];
      m = mn;
    } else {
      float mn = fmaxf(m, a0);
      float sc = __expf(m - mn);
      float ea = __expf(a0 - mn);
      l = l * sc + ea;
#pragma unroll
      for (int c = 0; c < 8; ++c) o[c] = o[c] * sc + ea * (float)va[c];
      m = mn;
    }
    ka = kc; va = vc; kb = kd; vb = vd;
    i += 2;
  }

  float inv = 1.f / (l + 1e-16f);
  f16x8 sv = __builtin_nontemporal_load((const f16x8*)(QS + rbase + 64));
  f32x4 r0, r1;
#pragma unroll
  for (int c = 0; c < 4; ++c) r0[c] = o[c] * inv + (float)sv[c];
#pragma unroll
  for (int c = 0; c < 4; ++c) r1[c] = o[c + 4] * inv + (float)sv[c + 4];
  float* op = out + (size_t)n * 64 + gl * 8;
  *(f32x4*)op = r0;
  *(f32x4*)(op + 4) = r1;
}

extern "C" void kernel_launch(void* const* d_in, const int* in_sizes, int n_in,
                              void* d_out, int out_size, void* d_ws, size_t ws_size,
                              hipStream_t stream) {
  const float* x = (const float*)d_in[0];
  const int* ei = (const int*)d_in[1];
  const int N = in_sizes[0] / 128;
  const int E = in_sizes[1] / 2;
  // pad M so mtiles is a multiple of 8 (XCD striping)
  const int Npad = ((N + 1023) / 1024) * 1024;
  const int mtiles = Npad / 128;
  const int* srcp = ei;
  const int* dstp = ei + E;

  const float* Wq0 = (const float*)d_in[2];  const float* bq0 = (const float*)d_in[3];
  const float* Wk0 = (const float*)d_in[4];  const float* bk0 = (const float*)d_in[5];
  const float* Wv0 = (const float*)d_in[6];  const float* bv0 = (const float*)d_in[7];
  const float* Ws0 = (const float*)d_in[8];  const float* bs0 = (const float*)d_in[9];
  const float* Wq1 = (const float*)d_in[10]; const float* bq1 = (const float*)d_in[11];
  const float* Wk1 = (const float*)d_in[12]; const float* bk1 = (const float*)d_in[13];
  const float* Wv1 = (const float*)d_in[14]; const float* bv1 = (const float*)d_in[15];
  const float* Ws1 = (const float*)d_in[16]; const float* bs1 = (const float*)d_in[17];
  const float* Wq2 = (const float*)d_in[18]; const float* bq2 = (const float*)d_in[19];
  const float* Wk2 = (const float*)d_in[20]; const float* bk2 = (const float*)d_in[21];
  const float* Wv2 = (const float*)d_in[22]; const float* bv2 = (const float*)d_in[23];
  const float* Ws2 = (const float*)d_in[24]; const float* bs2 = (const float*)d_in[25];

  // ---- workspace layout ----
  char* p = (char*)d_ws;
  __half* QS = (__half*)p;               p += (size_t)Npad * 1024 * 2;  // 102.8 MB
  __half* KV = (__half*)p;               p += (size_t)Npad * 1024;      // fp8 rows (1KB); layer2 reuses as fp16 (256B rows)
  __half* H  = (__half*)p;               p += (size_t)Npad * 512 * 2;   // 51.4 MB
  __half* Wt = (__half*)p;               p += (size_t)1441792 * 2;      // 2.88 MB
  float* bias_arena = (float*)p;         p += 4352 * 4;
  int* deg    = (int*)p;                 p += (size_t)N * 4;
  int* rowptr = (int*)p;                 p += (size_t)(N + 1) * 4;
  int* cursor = (int*)p;                 p += (size_t)(N + 1) * 4;
  int* colv   = (int*)p;                 p += (size_t)E * 4;
  int* bsum   = (int*)p;                 p += 256 * 4;
  size_t need = p - (char*)d_ws;
  if (ws_size < need) {
    fprintf(stderr, "kernel_launch: ws_size=%zu < need=%zu — aborting cleanly\n",
            ws_size, need);
    return;
  }

  const int nscan = (N + 255) / 256;

  // ---- prep ----
  transpose_all_kernel<<<dim3(16, 16, 12), 256, 0, stream>>>(
      Wq0, Wk0, Wv0, Ws0, Wq1, Wk1, Wv1, Ws1, Wq2, Wk2, Wv2, Ws2, Wt);
  bias_all_kernel<<<12, 256, 0, stream>>>(
      bq0, bk0, bv0, bs0, bq1, bk1, bv1, bs1, bq2, bk2, bv2, bs2, bias_arena);
  zero_misc_kernel<<<((Npad - N) * 512 / 8 + 255) / 256 > (N + 255) / 256
                         ? ((Npad - N) * 512 / 8 + 255) / 256
                         : (N + 255) / 256,
                    256, 0, stream>>>(deg, H, N, Npad);

  // ---- CSR build ----
  degree_kernel<<<(E + 255) / 256, 256, 0, stream>>>(dstp, deg, E);
  scan_a_kernel<<<nscan, 256, 0, stream>>>(deg, rowptr, bsum, N);
  scan_b_kernel<<<1, 256, 0, stream>>>(bsum, nscan);
  scan_c_kernel<<<nscan, 256, 0, stream>>>(rowptr, cursor, bsum, N);
  scatter_kernel<<<(E + 255) / 256, 256, 0, stream>>>(srcp, dstp, cursor, colv, E);

  __half* Wt0 = Wt;
  __half* Wt1 = Wt + 262144;
  __half* Wt2 = Wt + 1310720;

  // ---- layer 0: K=128, D=512, n-tiles 8 ----
  gemm_mfma_kernel<0><<<mtiles * 8, 256, 0, stream>>>(
      x, Wt0, bias_arena, QS, KV, N);
  attn_h8_kernel<<<(N + 3) / 4, 256, 0, stream>>>(QS, (const unsigned char*)KV,
                                                  rowptr, colv, H, N);

  // ---- layer 1: K=512, D=512, n-tiles 8 ----
  gemm_mfma_kernel<1><<<mtiles * 8, 256, 0, stream>>>(
      H, Wt1, bias_arena + 2048, QS, KV, Npad);
  attn_h8_kernel<<<(N + 3) / 4, 256, 0, stream>>>(QS, (const unsigned char*)KV,
                                                  rowptr, colv, H, N);

  // ---- layer 2: K=512, D=64, n-tiles 1 ----
  gemm_mfma_kernel<2><<<mtiles, 256, 0, stream>>>(
      H, Wt2, bias_arena + 4096, QS, KV, Npad);
  attn_h1_kernel<<<(N + 31) / 32, 256, 0, stream>>>(QS, KV, rowptr, colv,
                                                    (float*)d_out, N);
}

// Round 7
// 719.199 us; speedup vs baseline: 1.8252x; 1.0388x over previous
//
#include <hip/hip_runtime.h>
#include <hip/hip_fp16.h>
#include <math.h>
#include <stdio.h>

// N=50000, E=800000, IN=128, C=64, H=8, H*C=512
// R6: GEMM K-loop -> 3-deep pipeline with COUNTED vmcnt (T3/T4). R5 evidence:
// __syncthreads' implicit vmcnt(0) drains the just-issued stage every step
// (depth-1 can't cover ~500cy HBM latency; 153us, MfmaUtil 29%). Now: 3 LDS
// buffers (72KB, 2 blocks/CU), per step wait vmcnt(12) = tile issued 3 steps
// ago already landed; raw s_barrier (no drain); stage t+3 after all waves
// finish reading buf t%3 (lgkmcnt0+barrier); setprio around MFMA (T5).
// x pre-converted to fp16 (xh) so all layers stage via global_load_lds.
// Epilogue (R3/R4, validated) unchanged. attn fp8 KV (R2) unchanged.

using f16x8 = __attribute__((ext_vector_type(8))) _Float16;
using f32x4 = __attribute__((ext_vector_type(4))) float;

__device__ __forceinline__ void load_lds16(const void* g, void* l) {
  __builtin_amdgcn_global_load_lds((const __attribute__((address_space(1))) void*)g,
                                   (__attribute__((address_space(3))) void*)l,
                                   16, 0, 0);
}

// ---- fp8 e4m3 helpers (HW cvt on gfx950; software fallback kept for safety) ----
__device__ __forceinline__ void fp8x4_to_f32(unsigned int w, float* o4) {
#if __has_builtin(__builtin_amdgcn_cvt_pk_f32_fp8)
  auto lo = __builtin_amdgcn_cvt_pk_f32_fp8(w, false);
  auto hi = __builtin_amdgcn_cvt_pk_f32_fp8(w, true);
  o4[0] = lo[0]; o4[1] = lo[1]; o4[2] = hi[0]; o4[3] = hi[1];
#else
#pragma unroll
  for (int t = 0; t < 4; ++t) {
    unsigned int b = (w >> (8 * t)) & 0xFFu;
    unsigned short h = (unsigned short)(((b & 0x80u) << 8) | ((b & 0x7Fu) << 7));
    __half hv = *(__half*)&h;
    o4[t] = (float)hv * 256.0f;
  }
#endif
}

__device__ __forceinline__ unsigned int fp8_pack2_sw(float a, float b) {
  unsigned int r = 0;
#pragma unroll
  for (int t = 0; t < 2; ++t) {
    float f = t ? b : a;
    __half h = __float2half(f * (1.0f / 256.0f));
    unsigned short hb = *(unsigned short*)&h;
    unsigned int sign = (hb >> 8) & 0x80u;
    unsigned int mag = (hb & 0x7FFFu) + 0x40u;  // round
    unsigned int e = (mag >> 7) & 0x7Fu;
    if ((mag >> 7) > 0x7Eu) e = 0x7Eu;          // clamp below NaN pattern
    r |= (sign | e) << (8 * t);
  }
  return r;
}

__device__ __forceinline__ uint2 fp8_pack8(const float* f) {
#if __has_builtin(__builtin_amdgcn_cvt_pk_fp8_f32)
  int w0 = __builtin_amdgcn_cvt_pk_fp8_f32(f[0], f[1], 0, false);
  w0 = __builtin_amdgcn_cvt_pk_fp8_f32(f[2], f[3], w0, true);
  int w1 = __builtin_amdgcn_cvt_pk_fp8_f32(f[4], f[5], 0, false);
  w1 = __builtin_amdgcn_cvt_pk_fp8_f32(f[6], f[7], w1, true);
  uint2 r; r.x = (unsigned)w0; r.y = (unsigned)w1; return r;
#else
  uint2 r;
  r.x = fp8_pack2_sw(f[0], f[1]) | (fp8_pack2_sw(f[2], f[3]) << 16);
  r.y = fp8_pack2_sw(f[4], f[5]) | (fp8_pack2_sw(f[6], f[7]) << 16);
  return r;
#endif
}

// ---------------- CSR build ----------------
__global__ void zero_misc_kernel(int* __restrict__ deg, __half* __restrict__ H,
                                 int N, int Npad) {
  int t = blockIdx.x * 256 + threadIdx.x;
  if (t < N) deg[t] = 0;
  int nz = (Npad - N) * 512 / 8;
  if (t < nz) {
    f16x8 z = {};
    *(f16x8*)(H + (size_t)N * 512 + (size_t)t * 8) = z;
  }
}

// x (f32, N x 128) -> xh (f16, Npad x 128), pad rows zeroed
__global__ void convert_x_kernel(const float* __restrict__ x, __half* __restrict__ xh,
                                 int N, int Npad) {
  int t = blockIdx.x * 256 + threadIdx.x;  // one thread per 8 halves
  if (t >= Npad * 16) return;
  int row = t >> 4;
  f16x8 hv = {};
  if (row < N) {
    const float* g = x + (size_t)t * 8;
    float4 f0 = *(const float4*)g;
    float4 f1 = *(const float4*)(g + 4);
    hv[0] = (_Float16)f0.x; hv[1] = (_Float16)f0.y;
    hv[2] = (_Float16)f0.z; hv[3] = (_Float16)f0.w;
    hv[4] = (_Float16)f1.x; hv[5] = (_Float16)f1.y;
    hv[6] = (_Float16)f1.z; hv[7] = (_Float16)f1.w;
  }
  *(f16x8*)(xh + (size_t)t * 8) = hv;
}

__global__ void degree_kernel(const int* __restrict__ dst, int* __restrict__ deg, int E) {
  int e = blockIdx.x * blockDim.x + threadIdx.x;
  if (e < E) atomicAdd(&deg[dst[e]], 1);
}

__global__ __launch_bounds__(256)
void scan_a_kernel(const int* __restrict__ deg, int* __restrict__ rowptr,
                   int* __restrict__ bsum, int n) {
  __shared__ int tmp[256];
  int t = threadIdx.x;
  int i = blockIdx.x * 256 + t;
  int v = (i < n) ? deg[i] : 0;
  tmp[t] = v;
  __syncthreads();
#pragma unroll
  for (int off = 1; off < 256; off <<= 1) {
    int u = (t >= off) ? tmp[t - off] : 0;
    __syncthreads();
    tmp[t] += u;
    __syncthreads();
  }
  if (i < n) rowptr[i + 1] = tmp[t];
  if (t == 255) bsum[blockIdx.x] = tmp[255];
}

__global__ __launch_bounds__(256)
void scan_b_kernel(int* __restrict__ bsum, int nb) {
  __shared__ int tmp[256];
  int t = threadIdx.x;
  int v = (t < nb) ? bsum[t] : 0;
  tmp[t] = v;
  __syncthreads();
#pragma unroll
  for (int off = 1; off < 256; off <<= 1) {
    int u = (t >= off) ? tmp[t - off] : 0;
    __syncthreads();
    tmp[t] += u;
    __syncthreads();
  }
  if (t < nb) bsum[t] = tmp[t] - v;  // exclusive
}

__global__ __launch_bounds__(256)
void scan_c_kernel(int* __restrict__ rowptr, int* __restrict__ cursor,
                   const int* __restrict__ bsum, int n) {
  int i = blockIdx.x * 256 + threadIdx.x;
  if (i < n) {
    int r = rowptr[i + 1] + bsum[blockIdx.x];
    rowptr[i + 1] = r;
    cursor[i + 1] = r;
  }
  if (i == 0) { rowptr[0] = 0; cursor[0] = 0; }
}

__global__ void scatter_kernel(const int* __restrict__ src, const int* __restrict__ dst,
                               int* __restrict__ cursor, int* __restrict__ col, int E) {
  int e = blockIdx.x * blockDim.x + threadIdx.x;
  if (e < E) {
    int pos = atomicAdd(&cursor[dst[e]], 1);
    col[pos] = src[e];
  }
}

// ---------------- prep: weights/biases ----------------
__global__ __launch_bounds__(256)
void transpose_all_kernel(
    const float* __restrict__ Wq0, const float* __restrict__ Wk0,
    const float* __restrict__ Wv0, const float* __restrict__ Ws0,
    const float* __restrict__ Wq1, const float* __restrict__ Wk1,
    const float* __restrict__ Wv1, const float* __restrict__ Ws1,
    const float* __restrict__ Wq2, const float* __restrict__ Wk2,
    const float* __restrict__ Wv2, const float* __restrict__ Ws2,
    __half* __restrict__ Wt) {
  int z = blockIdx.z;
  int layer = z >> 2, m = z & 3;
  int K = (layer == 0) ? 128 : 512;
  int D = (layer == 2) ? 64 : 512;
  int c0 = blockIdx.x * 32, k0 = blockIdx.y * 32;
  if (c0 >= D || k0 >= K) return;
  const float* W;
  switch (z) {
    case 0: W = Wq0; break; case 1: W = Wk0; break;
    case 2: W = Wv0; break; case 3: W = Ws0; break;
    case 4: W = Wq1; break; case 5: W = Wk1; break;
    case 6: W = Wv1; break; case 7: W = Ws1; break;
    case 8: W = Wq2; break; case 9: W = Wk2; break;
    case 10: W = Wv2; break; default: W = Ws2; break;
  }
  __half* dstBase = Wt + ((layer == 0) ? 0 : (layer == 1) ? 262144 : 1310720);
  __shared__ float t[32][33];
  int tx = threadIdx.x & 31, ty = threadIdx.x >> 5;  // (32,8)
#pragma unroll
  for (int r = 0; r < 4; ++r)
    t[ty + 8 * r][tx] = W[(size_t)(k0 + ty + 8 * r) * D + c0 + tx];
  __syncthreads();
#pragma unroll
  for (int r = 0; r < 4; ++r)
    dstBase[(size_t)(m * D + c0 + ty + 8 * r) * K + k0 + tx] =
        __float2half(t[tx][ty + 8 * r]);
}

__global__ void bias_all_kernel(
    const float* __restrict__ b0, const float* __restrict__ b1,
    const float* __restrict__ b2, const float* __restrict__ b3,
    const float* __restrict__ b4, const float* __restrict__ b5,
    const float* __restrict__ b6, const float* __restrict__ b7,
    const float* __restrict__ b8, const float* __restrict__ b9,
    const float* __restrict__ b10, const float* __restrict__ b11,
    float* __restrict__ bias_arena) {
  int z = blockIdx.x;
  int layer = z >> 2, m = z & 3;
  int D = (layer == 2) ? 64 : 512;
  const float* b;
  switch (z) {
    case 0: b = b0; break; case 1: b = b1; break;
    case 2: b = b2; break; case 3: b = b3; break;
    case 4: b = b4; break; case 5: b = b5; break;
    case 6: b = b6; break; case 7: b = b7; break;
    case 8: b = b8; break; case 9: b = b9; break;
    case 10: b = b10; break; default: b = b11; break;
  }
  float* dst = bias_arena + ((layer == 0) ? 0 : (layer == 1) ? 2048 : 4096) + m * D;
  for (int c = threadIdx.x; c < D; c += 256) dst[c] = b[c];
}

// ---------------- MFMA GEMM: 128x256 block tile, 64x128 wave tile ----------------
// BK=32, 3-deep LDS pipeline (3 x 24KB). Row = 32 halves (64B) = 4x16B slots;
// slot s of row r holds k-chunk s ^ ((r>>1)&3) (2-way bank = free).
// Step t: vmcnt(12) [tile t landed, t+1/t+2 in flight] -> s_barrier ->
// ds_read frags -> lgkmcnt(0)+barrier [all waves done with buf t%3] ->
// stage tile t+3 into buf t%3 -> setprio(1) MFMA x32 setprio(0).
// A is always fp16 (x pre-converted). Epilogue: LDS-staged coalesced stores.
template <int LAYER>
__global__ __launch_bounds__(256, 2)
void gemm_mfma_kernel(const __half* __restrict__ Aptr,
                      const __half* __restrict__ Wt,
                      const float* __restrict__ bias,
                      __half* __restrict__ QS, __half* __restrict__ KV) {
  constexpr int K = (LAYER == 0) ? 128 : 512;
  constexpr int lda = (LAYER == 0) ? 128 : 512;
  constexpr int NT = (LAYER == 2) ? 1 : 8;  // 256-wide n-tiles
  constexpr int NSTEP = K / 32;
  __shared__ __align__(16) char smem_raw[73728];  // 3 x 24KB
  __half* sm = (__half*)smem_raw;
  int tid = threadIdx.x;
  int wave = tid >> 6, lane = tid & 63;
  int wr = wave >> 1, wc = wave & 1;
  int bid = blockIdx.x;
  int xcd = bid & 7;
  int r = bid >> 3;
  int n0 = (r % NT) * 256;
  int m0 = ((r / NT) * 8 + xcd) * 128;
  // staging decomposition: lane -> (row-in-16, slot-in-4)
  int srow = lane >> 2;
  int sslot = lane & 3;
  int skc = (sslot ^ ((srow >> 1) & 3)) << 3;  // swizzled k offset (halves)
  // fragment read decomposition
  int quad = lane >> 4, rr = lane & 15;
  int rslot = (quad ^ ((rr >> 1) & 3)) << 3;   // read k offset within row

  f32x4 acc[4][8] = {};

  auto stage = [&](int buf, int kt) {
    __half* As = sm + buf * 12288;
    __half* Bs = As + 4096;
#pragma unroll
    for (int p = 0; p < 2; ++p) {
      int rbase = wave * 32 + p * 16;
      const __half* ga = Aptr + (size_t)(m0 + rbase + srow) * lda + kt + skc;
      load_lds16(ga, &As[rbase * 32]);
    }
#pragma unroll
    for (int p = 0; p < 4; ++p) {
      int rbase = wave * 64 + p * 16;
      const __half* gb = Wt + (size_t)(n0 + rbase + srow) * K + kt + skc;
      load_lds16(gb, &Bs[rbase * 32]);
    }
  };

  // prologue: 3 tiles in flight (NSTEP >= 4 for all layers)
  stage(0, 0);
  stage(1, 32);
  stage(2, 64);

  for (int t = 0; t < NSTEP; ++t) {
    // counted wait: tile t complete; keep later tiles' loads in flight
    if (t + 2 < NSTEP)      asm volatile("s_waitcnt vmcnt(12)" ::: "memory");
    else if (t + 1 < NSTEP) asm volatile("s_waitcnt vmcnt(6)" ::: "memory");
    else                    asm volatile("s_waitcnt vmcnt(0)" ::: "memory");
    __builtin_amdgcn_s_barrier();  // all waves' tile-t loads landed

    const __half* As = sm + (t % 3) * 12288;
    const __half* Bs = As + 4096;
    f16x8 a[4], b[8];
#pragma unroll
    for (int i = 0; i < 4; ++i) {
      int row = wr * 64 + i * 16 + rr;
      a[i] = *(const f16x8*)&As[row * 32 + rslot];
    }
#pragma unroll
    for (int j = 0; j < 8; ++j) {
      int row = wc * 128 + j * 16 + rr;
      b[j] = *(const f16x8*)&Bs[row * 32 + rslot];
    }
    asm volatile("s_waitcnt lgkmcnt(0)" ::: "memory");
    __builtin_amdgcn_sched_barrier(0);
    __builtin_amdgcn_s_barrier();  // all waves done reading buf t%3

    if (t + 3 < NSTEP) stage(t % 3, (t + 3) * 32);

    __builtin_amdgcn_s_setprio(1);
#pragma unroll
    for (int i = 0; i < 4; ++i)
#pragma unroll
      for (int j = 0; j < 8; ++j)
        acc[i][j] = __builtin_amdgcn_mfma_f32_16x16x32_f16(a[i], b[j], acc[i][j], 0, 0, 0);
    __builtin_amdgcn_s_setprio(0);
  }
  __syncthreads();  // protect epilogue's smem reuse from last step's reads

  // ---- epilogue: LDS-staged coalesced stores ----
  // C/D frag layout: col = lane&15, row = (lane>>4)*4 + reg
  int cl = lane & 15, rb = (lane >> 4) * 4;

  if constexpr (LAYER == 2) {
    // all fp16; 2 rounds of 64 rows; per-chunk seg routing (4 segs x 64 cols)
    __half* S = (__half*)smem_raw;  // [64][264] halves
#pragma unroll
    for (int round = 0; round < 2; ++round) {
      if (wr == round) {
#pragma unroll
        for (int i = 0; i < 4; ++i)
#pragma unroll
          for (int j = 0; j < 8; ++j) {
            int colL = wc * 128 + j * 16 + cl;
            float bj = bias[colL];
#pragma unroll
            for (int rg = 0; rg < 4; ++rg) {
              int rowL = i * 16 + rb + rg;
              S[rowL * 264 + colL] = __float2half(acc[i][j][rg] + bj);
            }
          }
      }
      __syncthreads();
#pragma unroll
      for (int it = 0; it < 8; ++it) {
        int id = it * 256 + tid;
        int rowL = id >> 5, ch = id & 31;
        int grow = m0 + round * 64 + rowL;
        int colb = ch * 8;
        int seg = colb >> 6, c = colb & 63;
        __half* base = (seg == 0) ? QS + (size_t)grow * 128 + c
                     : (seg == 3) ? QS + (size_t)grow * 128 + 64 + c
                     : (seg == 1) ? KV + (size_t)grow * 128 + c
                                  : KV + (size_t)grow * 128 + 64 + c;
        *(f16x8*)base = *(const f16x8*)&S[rowL * 264 + colb];
      }
      __syncthreads();
    }
  } else {
    const int msegB = n0 >> 9;   // block-uniform mseg (0=Q,1=K,2=V,3=S)
    const int cb = n0 & 511;     // col base within the 512-wide matrix
    if (msegB == 0 || msegB == 3) {
      // fp16 path -> QS
      __half* S = (__half*)smem_raw;  // [64][264] halves
      const int coff = (msegB == 3) ? 512 : 0;
#pragma unroll
      for (int round = 0; round < 2; ++round) {
        if (wr == round) {
#pragma unroll
          for (int i = 0; i < 4; ++i)
#pragma unroll
            for (int j = 0; j < 8; ++j) {
              int colL = wc * 128 + j * 16 + cl;
              float bj = bias[n0 + colL];
#pragma unroll
              for (int rg = 0; rg < 4; ++rg) {
                int rowL = i * 16 + rb + rg;
                S[rowL * 264 + colL] = __float2half(acc[i][j][rg] + bj);
              }
            }
        }
        __syncthreads();
#pragma unroll
        for (int it = 0; it < 8; ++it) {
          int id = it * 256 + tid;
          int rowL = id >> 5, ch = id & 31;
          int grow = m0 + round * 64 + rowL;
          int colb = ch * 8;
          *(f16x8*)(QS + (size_t)grow * 1024 + coff + cb + colb) =
              *(const f16x8*)&S[rowL * 264 + colb];
        }
        __syncthreads();
      }
    } else {
      // fp8 path -> KV8 interleaved [K 8B | V 8B] per 8-col group
      float* S = (float*)smem_raw;  // [32][260] floats
      unsigned char* KV8 = (unsigned char*)KV;
      const int koff = (msegB == 2) ? 8 : 0;
#pragma unroll
      for (int round = 0; round < 4; ++round) {
        if (wr == (round >> 1)) {
#pragma unroll
          for (int ii = 0; ii < 2; ++ii) {
#pragma unroll
            for (int j = 0; j < 8; ++j) {
              int colL = wc * 128 + j * 16 + cl;
              float bj = bias[n0 + colL];
#pragma unroll
              for (int rg = 0; rg < 4; ++rg) {
                int rowL = ii * 16 + rb + rg;
                S[rowL * 260 + colL] = acc[(round & 1) * 2 + ii][j][rg] + bj;
              }
            }
          }
        }
        __syncthreads();
#pragma unroll
        for (int it = 0; it < 4; ++it) {
          int id = it * 256 + tid;
          int rowL = id >> 5, ch = id & 31;
          int grow = m0 + round * 32 + rowL;
          int colb = ch * 8;
          float f[8];
          f32x4 lo = *(const f32x4*)&S[rowL * 260 + colb];
          f32x4 hi = *(const f32x4*)&S[rowL * 260 + colb + 4];
          f[0] = lo[0]; f[1] = lo[1]; f[2] = lo[2]; f[3] = lo[3];
          f[4] = hi[0]; f[5] = hi[1]; f[6] = hi[2]; f[7] = hi[3];
          uint2 pk = fp8_pack8(f);
          *(uint2*)(KV8 + (size_t)grow * 1024 + ((cb + colb) >> 3) * 16 + koff) = pk;
        }
        __syncthreads();
      }
    }
  }
}

// ---------------- attention H=8 C=64: one WAVE per node, fp8 KV, 2-pair pipeline ----------------
__global__ __launch_bounds__(256)
void attn_h8_kernel(const __half* __restrict__ QS, const unsigned char* __restrict__ KV8,
                    const int* __restrict__ rowptr, const int* __restrict__ col,
                    __half* __restrict__ Hout, int N) {
  int n = blockIdx.x * 4 + (threadIdx.x >> 6);
  if (n >= N) return;
  int lane = threadIdx.x & 63;
  size_t rbase = (size_t)n * 1024 + lane * 8;

  f16x8 qv = __builtin_nontemporal_load((const f16x8*)(QS + rbase));
  float qf[8];
#pragma unroll
  for (int j = 0; j < 8; ++j) qf[j] = (float)qv[j];

  int e0 = rowptr[n], e1 = rowptr[n + 1];
  float m = -INFINITY, l = 0.f;
  float o[8] = {};

  const uint4* KVL = (const uint4*)KV8;  // one row = 64 uint4 (lane-interleaved K|V)
  uint4 ea = {}, eb = {};
  int i = e0;
  if (i < e1)     ea = KVL[(size_t)col[i] * 64 + lane];
  if (i + 1 < e1) eb = KVL[(size_t)col[i + 1] * 64 + lane];

  while (i < e1) {
    int rem = e1 - i;
    uint4 ec = {}, ed = {};
    if (rem > 2) ec = KVL[(size_t)col[i + 2] * 64 + lane];
    if (rem > 3) ed = KVL[(size_t)col[i + 3] * 64 + lane];
    float ka[8], kb[8];
    fp8x4_to_f32(ea.x, ka); fp8x4_to_f32(ea.y, ka + 4);
    fp8x4_to_f32(eb.x, kb); fp8x4_to_f32(eb.y, kb + 4);
    float pa = 0.f, pb = 0.f;
#pragma unroll
    for (int j = 0; j < 8; ++j) { pa += ka[j] * qf[j]; pb += kb[j] * qf[j]; }
    pa += __shfl_xor(pa, 1, 64); pb += __shfl_xor(pb, 1, 64);
    pa += __shfl_xor(pa, 2, 64); pb += __shfl_xor(pb, 2, 64);
    pa += __shfl_xor(pa, 4, 64); pb += __shfl_xor(pb, 4, 64);
    float a0 = pa * 0.125f;
    float va[8];
    fp8x4_to_f32(ea.z, va); fp8x4_to_f32(ea.w, va + 4);
    if (rem > 1) {
      float vb[8];
      fp8x4_to_f32(eb.z, vb); fp8x4_to_f32(eb.w, vb + 4);
      float a1 = pb * 0.125f;
      float mn = fmaxf(m, fmaxf(a0, a1));
      float sc = __expf(m - mn);
      float ex0 = __expf(a0 - mn), ex1 = __expf(a1 - mn);
      l = l * sc + ex0 + ex1;
#pragma unroll
      for (int c = 0; c < 8; ++c)
        o[c] = o[c] * sc + ex0 * va[c] + ex1 * vb[c];
      m = mn;
    } else {
      float mn = fmaxf(m, a0);
      float sc = __expf(m - mn);
      float ex0 = __expf(a0 - mn);
      l = l * sc + ex0;
#pragma unroll
      for (int c = 0; c < 8; ++c) o[c] = o[c] * sc + ex0 * va[c];
      m = mn;
    }
    ea = ec; eb = ed;
    i += 2;
  }

  float inv = 1.f / (l + 1e-16f);
  f16x8 sv = __builtin_nontemporal_load((const f16x8*)(QS + rbase + 512));
  f16x8 hv;
#pragma unroll
  for (int c = 0; c < 8; ++c) {
    float r = o[c] * inv + (float)sv[c];
    hv[c] = (_Float16)fmaxf(r, 0.f);
  }
  __builtin_nontemporal_store(hv, (f16x8*)(Hout + (size_t)n * 512 + lane * 8));
}

// ---------------- attention H=1 C=64: 8-lane group per node, fp16 KV ----------------
__global__ __launch_bounds__(256)
void attn_h1_kernel(const __half* __restrict__ QS, const __half* __restrict__ KV,
                    const int* __restrict__ rowptr, const int* __restrict__ col,
                    float* __restrict__ out, int N) {
  int n = (blockIdx.x * 256 + threadIdx.x) >> 3;
  if (n >= N) return;
  int gl = threadIdx.x & 7;
  size_t rbase = (size_t)n * 128 + gl * 8;

  f16x8 qv = __builtin_nontemporal_load((const f16x8*)(QS + rbase));
  float qf[8];
#pragma unroll
  for (int j = 0; j < 8; ++j) qf[j] = (float)qv[j];

  int e0 = rowptr[n], e1 = rowptr[n + 1];
  float m = -INFINITY, l = 0.f;
  float o[8] = {};

  f16x8 ka = {}, va = {}, kb = {}, vb = {};
  int i = e0;
  if (i < e1) {
    const __half* p = KV + (size_t)col[i] * 128 + gl * 8;
    ka = *(const f16x8*)p; va = *(const f16x8*)(p + 64);
  }
  if (i + 1 < e1) {
    const __half* p = KV + (size_t)col[i + 1] * 128 + gl * 8;
    kb = *(const f16x8*)p; vb = *(const f16x8*)(p + 64);
  }

  while (i < e1) {
    int rem = e1 - i;
    f16x8 kc = {}, vc = {}, kd = {}, vd = {};
    if (rem > 2) {
      const __half* p = KV + (size_t)col[i + 2] * 128 + gl * 8;
      kc = *(const f16x8*)p; vc = *(const f16x8*)(p + 64);
    }
    if (rem > 3) {
      const __half* p = KV + (size_t)col[i + 3] * 128 + gl * 8;
      kd = *(const f16x8*)p; vd = *(const f16x8*)(p + 64);
    }
    float pa = 0.f, pb = 0.f;
#pragma unroll
    for (int j = 0; j < 8; ++j) { pa += (float)ka[j] * qf[j]; pb += (float)kb[j] * qf[j]; }
    pa += __shfl_xor(pa, 1, 64); pb += __shfl_xor(pb, 1, 64);
    pa += __shfl_xor(pa, 2, 64); pb += __shfl_xor(pb, 2, 64);
    pa += __shfl_xor(pa, 4, 64); pb += __shfl_xor(pb, 4, 64);
    float a0 = pa * 0.125f;
    if (rem > 1) {
      float a1 = pb * 0.125f;
      float mn = fmaxf(m, fmaxf(a0, a1));
      float sc = __expf(m - mn);
      float ea = __expf(a0 - mn), eb = __expf(a1 - mn);
      l = l * sc + ea + eb;
#pragma unroll
      for (int c = 0; c < 8; ++c)
        o[c] = o[c] * sc + ea * (float)va[c] + eb * (float)vb[c];
      m = mn;
    } else {
      float mn = fmaxf(m, a0);
      float sc = __expf(m - mn);
      float ea = __expf(a0 - mn);
      l = l * sc + ea;
#pragma unroll
      for (int c = 0; c < 8; ++c) o[c] = o[c] * sc + ea * (float)va[c];
      m = mn;
    }
    ka = kc; va = vc; kb = kd; vb = vd;
    i += 2;
  }

  float inv = 1.f / (l + 1e-16f);
  f16x8 sv = __builtin_nontemporal_load((const f16x8*)(QS + rbase + 64));
  f32x4 r0, r1;
#pragma unroll
  for (int c = 0; c < 4; ++c) r0[c] = o[c] * inv + (float)sv[c];
#pragma unroll
  for (int c = 0; c < 4; ++c) r1[c] = o[c + 4] * inv + (float)sv[c + 4];
  float* op = out + (size_t)n * 64 + gl * 8;
  *(f32x4*)op = r0;
  *(f32x4*)(op + 4) = r1;
}

extern "C" void kernel_launch(void* const* d_in, const int* in_sizes, int n_in,
                              void* d_out, int out_size, void* d_ws, size_t ws_size,
                              hipStream_t stream) {
  const float* x = (const float*)d_in[0];
  const int* ei = (const int*)d_in[1];
  const int N = in_sizes[0] / 128;
  const int E = in_sizes[1] / 2;
  // pad M so mtiles is a multiple of 8 (XCD striping)
  const int Npad = ((N + 1023) / 1024) * 1024;
  const int mtiles = Npad / 128;
  const int* srcp = ei;
  const int* dstp = ei + E;

  const float* Wq0 = (const float*)d_in[2];  const float* bq0 = (const float*)d_in[3];
  const float* Wk0 = (const float*)d_in[4];  const float* bk0 = (const float*)d_in[5];
  const float* Wv0 = (const float*)d_in[6];  const float* bv0 = (const float*)d_in[7];
  const float* Ws0 = (const float*)d_in[8];  const float* bs0 = (const float*)d_in[9];
  const float* Wq1 = (const float*)d_in[10]; const float* bq1 = (const float*)d_in[11];
  const float* Wk1 = (const float*)d_in[12]; const float* bk1 = (const float*)d_in[13];
  const float* Wv1 = (const float*)d_in[14]; const float* bv1 = (const float*)d_in[15];
  const float* Ws1 = (const float*)d_in[16]; const float* bs1 = (const float*)d_in[17];
  const float* Wq2 = (const float*)d_in[18]; const float* bq2 = (const float*)d_in[19];
  const float* Wk2 = (const float*)d_in[20]; const float* bk2 = (const float*)d_in[21];
  const float* Wv2 = (const float*)d_in[22]; const float* bv2 = (const float*)d_in[23];
  const float* Ws2 = (const float*)d_in[24]; const float* bs2 = (const float*)d_in[25];

  // ---- workspace layout ----
  char* p = (char*)d_ws;
  __half* QS = (__half*)p;               p += (size_t)Npad * 1024 * 2;  // 102.8 MB
  __half* KV = (__half*)p;               p += (size_t)Npad * 1024;      // fp8 rows (1KB); layer2 reuses as fp16 (256B rows)
  __half* H  = (__half*)p;               p += (size_t)Npad * 512 * 2;   // 51.4 MB
  __half* xh = (__half*)p;               p += (size_t)Npad * 128 * 2;   // 13.1 MB
  __half* Wt = (__half*)p;               p += (size_t)1441792 * 2;      // 2.88 MB
  float* bias_arena = (float*)p;         p += 4352 * 4;
  int* deg    = (int*)p;                 p += (size_t)N * 4;
  int* rowptr = (int*)p;                 p += (size_t)(N + 1) * 4;
  int* cursor = (int*)p;                 p += (size_t)(N + 1) * 4;
  int* colv   = (int*)p;                 p += (size_t)E * 4;
  int* bsum   = (int*)p;                 p += 256 * 4;
  size_t need = p - (char*)d_ws;
  if (ws_size < need) {
    fprintf(stderr, "kernel_launch: ws_size=%zu < need=%zu — aborting cleanly\n",
            ws_size, need);
    return;
  }

  const int nscan = (N + 255) / 256;

  // ---- prep ----
  transpose_all_kernel<<<dim3(16, 16, 12), 256, 0, stream>>>(
      Wq0, Wk0, Wv0, Ws0, Wq1, Wk1, Wv1, Ws1, Wq2, Wk2, Wv2, Ws2, Wt);
  bias_all_kernel<<<12, 256, 0, stream>>>(
      bq0, bk0, bv0, bs0, bq1, bk1, bv1, bs1, bq2, bk2, bv2, bs2, bias_arena);
  zero_misc_kernel<<<((Npad - N) * 512 / 8 + 255) / 256 > (N + 255) / 256
                         ? ((Npad - N) * 512 / 8 + 255) / 256
                         : (N + 255) / 256,
                    256, 0, stream>>>(deg, H, N, Npad);
  convert_x_kernel<<<(Npad * 16 + 255) / 256, 256, 0, stream>>>(x, xh, N, Npad);

  // ---- CSR build ----
  degree_kernel<<<(E + 255) / 256, 256, 0, stream>>>(dstp, deg, E);
  scan_a_kernel<<<nscan, 256, 0, stream>>>(deg, rowptr, bsum, N);
  scan_b_kernel<<<1, 256, 0, stream>>>(bsum, nscan);
  scan_c_kernel<<<nscan, 256, 0, stream>>>(rowptr, cursor, bsum, N);
  scatter_kernel<<<(E + 255) / 256, 256, 0, stream>>>(srcp, dstp, cursor, colv, E);

  __half* Wt0 = Wt;
  __half* Wt1 = Wt + 262144;
  __half* Wt2 = Wt + 1310720;

  // ---- layer 0: K=128, D=512, n-tiles 8 ----
  gemm_mfma_kernel<0><<<mtiles * 8, 256, 0, stream>>>(
      xh, Wt0, bias_arena, QS, KV);
  attn_h8_kernel<<<(N + 3) / 4, 256, 0, stream>>>(QS, (const unsigned char*)KV,
                                                  rowptr, colv, H, N);

  // ---- layer 1: K=512, D=512, n-tiles 8 ----
  gemm_mfma_kernel<1><<<mtiles * 8, 256, 0, stream>>>(
      H, Wt1, bias_arena + 2048, QS, KV);
  attn_h8_kernel<<<(N + 3) / 4, 256, 0, stream>>>(QS, (const unsigned char*)KV,
                                                  rowptr, colv, H, N);

  // ---- layer 2: K=512, D=64, n-tiles 1 ----
  gemm_mfma_kernel<2><<<mtiles, 256, 0, stream>>>(
      H, Wt2, bias_arena + 4096, QS, KV);
  attn_h1_kernel<<<(N + 31) / 32, 256, 0, stream>>>(QS, KV, rowptr, colv,
                                                    (float*)d_out, N);
}

// Round 8
// 718.124 us; speedup vs baseline: 1.8279x; 1.0015x over previous
//
#include <hip/hip_runtime.h>
#include <hip/hip_fp16.h>
#include <math.h>
#include <stdio.h>

// N=50000, E=800000, IN=128, C=64, H=8, H*C=512
// R7: GEMM step reorder: read -> MFMA -> barrier -> stage. R6 evidence: the
// explicit lgkmcnt(0)+sched_barrier+barrier BETWEEN reads and MFMA serialized
// the step (LDS 384cy + MFMA 307cy additive -> util ceiling ~40%, measured
// 31%). Every ds_read feeds an MFMA, so reads are complete when the MFMA
// block ends; barrier AFTER MFMAs protects buf reuse equally, and the
// compiler's fine-grained lgkmcnt interleaves reads with MFMAs.
// vmcnt ledger unchanged: outstanding<=18, wait 12/6/0 lands tile t exactly.
// Epilogue (R3/R4), fp8 KV attn (R2), 3-buf counted vmcnt (R6) unchanged.

using f16x8 = __attribute__((ext_vector_type(8))) _Float16;
using f32x4 = __attribute__((ext_vector_type(4))) float;

__device__ __forceinline__ void load_lds16(const void* g, void* l) {
  __builtin_amdgcn_global_load_lds((const __attribute__((address_space(1))) void*)g,
                                   (__attribute__((address_space(3))) void*)l,
                                   16, 0, 0);
}

// ---- fp8 e4m3 helpers (HW cvt on gfx950; software fallback kept for safety) ----
__device__ __forceinline__ void fp8x4_to_f32(unsigned int w, float* o4) {
#if __has_builtin(__builtin_amdgcn_cvt_pk_f32_fp8)
  auto lo = __builtin_amdgcn_cvt_pk_f32_fp8(w, false);
  auto hi = __builtin_amdgcn_cvt_pk_f32_fp8(w, true);
  o4[0] = lo[0]; o4[1] = lo[1]; o4[2] = hi[0]; o4[3] = hi[1];
#else
#pragma unroll
  for (int t = 0; t < 4; ++t) {
    unsigned int b = (w >> (8 * t)) & 0xFFu;
    unsigned short h = (unsigned short)(((b & 0x80u) << 8) | ((b & 0x7Fu) << 7));
    __half hv = *(__half*)&h;
    o4[t] = (float)hv * 256.0f;
  }
#endif
}

__device__ __forceinline__ unsigned int fp8_pack2_sw(float a, float b) {
  unsigned int r = 0;
#pragma unroll
  for (int t = 0; t < 2; ++t) {
    float f = t ? b : a;
    __half h = __float2half(f * (1.0f / 256.0f));
    unsigned short hb = *(unsigned short*)&h;
    unsigned int sign = (hb >> 8) & 0x80u;
    unsigned int mag = (hb & 0x7FFFu) + 0x40u;  // round
    unsigned int e = (mag >> 7) & 0x7Fu;
    if ((mag >> 7) > 0x7Eu) e = 0x7Eu;          // clamp below NaN pattern
    r |= (sign | e) << (8 * t);
  }
  return r;
}

__device__ __forceinline__ uint2 fp8_pack8(const float* f) {
#if __has_builtin(__builtin_amdgcn_cvt_pk_fp8_f32)
  int w0 = __builtin_amdgcn_cvt_pk_fp8_f32(f[0], f[1], 0, false);
  w0 = __builtin_amdgcn_cvt_pk_fp8_f32(f[2], f[3], w0, true);
  int w1 = __builtin_amdgcn_cvt_pk_fp8_f32(f[4], f[5], 0, false);
  w1 = __builtin_amdgcn_cvt_pk_fp8_f32(f[6], f[7], w1, true);
  uint2 r; r.x = (unsigned)w0; r.y = (unsigned)w1; return r;
#else
  uint2 r;
  r.x = fp8_pack2_sw(f[0], f[1]) | (fp8_pack2_sw(f[2], f[3]) << 16);
  r.y = fp8_pack2_sw(f[4], f[5]) | (fp8_pack2_sw(f[6], f[7]) << 16);
  return r;
#endif
}

// ---------------- CSR build ----------------
__global__ void zero_misc_kernel(int* __restrict__ deg, __half* __restrict__ H,
                                 int N, int Npad) {
  int t = blockIdx.x * 256 + threadIdx.x;
  if (t < N) deg[t] = 0;
  int nz = (Npad - N) * 512 / 8;
  if (t < nz) {
    f16x8 z = {};
    *(f16x8*)(H + (size_t)N * 512 + (size_t)t * 8) = z;
  }
}

// x (f32, N x 128) -> xh (f16, Npad x 128), pad rows zeroed
__global__ void convert_x_kernel(const float* __restrict__ x, __half* __restrict__ xh,
                                 int N, int Npad) {
  int t = blockIdx.x * 256 + threadIdx.x;  // one thread per 8 halves
  if (t >= Npad * 16) return;
  int row = t >> 4;
  f16x8 hv = {};
  if (row < N) {
    const float* g = x + (size_t)t * 8;
    float4 f0 = *(const float4*)g;
    float4 f1 = *(const float4*)(g + 4);
    hv[0] = (_Float16)f0.x; hv[1] = (_Float16)f0.y;
    hv[2] = (_Float16)f0.z; hv[3] = (_Float16)f0.w;
    hv[4] = (_Float16)f1.x; hv[5] = (_Float16)f1.y;
    hv[6] = (_Float16)f1.z; hv[7] = (_Float16)f1.w;
  }
  *(f16x8*)(xh + (size_t)t * 8) = hv;
}

__global__ void degree_kernel(const int* __restrict__ dst, int* __restrict__ deg, int E) {
  int e = blockIdx.x * blockDim.x + threadIdx.x;
  if (e < E) atomicAdd(&deg[dst[e]], 1);
}

__global__ __launch_bounds__(256)
void scan_a_kernel(const int* __restrict__ deg, int* __restrict__ rowptr,
                   int* __restrict__ bsum, int n) {
  __shared__ int tmp[256];
  int t = threadIdx.x;
  int i = blockIdx.x * 256 + t;
  int v = (i < n) ? deg[i] : 0;
  tmp[t] = v;
  __syncthreads();
#pragma unroll
  for (int off = 1; off < 256; off <<= 1) {
    int u = (t >= off) ? tmp[t - off] : 0;
    __syncthreads();
    tmp[t] += u;
    __syncthreads();
  }
  if (i < n) rowptr[i + 1] = tmp[t];
  if (t == 255) bsum[blockIdx.x] = tmp[255];
}

__global__ __launch_bounds__(256)
void scan_b_kernel(int* __restrict__ bsum, int nb) {
  __shared__ int tmp[256];
  int t = threadIdx.x;
  int v = (t < nb) ? bsum[t] : 0;
  tmp[t] = v;
  __syncthreads();
#pragma unroll
  for (int off = 1; off < 256; off <<= 1) {
    int u = (t >= off) ? tmp[t - off] : 0;
    __syncthreads();
    tmp[t] += u;
    __syncthreads();
  }
  if (t < nb) bsum[t] = tmp[t] - v;  // exclusive
}

__global__ __launch_bounds__(256)
void scan_c_kernel(int* __restrict__ rowptr, int* __restrict__ cursor,
                   const int* __restrict__ bsum, int n) {
  int i = blockIdx.x * 256 + threadIdx.x;
  if (i < n) {
    int r = rowptr[i + 1] + bsum[blockIdx.x];
    rowptr[i + 1] = r;
    cursor[i + 1] = r;
  }
  if (i == 0) { rowptr[0] = 0; cursor[0] = 0; }
}

__global__ void scatter_kernel(const int* __restrict__ src, const int* __restrict__ dst,
                               int* __restrict__ cursor, int* __restrict__ col, int E) {
  int e = blockIdx.x * blockDim.x + threadIdx.x;
  if (e < E) {
    int pos = atomicAdd(&cursor[dst[e]], 1);
    col[pos] = src[e];
  }
}

// ---------------- prep: weights/biases ----------------
__global__ __launch_bounds__(256)
void transpose_all_kernel(
    const float* __restrict__ Wq0, const float* __restrict__ Wk0,
    const float* __restrict__ Wv0, const float* __restrict__ Ws0,
    const float* __restrict__ Wq1, const float* __restrict__ Wk1,
    const float* __restrict__ Wv1, const float* __restrict__ Ws1,
    const float* __restrict__ Wq2, const float* __restrict__ Wk2,
    const float* __restrict__ Wv2, const float* __restrict__ Ws2,
    __half* __restrict__ Wt) {
  int z = blockIdx.z;
  int layer = z >> 2, m = z & 3;
  int K = (layer == 0) ? 128 : 512;
  int D = (layer == 2) ? 64 : 512;
  int c0 = blockIdx.x * 32, k0 = blockIdx.y * 32;
  if (c0 >= D || k0 >= K) return;
  const float* W;
  switch (z) {
    case 0: W = Wq0; break; case 1: W = Wk0; break;
    case 2: W = Wv0; break; case 3: W = Ws0; break;
    case 4: W = Wq1; break; case 5: W = Wk1; break;
    case 6: W = Wv1; break; case 7: W = Ws1; break;
    case 8: W = Wq2; break; case 9: W = Wk2; break;
    case 10: W = Wv2; break; default: W = Ws2; break;
  }
  __half* dstBase = Wt + ((layer == 0) ? 0 : (layer == 1) ? 262144 : 1310720);
  __shared__ float t[32][33];
  int tx = threadIdx.x & 31, ty = threadIdx.x >> 5;  // (32,8)
#pragma unroll
  for (int r = 0; r < 4; ++r)
    t[ty + 8 * r][tx] = W[(size_t)(k0 + ty + 8 * r) * D + c0 + tx];
  __syncthreads();
#pragma unroll
  for (int r = 0; r < 4; ++r)
    dstBase[(size_t)(m * D + c0 + ty + 8 * r) * K + k0 + tx] =
        __float2half(t[tx][ty + 8 * r]);
}

__global__ void bias_all_kernel(
    const float* __restrict__ b0, const float* __restrict__ b1,
    const float* __restrict__ b2, const float* __restrict__ b3,
    const float* __restrict__ b4, const float* __restrict__ b5,
    const float* __restrict__ b6, const float* __restrict__ b7,
    const float* __restrict__ b8, const float* __restrict__ b9,
    const float* __restrict__ b10, const float* __restrict__ b11,
    float* __restrict__ bias_arena) {
  int z = blockIdx.x;
  int layer = z >> 2, m = z & 3;
  int D = (layer == 2) ? 64 : 512;
  const float* b;
  switch (z) {
    case 0: b = b0; break; case 1: b = b1; break;
    case 2: b = b2; break; case 3: b = b3; break;
    case 4: b = b4; break; case 5: b = b5; break;
    case 6: b = b6; break; case 7: b = b7; break;
    case 8: b = b8; break; case 9: b = b9; break;
    case 10: b = b10; break; default: b = b11; break;
  }
  float* dst = bias_arena + ((layer == 0) ? 0 : (layer == 1) ? 2048 : 4096) + m * D;
  for (int c = threadIdx.x; c < D; c += 256) dst[c] = b[c];
}

// ---------------- MFMA GEMM: 128x256 block tile, 64x128 wave tile ----------------
// BK=32, 3-deep LDS pipeline (3 x 24KB). Row = 32 halves (64B) = 4x16B slots;
// slot s of row r holds k-chunk s ^ ((r>>1)&3) (2-way bank = free).
// Step t: vmcnt(12/6/0) [tile t landed, later tiles in flight] -> s_barrier ->
// ds_read frags + MFMA (compiler fine-grained lgkmcnt interleave) ->
// s_barrier [reads of buf t%3 all consumed] -> stage tile t+3 into buf t%3.
template <int LAYER>
__global__ __launch_bounds__(256, 2)
void gemm_mfma_kernel(const __half* __restrict__ Aptr,
                      const __half* __restrict__ Wt,
                      const float* __restrict__ bias,
                      __half* __restrict__ QS, __half* __restrict__ KV) {
  constexpr int K = (LAYER == 0) ? 128 : 512;
  constexpr int lda = (LAYER == 0) ? 128 : 512;
  constexpr int NT = (LAYER == 2) ? 1 : 8;  // 256-wide n-tiles
  constexpr int NSTEP = K / 32;
  __shared__ __align__(16) char smem_raw[73728];  // 3 x 24KB
  __half* sm = (__half*)smem_raw;
  int tid = threadIdx.x;
  int wave = tid >> 6, lane = tid & 63;
  int wr = wave >> 1, wc = wave & 1;
  int bid = blockIdx.x;
  int xcd = bid & 7;
  int r = bid >> 3;
  int n0 = (r % NT) * 256;
  int m0 = ((r / NT) * 8 + xcd) * 128;
  // staging decomposition: lane -> (row-in-16, slot-in-4)
  int srow = lane >> 2;
  int sslot = lane & 3;
  int skc = (sslot ^ ((srow >> 1) & 3)) << 3;  // swizzled k offset (halves)
  // fragment read decomposition
  int quad = lane >> 4, rr = lane & 15;
  int rslot = (quad ^ ((rr >> 1) & 3)) << 3;   // read k offset within row

  f32x4 acc[4][8] = {};

  auto stage = [&](int buf, int kt) {
    __half* As = sm + buf * 12288;
    __half* Bs = As + 4096;
#pragma unroll
    for (int p = 0; p < 2; ++p) {
      int rbase = wave * 32 + p * 16;
      const __half* ga = Aptr + (size_t)(m0 + rbase + srow) * lda + kt + skc;
      load_lds16(ga, &As[rbase * 32]);
    }
#pragma unroll
    for (int p = 0; p < 4; ++p) {
      int rbase = wave * 64 + p * 16;
      const __half* gb = Wt + (size_t)(n0 + rbase + srow) * K + kt + skc;
      load_lds16(gb, &Bs[rbase * 32]);
    }
  };

  // prologue: 3 tiles in flight (NSTEP >= 4 for all layers)
  stage(0, 0);
  stage(1, 32);
  stage(2, 64);

  for (int t = 0; t < NSTEP; ++t) {
    // counted wait: tile t complete; keep later tiles' loads in flight
    if (t + 2 < NSTEP)      asm volatile("s_waitcnt vmcnt(12)" ::: "memory");
    else if (t + 1 < NSTEP) asm volatile("s_waitcnt vmcnt(6)" ::: "memory");
    else                    asm volatile("s_waitcnt vmcnt(0)" ::: "memory");
    __builtin_amdgcn_s_barrier();  // all waves' tile-t loads landed

    const __half* As = sm + (t % 3) * 12288;
    const __half* Bs = As + 4096;
    f16x8 a[4], b[8];
#pragma unroll
    for (int i = 0; i < 4; ++i) {
      int row = wr * 64 + i * 16 + rr;
      a[i] = *(const f16x8*)&As[row * 32 + rslot];
    }
#pragma unroll
    for (int j = 0; j < 8; ++j) {
      int row = wc * 128 + j * 16 + rr;
      b[j] = *(const f16x8*)&Bs[row * 32 + rslot];
    }
    // no forced drain: compiler interleaves MFMAs with counted lgkmcnt
    __builtin_amdgcn_s_setprio(1);
#pragma unroll
    for (int i = 0; i < 4; ++i)
#pragma unroll
      for (int j = 0; j < 8; ++j)
        acc[i][j] = __builtin_amdgcn_mfma_f32_16x16x32_f16(a[i], b[j], acc[i][j], 0, 0, 0);
    __builtin_amdgcn_s_setprio(0);
    // all reads consumed by MFMAs above -> barrier makes buf t%3 safe to reuse
    __builtin_amdgcn_s_barrier();
    if (t + 3 < NSTEP) stage(t % 3, (t + 3) * 32);
  }
  __syncthreads();  // protect epilogue's smem reuse

  // ---- epilogue: LDS-staged coalesced stores ----
  // C/D frag layout: col = lane&15, row = (lane>>4)*4 + reg
  int cl = lane & 15, rb = (lane >> 4) * 4;

  if constexpr (LAYER == 2) {
    // all fp16; 2 rounds of 64 rows; per-chunk seg routing (4 segs x 64 cols)
    __half* S = (__half*)smem_raw;  // [64][264] halves
#pragma unroll
    for (int round = 0; round < 2; ++round) {
      if (wr == round) {
#pragma unroll
        for (int i = 0; i < 4; ++i)
#pragma unroll
          for (int j = 0; j < 8; ++j) {
            int colL = wc * 128 + j * 16 + cl;
            float bj = bias[colL];
#pragma unroll
            for (int rg = 0; rg < 4; ++rg) {
              int rowL = i * 16 + rb + rg;
              S[rowL * 264 + colL] = __float2half(acc[i][j][rg] + bj);
            }
          }
      }
      __syncthreads();
#pragma unroll
      for (int it = 0; it < 8; ++it) {
        int id = it * 256 + tid;
        int rowL = id >> 5, ch = id & 31;
        int grow = m0 + round * 64 + rowL;
        int colb = ch * 8;
        int seg = colb >> 6, c = colb & 63;
        __half* base = (seg == 0) ? QS + (size_t)grow * 128 + c
                     : (seg == 3) ? QS + (size_t)grow * 128 + 64 + c
                     : (seg == 1) ? KV + (size_t)grow * 128 + c
                                  : KV + (size_t)grow * 128 + 64 + c;
        *(f16x8*)base = *(const f16x8*)&S[rowL * 264 + colb];
      }
      __syncthreads();
    }
  } else {
    const int msegB = n0 >> 9;   // block-uniform mseg (0=Q,1=K,2=V,3=S)
    const int cb = n0 & 511;     // col base within the 512-wide matrix
    if (msegB == 0 || msegB == 3) {
      // fp16 path -> QS
      __half* S = (__half*)smem_raw;  // [64][264] halves
      const int coff = (msegB == 3) ? 512 : 0;
#pragma unroll
      for (int round = 0; round < 2; ++round) {
        if (wr == round) {
#pragma unroll
          for (int i = 0; i < 4; ++i)
#pragma unroll
            for (int j = 0; j < 8; ++j) {
              int colL = wc * 128 + j * 16 + cl;
              float bj = bias[n0 + colL];
#pragma unroll
              for (int rg = 0; rg < 4; ++rg) {
                int rowL = i * 16 + rb + rg;
                S[rowL * 264 + colL] = __float2half(acc[i][j][rg] + bj);
              }
            }
        }
        __syncthreads();
#pragma unroll
        for (int it = 0; it < 8; ++it) {
          int id = it * 256 + tid;
          int rowL = id >> 5, ch = id & 31;
          int grow = m0 + round * 64 + rowL;
          int colb = ch * 8;
          *(f16x8*)(QS + (size_t)grow * 1024 + coff + cb + colb) =
              *(const f16x8*)&S[rowL * 264 + colb];
        }
        __syncthreads();
      }
    } else {
      // fp8 path -> KV8 interleaved [K 8B | V 8B] per 8-col group
      float* S = (float*)smem_raw;  // [32][260] floats
      unsigned char* KV8 = (unsigned char*)KV;
      const int koff = (msegB == 2) ? 8 : 0;
#pragma unroll
      for (int round = 0; round < 4; ++round) {
        if (wr == (round >> 1)) {
#pragma unroll
          for (int ii = 0; ii < 2; ++ii) {
#pragma unroll
            for (int j = 0; j < 8; ++j) {
              int colL = wc * 128 + j * 16 + cl;
              float bj = bias[n0 + colL];
#pragma unroll
              for (int rg = 0; rg < 4; ++rg) {
                int rowL = ii * 16 + rb + rg;
                S[rowL * 260 + colL] = acc[(round & 1) * 2 + ii][j][rg] + bj;
              }
            }
          }
        }
        __syncthreads();
#pragma unroll
        for (int it = 0; it < 4; ++it) {
          int id = it * 256 + tid;
          int rowL = id >> 5, ch = id & 31;
          int grow = m0 + round * 32 + rowL;
          int colb = ch * 8;
          float f[8];
          f32x4 lo = *(const f32x4*)&S[rowL * 260 + colb];
          f32x4 hi = *(const f32x4*)&S[rowL * 260 + colb + 4];
          f[0] = lo[0]; f[1] = lo[1]; f[2] = lo[2]; f[3] = lo[3];
          f[4] = hi[0]; f[5] = hi[1]; f[6] = hi[2]; f[7] = hi[3];
          uint2 pk = fp8_pack8(f);
          *(uint2*)(KV8 + (size_t)grow * 1024 + ((cb + colb) >> 3) * 16 + koff) = pk;
        }
        __syncthreads();
      }
    }
  }
}

// ---------------- attention H=8 C=64: one WAVE per node, fp8 KV, 2-pair pipeline ----------------
__global__ __launch_bounds__(256)
void attn_h8_kernel(const __half* __restrict__ QS, const unsigned char* __restrict__ KV8,
                    const int* __restrict__ rowptr, const int* __restrict__ col,
                    __half* __restrict__ Hout, int N) {
  int n = blockIdx.x * 4 + (threadIdx.x >> 6);
  if (n >= N) return;
  int lane = threadIdx.x & 63;
  size_t rbase = (size_t)n * 1024 + lane * 8;

  f16x8 qv = __builtin_nontemporal_load((const f16x8*)(QS + rbase));
  float qf[8];
#pragma unroll
  for (int j = 0; j < 8; ++j) qf[j] = (float)qv[j];

  int e0 = rowptr[n], e1 = rowptr[n + 1];
  float m = -INFINITY, l = 0.f;
  float o[8] = {};

  const uint4* KVL = (const uint4*)KV8;  // one row = 64 uint4 (lane-interleaved K|V)
  uint4 ea = {}, eb = {};
  int i = e0;
  if (i < e1)     ea = KVL[(size_t)col[i] * 64 + lane];
  if (i + 1 < e1) eb = KVL[(size_t)col[i + 1] * 64 + lane];

  while (i < e1) {
    int rem = e1 - i;
    uint4 ec = {}, ed = {};
    if (rem > 2) ec = KVL[(size_t)col[i + 2] * 64 + lane];
    if (rem > 3) ed = KVL[(size_t)col[i + 3] * 64 + lane];
    float ka[8], kb[8];
    fp8x4_to_f32(ea.x, ka); fp8x4_to_f32(ea.y, ka + 4);
    fp8x4_to_f32(eb.x, kb); fp8x4_to_f32(eb.y, kb + 4);
    float pa = 0.f, pb = 0.f;
#pragma unroll
    for (int j = 0; j < 8; ++j) { pa += ka[j] * qf[j]; pb += kb[j] * qf[j]; }
    pa += __shfl_xor(pa, 1, 64); pb += __shfl_xor(pb, 1, 64);
    pa += __shfl_xor(pa, 2, 64); pb += __shfl_xor(pb, 2, 64);
    pa += __shfl_xor(pa, 4, 64); pb += __shfl_xor(pb, 4, 64);
    float a0 = pa * 0.125f;
    float va[8];
    fp8x4_to_f32(ea.z, va); fp8x4_to_f32(ea.w, va + 4);
    if (rem > 1) {
      float vb[8];
      fp8x4_to_f32(eb.z, vb); fp8x4_to_f32(eb.w, vb + 4);
      float a1 = pb * 0.125f;
      float mn = fmaxf(m, fmaxf(a0, a1));
      float sc = __expf(m - mn);
      float ex0 = __expf(a0 - mn), ex1 = __expf(a1 - mn);
      l = l * sc + ex0 + ex1;
#pragma unroll
      for (int c = 0; c < 8; ++c)
        o[c] = o[c] * sc + ex0 * va[c] + ex1 * vb[c];
      m = mn;
    } else {
      float mn = fmaxf(m, a0);
      float sc = __expf(m - mn);
      float ex0 = __expf(a0 - mn);
      l = l * sc + ex0;
#pragma unroll
      for (int c = 0; c < 8; ++c) o[c] = o[c] * sc + ex0 * va[c];
      m = mn;
    }
    ea = ec; eb = ed;
    i += 2;
  }

  float inv = 1.f / (l + 1e-16f);
  f16x8 sv = __builtin_nontemporal_load((const f16x8*)(QS + rbase + 512));
  f16x8 hv;
#pragma unroll
  for (int c = 0; c < 8; ++c) {
    float r = o[c] * inv + (float)sv[c];
    hv[c] = (_Float16)fmaxf(r, 0.f);
  }
  __builtin_nontemporal_store(hv, (f16x8*)(Hout + (size_t)n * 512 + lane * 8));
}

// ---------------- attention H=1 C=64: 8-lane group per node, fp16 KV ----------------
__global__ __launch_bounds__(256)
void attn_h1_kernel(const __half* __restrict__ QS, const __half* __restrict__ KV,
                    const int* __restrict__ rowptr, const int* __restrict__ col,
                    float* __restrict__ out, int N) {
  int n = (blockIdx.x * 256 + threadIdx.x) >> 3;
  if (n >= N) return;
  int gl = threadIdx.x & 7;
  size_t rbase = (size_t)n * 128 + gl * 8;

  f16x8 qv = __builtin_nontemporal_load((const f16x8*)(QS + rbase));
  float qf[8];
#pragma unroll
  for (int j = 0; j < 8; ++j) qf[j] = (float)qv[j];

  int e0 = rowptr[n], e1 = rowptr[n + 1];
  float m = -INFINITY, l = 0.f;
  float o[8] = {};

  f16x8 ka = {}, va = {}, kb = {}, vb = {};
  int i = e0;
  if (i < e1) {
    const __half* p = KV + (size_t)col[i] * 128 + gl * 8;
    ka = *(const f16x8*)p; va = *(const f16x8*)(p + 64);
  }
  if (i + 1 < e1) {
    const __half* p = KV + (size_t)col[i + 1] * 128 + gl * 8;
    kb = *(const f16x8*)p; vb = *(const f16x8*)(p + 64);
  }

  while (i < e1) {
    int rem = e1 - i;
    f16x8 kc = {}, vc = {}, kd = {}, vd = {};
    if (rem > 2) {
      const __half* p = KV + (size_t)col[i + 2] * 128 + gl * 8;
      kc = *(const f16x8*)p; vc = *(const f16x8*)(p + 64);
    }
    if (rem > 3) {
      const __half* p = KV + (size_t)col[i + 3] * 128 + gl * 8;
      kd = *(const f16x8*)p; vd = *(const f16x8*)(p + 64);
    }
    float pa = 0.f, pb = 0.f;
#pragma unroll
    for (int j = 0; j < 8; ++j) { pa += (float)ka[j] * qf[j]; pb += (float)kb[j] * qf[j]; }
    pa += __shfl_xor(pa, 1, 64); pb += __shfl_xor(pb, 1, 64);
    pa += __shfl_xor(pa, 2, 64); pb += __shfl_xor(pb, 2, 64);
    pa += __shfl_xor(pa, 4, 64); pb += __shfl_xor(pb, 4, 64);
    float a0 = pa * 0.125f;
    if (rem > 1) {
      float a1 = pb * 0.125f;
      float mn = fmaxf(m, fmaxf(a0, a1));
      float sc = __expf(m - mn);
      float ea = __expf(a0 - mn), eb = __expf(a1 - mn);
      l = l * sc + ea + eb;
#pragma unroll
      for (int c = 0; c < 8; ++c)
        o[c] = o[c] * sc + ea * (float)va[c] + eb * (float)vb[c];
      m = mn;
    } else {
      float mn = fmaxf(m, a0);
      float sc = __expf(m - mn);
      float ea = __expf(a0 - mn);
      l = l * sc + ea;
#pragma unroll
      for (int c = 0; c < 8; ++c) o[c] = o[c] * sc + ea * (float)va[c];
      m = mn;
    }
    ka = kc; va = vc; kb = kd; vb = vd;
    i += 2;
  }

  float inv = 1.f / (l + 1e-16f);
  f16x8 sv = __builtin_nontemporal_load((const f16x8*)(QS + rbase + 64));
  f32x4 r0, r1;
#pragma unroll
  for (int c = 0; c < 4; ++c) r0[c] = o[c] * inv + (float)sv[c];
#pragma unroll
  for (int c = 0; c < 4; ++c) r1[c] = o[c + 4] * inv + (float)sv[c + 4];
  float* op = out + (size_t)n * 64 + gl * 8;
  *(f32x4*)op = r0;
  *(f32x4*)(op + 4) = r1;
}

extern "C" void kernel_launch(void* const* d_in, const int* in_sizes, int n_in,
                              void* d_out, int out_size, void* d_ws, size_t ws_size,
                              hipStream_t stream) {
  const float* x = (const float*)d_in[0];
  const int* ei = (const int*)d_in[1];
  const int N = in_sizes[0] / 128;
  const int E = in_sizes[1] / 2;
  // pad M so mtiles is a multiple of 8 (XCD striping)
  const int Npad = ((N + 1023) / 1024) * 1024;
  const int mtiles = Npad / 128;
  const int* srcp = ei;
  const int* dstp = ei + E;

  const float* Wq0 = (const float*)d_in[2];  const float* bq0 = (const float*)d_in[3];
  const float* Wk0 = (const float*)d_in[4];  const float* bk0 = (const float*)d_in[5];
  const float* Wv0 = (const float*)d_in[6];  const float* bv0 = (const float*)d_in[7];
  const float* Ws0 = (const float*)d_in[8];  const float* bs0 = (const float*)d_in[9];
  const float* Wq1 = (const float*)d_in[10]; const float* bq1 = (const float*)d_in[11];
  const float* Wk1 = (const float*)d_in[12]; const float* bk1 = (const float*)d_in[13];
  const float* Wv1 = (const float*)d_in[14]; const float* bv1 = (const float*)d_in[15];
  const float* Ws1 = (const float*)d_in[16]; const float* bs1 = (const float*)d_in[17];
  const float* Wq2 = (const float*)d_in[18]; const float* bq2 = (const float*)d_in[19];
  const float* Wk2 = (const float*)d_in[20]; const float* bk2 = (const float*)d_in[21];
  const float* Wv2 = (const float*)d_in[22]; const float* bv2 = (const float*)d_in[23];
  const float* Ws2 = (const float*)d_in[24]; const float* bs2 = (const float*)d_in[25];

  // ---- workspace layout ----
  char* p = (char*)d_ws;
  __half* QS = (__half*)p;               p += (size_t)Npad * 1024 * 2;  // 102.8 MB
  __half* KV = (__half*)p;               p += (size_t)Npad * 1024;      // fp8 rows (1KB); layer2 reuses as fp16 (256B rows)
  __half* H  = (__half*)p;               p += (size_t)Npad * 512 * 2;   // 51.4 MB
  __half* xh = (__half*)p;               p += (size_t)Npad * 128 * 2;   // 13.1 MB
  __half* Wt = (__half*)p;               p += (size_t)1441792 * 2;      // 2.88 MB
  float* bias_arena = (float*)p;         p += 4352 * 4;
  int* deg    = (int*)p;                 p += (size_t)N * 4;
  int* rowptr = (int*)p;                 p += (size_t)(N + 1) * 4;
  int* cursor = (int*)p;                 p += (size_t)(N + 1) * 4;
  int* colv   = (int*)p;                 p += (size_t)E * 4;
  int* bsum   = (int*)p;                 p += 256 * 4;
  size_t need = p - (char*)d_ws;
  if (ws_size < need) {
    fprintf(stderr, "kernel_launch: ws_size=%zu < need=%zu — aborting cleanly\n",
            ws_size, need);
    return;
  }

  const int nscan = (N + 255) / 256;

  // ---- prep ----
  transpose_all_kernel<<<dim3(16, 16, 12), 256, 0, stream>>>(
      Wq0, Wk0, Wv0, Ws0, Wq1, Wk1, Wv1, Ws1, Wq2, Wk2, Wv2, Ws2, Wt);
  bias_all_kernel<<<12, 256, 0, stream>>>(
      bq0, bk0, bv0, bs0, bq1, bk1, bv1, bs1, bq2, bk2, bv2, bs2, bias_arena);
  zero_misc_kernel<<<((Npad - N) * 512 / 8 + 255) / 256 > (N + 255) / 256
                         ? ((Npad - N) * 512 / 8 + 255) / 256
                         : (N + 255) / 256,
                    256, 0, stream>>>(deg, H, N, Npad);
  convert_x_kernel<<<(Npad * 16 + 255) / 256, 256, 0, stream>>>(x, xh, N, Npad);

  // ---- CSR build ----
  degree_kernel<<<(E + 255) / 256, 256, 0, stream>>>(dstp, deg, E);
  scan_a_kernel<<<nscan, 256, 0, stream>>>(deg, rowptr, bsum, N);
  scan_b_kernel<<<1, 256, 0, stream>>>(bsum, nscan);
  scan_c_kernel<<<nscan, 256, 0, stream>>>(rowptr, cursor, bsum, N);
  scatter_kernel<<<(E + 255) / 256, 256, 0, stream>>>(srcp, dstp, cursor, colv, E);

  __half* Wt0 = Wt;
  __half* Wt1 = Wt + 262144;
  __half* Wt2 = Wt + 1310720;

  // ---- layer 0: K=128, D=512, n-tiles 8 ----
  gemm_mfma_kernel<0><<<mtiles * 8, 256, 0, stream>>>(
      xh, Wt0, bias_arena, QS, KV);
  attn_h8_kernel<<<(N + 3) / 4, 256, 0, stream>>>(QS, (const unsigned char*)KV,
                                                  rowptr, colv, H, N);

  // ---- layer 1: K=512, D=512, n-tiles 8 ----
  gemm_mfma_kernel<1><<<mtiles * 8, 256, 0, stream>>>(
      H, Wt1, bias_arena + 2048, QS, KV);
  attn_h8_kernel<<<(N + 3) / 4, 256, 0, stream>>>(QS, (const unsigned char*)KV,
                                                  rowptr, colv, H, N);

  // ---- layer 2: K=512, D=64, n-tiles 1 ----
  gemm_mfma_kernel<2><<<mtiles, 256, 0, stream>>>(
      H, Wt2, bias_arena + 4096, QS, KV);
  attn_h1_kernel<<<(N + 31) / 32, 256, 0, stream>>>(QS, KV, rowptr, colv,
                                                    (float*)d_out, N);
}

// Round 9
// 714.819 us; speedup vs baseline: 1.8363x; 1.0046x over previous
//
#include <hip/hip_runtime.h>
#include <hip/hip_fp16.h>
#include <math.h>
#include <stdio.h>

// N=50000, E=800000, IN=128, C=64, H=8, H*C=512
// R8: Q -> fp8 for layers 0/1. Evidence: GEMM K-loop pinned at 146us across
// FOUR schedule variants (R4-R7, MfmaUtil ~30%) -> frozen. attn scales 1:1
// with L2-miss bytes (822MB/243us fp16 -> ~470MB/~140us fp8 KV, pinned
// ~3.5TB/s = L3 BW). Q feeds only the QK dot (precision-equiv to K, already
// fp8). Q8 = dense 512B rows (GEMM epilogue packs from f32); S stays fp16
// (512-half rows). Layer 2 path unchanged. zero_misc+convert_x merged.
// absmax expected 0.0088 -> ~0.012; if FAIL, revert Q to fp16.

using f16x8 = __attribute__((ext_vector_type(8))) _Float16;
using f32x4 = __attribute__((ext_vector_type(4))) float;

__device__ __forceinline__ void load_lds16(const void* g, void* l) {
  __builtin_amdgcn_global_load_lds((const __attribute__((address_space(1))) void*)g,
                                   (__attribute__((address_space(3))) void*)l,
                                   16, 0, 0);
}

// ---- fp8 e4m3 helpers (HW cvt on gfx950; software fallback kept for safety) ----
__device__ __forceinline__ void fp8x4_to_f32(unsigned int w, float* o4) {
#if __has_builtin(__builtin_amdgcn_cvt_pk_f32_fp8)
  auto lo = __builtin_amdgcn_cvt_pk_f32_fp8(w, false);
  auto hi = __builtin_amdgcn_cvt_pk_f32_fp8(w, true);
  o4[0] = lo[0]; o4[1] = lo[1]; o4[2] = hi[0]; o4[3] = hi[1];
#else
#pragma unroll
  for (int t = 0; t < 4; ++t) {
    unsigned int b = (w >> (8 * t)) & 0xFFu;
    unsigned short h = (unsigned short)(((b & 0x80u) << 8) | ((b & 0x7Fu) << 7));
    __half hv = *(__half*)&h;
    o4[t] = (float)hv * 256.0f;
  }
#endif
}

__device__ __forceinline__ unsigned int fp8_pack2_sw(float a, float b) {
  unsigned int r = 0;
#pragma unroll
  for (int t = 0; t < 2; ++t) {
    float f = t ? b : a;
    __half h = __float2half(f * (1.0f / 256.0f));
    unsigned short hb = *(unsigned short*)&h;
    unsigned int sign = (hb >> 8) & 0x80u;
    unsigned int mag = (hb & 0x7FFFu) + 0x40u;  // round
    unsigned int e = (mag >> 7) & 0x7Fu;
    if ((mag >> 7) > 0x7Eu) e = 0x7Eu;          // clamp below NaN pattern
    r |= (sign | e) << (8 * t);
  }
  return r;
}

__device__ __forceinline__ uint2 fp8_pack8(const float* f) {
#if __has_builtin(__builtin_amdgcn_cvt_pk_fp8_f32)
  int w0 = __builtin_amdgcn_cvt_pk_fp8_f32(f[0], f[1], 0, false);
  w0 = __builtin_amdgcn_cvt_pk_fp8_f32(f[2], f[3], w0, true);
  int w1 = __builtin_amdgcn_cvt_pk_fp8_f32(f[4], f[5], 0, false);
  w1 = __builtin_amdgcn_cvt_pk_fp8_f32(f[6], f[7], w1, true);
  uint2 r; r.x = (unsigned)w0; r.y = (unsigned)w1; return r;
#else
  uint2 r;
  r.x = fp8_pack2_sw(f[0], f[1]) | (fp8_pack2_sw(f[2], f[3]) << 16);
  r.y = fp8_pack2_sw(f[4], f[5]) | (fp8_pack2_sw(f[6], f[7]) << 16);
  return r;
#endif
}

// ---------------- prep: zero deg, zero H pad, convert x->fp16 ----------------
__global__ void prep_x_kernel(const float* __restrict__ x, __half* __restrict__ xh,
                              int* __restrict__ deg, __half* __restrict__ H,
                              int N, int Npad) {
  int t = blockIdx.x * 256 + threadIdx.x;
  if (t < N) deg[t] = 0;
  int nz = (Npad - N) * 64;  // pad vec8 slots of H
  if (t < nz) {
    f16x8 z = {};
    *(f16x8*)(H + (size_t)N * 512 + (size_t)t * 8) = z;
  }
  if (t < Npad * 16) {
    int row = t >> 4;
    f16x8 hv = {};
    if (row < N) {
      const float* g = x + (size_t)t * 8;
      float4 f0 = *(const float4*)g;
      float4 f1 = *(const float4*)(g + 4);
      hv[0] = (_Float16)f0.x; hv[1] = (_Float16)f0.y;
      hv[2] = (_Float16)f0.z; hv[3] = (_Float16)f0.w;
      hv[4] = (_Float16)f1.x; hv[5] = (_Float16)f1.y;
      hv[6] = (_Float16)f1.z; hv[7] = (_Float16)f1.w;
    }
    *(f16x8*)(xh + (size_t)t * 8) = hv;
  }
}

// ---------------- CSR build ----------------
__global__ void degree_kernel(const int* __restrict__ dst, int* __restrict__ deg, int E) {
  int e = blockIdx.x * blockDim.x + threadIdx.x;
  if (e < E) atomicAdd(&deg[dst[e]], 1);
}

__global__ __launch_bounds__(256)
void scan_a_kernel(const int* __restrict__ deg, int* __restrict__ rowptr,
                   int* __restrict__ bsum, int n) {
  __shared__ int tmp[256];
  int t = threadIdx.x;
  int i = blockIdx.x * 256 + t;
  int v = (i < n) ? deg[i] : 0;
  tmp[t] = v;
  __syncthreads();
#pragma unroll
  for (int off = 1; off < 256; off <<= 1) {
    int u = (t >= off) ? tmp[t - off] : 0;
    __syncthreads();
    tmp[t] += u;
    __syncthreads();
  }
  if (i < n) rowptr[i + 1] = tmp[t];
  if (t == 255) bsum[blockIdx.x] = tmp[255];
}

__global__ __launch_bounds__(256)
void scan_b_kernel(int* __restrict__ bsum, int nb) {
  __shared__ int tmp[256];
  int t = threadIdx.x;
  int v = (t < nb) ? bsum[t] : 0;
  tmp[t] = v;
  __syncthreads();
#pragma unroll
  for (int off = 1; off < 256; off <<= 1) {
    int u = (t >= off) ? tmp[t - off] : 0;
    __syncthreads();
    tmp[t] += u;
    __syncthreads();
  }
  if (t < nb) bsum[t] = tmp[t] - v;  // exclusive
}

__global__ __launch_bounds__(256)
void scan_c_kernel(int* __restrict__ rowptr, int* __restrict__ cursor,
                   const int* __restrict__ bsum, int n) {
  int i = blockIdx.x * 256 + threadIdx.x;
  if (i < n) {
    int r = rowptr[i + 1] + bsum[blockIdx.x];
    rowptr[i + 1] = r;
    cursor[i + 1] = r;
  }
  if (i == 0) { rowptr[0] = 0; cursor[0] = 0; }
}

__global__ void scatter_kernel(const int* __restrict__ src, const int* __restrict__ dst,
                               int* __restrict__ cursor, int* __restrict__ col, int E) {
  int e = blockIdx.x * blockDim.x + threadIdx.x;
  if (e < E) {
    int pos = atomicAdd(&cursor[dst[e]], 1);
    col[pos] = src[e];
  }
}

// ---------------- prep: weights/biases ----------------
__global__ __launch_bounds__(256)
void transpose_all_kernel(
    const float* __restrict__ Wq0, const float* __restrict__ Wk0,
    const float* __restrict__ Wv0, const float* __restrict__ Ws0,
    const float* __restrict__ Wq1, const float* __restrict__ Wk1,
    const float* __restrict__ Wv1, const float* __restrict__ Ws1,
    const float* __restrict__ Wq2, const float* __restrict__ Wk2,
    const float* __restrict__ Wv2, const float* __restrict__ Ws2,
    __half* __restrict__ Wt) {
  int z = blockIdx.z;
  int layer = z >> 2, m = z & 3;
  int K = (layer == 0) ? 128 : 512;
  int D = (layer == 2) ? 64 : 512;
  int c0 = blockIdx.x * 32, k0 = blockIdx.y * 32;
  if (c0 >= D || k0 >= K) return;
  const float* W;
  switch (z) {
    case 0: W = Wq0; break; case 1: W = Wk0; break;
    case 2: W = Wv0; break; case 3: W = Ws0; break;
    case 4: W = Wq1; break; case 5: W = Wk1; break;
    case 6: W = Wv1; break; case 7: W = Ws1; break;
    case 8: W = Wq2; break; case 9: W = Wk2; break;
    case 10: W = Wv2; break; default: W = Ws2; break;
  }
  __half* dstBase = Wt + ((layer == 0) ? 0 : (layer == 1) ? 262144 : 1310720);
  __shared__ float t[32][33];
  int tx = threadIdx.x & 31, ty = threadIdx.x >> 5;  // (32,8)
#pragma unroll
  for (int r = 0; r < 4; ++r)
    t[ty + 8 * r][tx] = W[(size_t)(k0 + ty + 8 * r) * D + c0 + tx];
  __syncthreads();
#pragma unroll
  for (int r = 0; r < 4; ++r)
    dstBase[(size_t)(m * D + c0 + ty + 8 * r) * K + k0 + tx] =
        __float2half(t[tx][ty + 8 * r]);
}

__global__ void bias_all_kernel(
    const float* __restrict__ b0, const float* __restrict__ b1,
    const float* __restrict__ b2, const float* __restrict__ b3,
    const float* __restrict__ b4, const float* __restrict__ b5,
    const float* __restrict__ b6, const float* __restrict__ b7,
    const float* __restrict__ b8, const float* __restrict__ b9,
    const float* __restrict__ b10, const float* __restrict__ b11,
    float* __restrict__ bias_arena) {
  int z = blockIdx.x;
  int layer = z >> 2, m = z & 3;
  int D = (layer == 2) ? 64 : 512;
  const float* b;
  switch (z) {
    case 0: b = b0; break; case 1: b = b1; break;
    case 2: b = b2; break; case 3: b = b3; break;
    case 4: b = b4; break; case 5: b = b5; break;
    case 6: b = b6; break; case 7: b = b7; break;
    case 8: b = b8; break; case 9: b = b9; break;
    case 10: b = b10; break; default: b = b11; break;
  }
  float* dst = bias_arena + ((layer == 0) ? 0 : (layer == 1) ? 2048 : 4096) + m * D;
  for (int c = threadIdx.x; c < D; c += 256) dst[c] = b[c];
}

// ---------------- MFMA GEMM: 128x256 block tile, 64x128 wave tile ----------------
// BK=32, 3-deep LDS pipeline (3 x 24KB), counted vmcnt (R6/R7, frozen).
// Epilogue (layers 0/1): mseg 0 (Q) -> fp8 dense Q8 (512B rows);
// mseg 1/2 (K/V) -> fp8 interleaved KV8 (1KB rows); mseg 3 (S) -> fp16 S16
// (512-half rows). LAYER 2: fp16 dual QS/KV (128-half rows), unchanged.
template <int LAYER>
__global__ __launch_bounds__(256, 2)
void gemm_mfma_kernel(const __half* __restrict__ Aptr,
                      const __half* __restrict__ Wt,
                      const float* __restrict__ bias,
                      __half* __restrict__ QS, __half* __restrict__ KV,
                      unsigned char* __restrict__ Q8,
                      __half* __restrict__ S16) {
  constexpr int K = (LAYER == 0) ? 128 : 512;
  constexpr int lda = (LAYER == 0) ? 128 : 512;
  constexpr int NT = (LAYER == 2) ? 1 : 8;  // 256-wide n-tiles
  constexpr int NSTEP = K / 32;
  __shared__ __align__(16) char smem_raw[73728];  // 3 x 24KB
  __half* sm = (__half*)smem_raw;
  int tid = threadIdx.x;
  int wave = tid >> 6, lane = tid & 63;
  int wr = wave >> 1, wc = wave & 1;
  int bid = blockIdx.x;
  int xcd = bid & 7;
  int r = bid >> 3;
  int n0 = (r % NT) * 256;
  int m0 = ((r / NT) * 8 + xcd) * 128;
  // staging decomposition: lane -> (row-in-16, slot-in-4)
  int srow = lane >> 2;
  int sslot = lane & 3;
  int skc = (sslot ^ ((srow >> 1) & 3)) << 3;  // swizzled k offset (halves)
  // fragment read decomposition
  int quad = lane >> 4, rr = lane & 15;
  int rslot = (quad ^ ((rr >> 1) & 3)) << 3;   // read k offset within row

  f32x4 acc[4][8] = {};

  auto stage = [&](int buf, int kt) {
    __half* As = sm + buf * 12288;
    __half* Bs = As + 4096;
#pragma unroll
    for (int p = 0; p < 2; ++p) {
      int rbase = wave * 32 + p * 16;
      const __half* ga = Aptr + (size_t)(m0 + rbase + srow) * lda + kt + skc;
      load_lds16(ga, &As[rbase * 32]);
    }
#pragma unroll
    for (int p = 0; p < 4; ++p) {
      int rbase = wave * 64 + p * 16;
      const __half* gb = Wt + (size_t)(n0 + rbase + srow) * K + kt + skc;
      load_lds16(gb, &Bs[rbase * 32]);
    }
  };

  // prologue: 3 tiles in flight (NSTEP >= 4 for all layers)
  stage(0, 0);
  stage(1, 32);
  stage(2, 64);

  for (int t = 0; t < NSTEP; ++t) {
    if (t + 2 < NSTEP)      asm volatile("s_waitcnt vmcnt(12)" ::: "memory");
    else if (t + 1 < NSTEP) asm volatile("s_waitcnt vmcnt(6)" ::: "memory");
    else                    asm volatile("s_waitcnt vmcnt(0)" ::: "memory");
    __builtin_amdgcn_s_barrier();  // all waves' tile-t loads landed

    const __half* As = sm + (t % 3) * 12288;
    const __half* Bs = As + 4096;
    f16x8 a[4], b[8];
#pragma unroll
    for (int i = 0; i < 4; ++i) {
      int row = wr * 64 + i * 16 + rr;
      a[i] = *(const f16x8*)&As[row * 32 + rslot];
    }
#pragma unroll
    for (int j = 0; j < 8; ++j) {
      int row = wc * 128 + j * 16 + rr;
      b[j] = *(const f16x8*)&Bs[row * 32 + rslot];
    }
    __builtin_amdgcn_s_setprio(1);
#pragma unroll
    for (int i = 0; i < 4; ++i)
#pragma unroll
      for (int j = 0; j < 8; ++j)
        acc[i][j] = __builtin_amdgcn_mfma_f32_16x16x32_f16(a[i], b[j], acc[i][j], 0, 0, 0);
    __builtin_amdgcn_s_setprio(0);
    __builtin_amdgcn_s_barrier();  // reads of buf t%3 all consumed
    if (t + 3 < NSTEP) stage(t % 3, (t + 3) * 32);
  }
  __syncthreads();  // protect epilogue's smem reuse

  // ---- epilogue: LDS-staged coalesced stores ----
  int cl = lane & 15, rb = (lane >> 4) * 4;

  if constexpr (LAYER == 2) {
    // all fp16; 2 rounds of 64 rows; per-chunk seg routing (4 segs x 64 cols)
    __half* S = (__half*)smem_raw;  // [64][264] halves
#pragma unroll
    for (int round = 0; round < 2; ++round) {
      if (wr == round) {
#pragma unroll
        for (int i = 0; i < 4; ++i)
#pragma unroll
          for (int j = 0; j < 8; ++j) {
            int colL = wc * 128 + j * 16 + cl;
            float bj = bias[colL];
#pragma unroll
            for (int rg = 0; rg < 4; ++rg) {
              int rowL = i * 16 + rb + rg;
              S[rowL * 264 + colL] = __float2half(acc[i][j][rg] + bj);
            }
          }
      }
      __syncthreads();
#pragma unroll
      for (int it = 0; it < 8; ++it) {
        int id = it * 256 + tid;
        int rowL = id >> 5, ch = id & 31;
        int grow = m0 + round * 64 + rowL;
        int colb = ch * 8;
        int seg = colb >> 6, c = colb & 63;
        __half* base = (seg == 0) ? QS + (size_t)grow * 128 + c
                     : (seg == 3) ? QS + (size_t)grow * 128 + 64 + c
                     : (seg == 1) ? KV + (size_t)grow * 128 + c
                                  : KV + (size_t)grow * 128 + 64 + c;
        *(f16x8*)base = *(const f16x8*)&S[rowL * 264 + colb];
      }
      __syncthreads();
    }
  } else {
    const int msegB = n0 >> 9;   // block-uniform mseg (0=Q,1=K,2=V,3=S)
    const int cb = n0 & 511;     // col base within the 512-wide matrix
    if (msegB == 3) {
      // fp16 path -> S16 (512-half rows)
      __half* S = (__half*)smem_raw;  // [64][264] halves
#pragma unroll
      for (int round = 0; round < 2; ++round) {
        if (wr == round) {
#pragma unroll
          for (int i = 0; i < 4; ++i)
#pragma unroll
            for (int j = 0; j < 8; ++j) {
              int colL = wc * 128 + j * 16 + cl;
              float bj = bias[n0 + colL];
#pragma unroll
              for (int rg = 0; rg < 4; ++rg) {
                int rowL = i * 16 + rb + rg;
                S[rowL * 264 + colL] = __float2half(acc[i][j][rg] + bj);
              }
            }
        }
        __syncthreads();
#pragma unroll
        for (int it = 0; it < 8; ++it) {
          int id = it * 256 + tid;
          int rowL = id >> 5, ch = id & 31;
          int grow = m0 + round * 64 + rowL;
          int colb = ch * 8;
          *(f16x8*)(S16 + (size_t)grow * 512 + cb + colb) =
              *(const f16x8*)&S[rowL * 264 + colb];
        }
        __syncthreads();
      }
    } else if (msegB == 0) {
      // fp8 dense path -> Q8 (512-byte rows)
      float* S = (float*)smem_raw;  // [32][260] floats
#pragma unroll
      for (int round = 0; round < 4; ++round) {
        if (wr == (round >> 1)) {
#pragma unroll
          for (int ii = 0; ii < 2; ++ii) {
#pragma unroll
            for (int j = 0; j < 8; ++j) {
              int colL = wc * 128 + j * 16 + cl;
              float bj = bias[n0 + colL];
#pragma unroll
              for (int rg = 0; rg < 4; ++rg) {
                int rowL = ii * 16 + rb + rg;
                S[rowL * 260 + colL] = acc[(round & 1) * 2 + ii][j][rg] + bj;
              }
            }
          }
        }
        __syncthreads();
#pragma unroll
        for (int it = 0; it < 4; ++it) {
          int id = it * 256 + tid;
          int rowL = id >> 5, ch = id & 31;
          int grow = m0 + round * 32 + rowL;
          int colb = ch * 8;
          float f[8];
          f32x4 lo = *(const f32x4*)&S[rowL * 260 + colb];
          f32x4 hi = *(const f32x4*)&S[rowL * 260 + colb + 4];
          f[0] = lo[0]; f[1] = lo[1]; f[2] = lo[2]; f[3] = lo[3];
          f[4] = hi[0]; f[5] = hi[1]; f[6] = hi[2]; f[7] = hi[3];
          uint2 pk = fp8_pack8(f);
          *(uint2*)(Q8 + (size_t)grow * 512 + cb + colb) = pk;
        }
        __syncthreads();
      }
    } else {
      // fp8 path -> KV8 interleaved [K 8B | V 8B] per 8-col group (1KB rows)
      float* S = (float*)smem_raw;  // [32][260] floats
      unsigned char* KV8 = (unsigned char*)KV;
      const int koff = (msegB == 2) ? 8 : 0;
#pragma unroll
      for (int round = 0; round < 4; ++round) {
        if (wr == (round >> 1)) {
#pragma unroll
          for (int ii = 0; ii < 2; ++ii) {
#pragma unroll
            for (int j = 0; j < 8; ++j) {
              int colL = wc * 128 + j * 16 + cl;
              float bj = bias[n0 + colL];
#pragma unroll
              for (int rg = 0; rg < 4; ++rg) {
                int rowL = ii * 16 + rb + rg;
                S[rowL * 260 + colL] = acc[(round & 1) * 2 + ii][j][rg] + bj;
              }
            }
          }
        }
        __syncthreads();
#pragma unroll
        for (int it = 0; it < 4; ++it) {
          int id = it * 256 + tid;
          int rowL = id >> 5, ch = id & 31;
          int grow = m0 + round * 32 + rowL;
          int colb = ch * 8;
          float f[8];
          f32x4 lo = *(const f32x4*)&S[rowL * 260 + colb];
          f32x4 hi = *(const f32x4*)&S[rowL * 260 + colb + 4];
          f[0] = lo[0]; f[1] = lo[1]; f[2] = lo[2]; f[3] = lo[3];
          f[4] = hi[0]; f[5] = hi[1]; f[6] = hi[2]; f[7] = hi[3];
          uint2 pk = fp8_pack8(f);
          *(uint2*)(KV8 + (size_t)grow * 1024 + ((cb + colb) >> 3) * 16 + koff) = pk;
        }
        __syncthreads();
      }
    }
  }
}

// ---------------- attention H=8 C=64: one WAVE per node, fp8 Q/KV ----------------
__global__ __launch_bounds__(256)
void attn_h8_kernel(const unsigned char* __restrict__ Q8,
                    const __half* __restrict__ S16,
                    const unsigned char* __restrict__ KV8,
                    const int* __restrict__ rowptr, const int* __restrict__ col,
                    __half* __restrict__ Hout, int N) {
  int n = blockIdx.x * 4 + (threadIdx.x >> 6);
  if (n >= N) return;
  int lane = threadIdx.x & 63;

  uint2 qw = *(const uint2*)(Q8 + (size_t)n * 512 + lane * 8);
  float qf[8];
  fp8x4_to_f32(qw.x, qf);
  fp8x4_to_f32(qw.y, qf + 4);

  int e0 = rowptr[n], e1 = rowptr[n + 1];
  float m = -INFINITY, l = 0.f;
  float o[8] = {};

  const uint4* KVL = (const uint4*)KV8;  // one row = 64 uint4 (lane-interleaved K|V)
  uint4 ea = {}, eb = {};
  int i = e0;
  if (i < e1)     ea = KVL[(size_t)col[i] * 64 + lane];
  if (i + 1 < e1) eb = KVL[(size_t)col[i + 1] * 64 + lane];

  while (i < e1) {
    int rem = e1 - i;
    uint4 ec = {}, ed = {};
    if (rem > 2) ec = KVL[(size_t)col[i + 2] * 64 + lane];
    if (rem > 3) ed = KVL[(size_t)col[i + 3] * 64 + lane];
    float ka[8], kb[8];
    fp8x4_to_f32(ea.x, ka); fp8x4_to_f32(ea.y, ka + 4);
    fp8x4_to_f32(eb.x, kb); fp8x4_to_f32(eb.y, kb + 4);
    float pa = 0.f, pb = 0.f;
#pragma unroll
    for (int j = 0; j < 8; ++j) { pa += ka[j] * qf[j]; pb += kb[j] * qf[j]; }
    pa += __shfl_xor(pa, 1, 64); pb += __shfl_xor(pb, 1, 64);
    pa += __shfl_xor(pa, 2, 64); pb += __shfl_xor(pb, 2, 64);
    pa += __shfl_xor(pa, 4, 64); pb += __shfl_xor(pb, 4, 64);
    float a0 = pa * 0.125f;
    float va[8];
    fp8x4_to_f32(ea.z, va); fp8x4_to_f32(ea.w, va + 4);
    if (rem > 1) {
      float vb[8];
      fp8x4_to_f32(eb.z, vb); fp8x4_to_f32(eb.w, vb + 4);
      float a1 = pb * 0.125f;
      float mn = fmaxf(m, fmaxf(a0, a1));
      float sc = __expf(m - mn);
      float ex0 = __expf(a0 - mn), ex1 = __expf(a1 - mn);
      l = l * sc + ex0 + ex1;
#pragma unroll
      for (int c = 0; c < 8; ++c)
        o[c] = o[c] * sc + ex0 * va[c] + ex1 * vb[c];
      m = mn;
    } else {
      float mn = fmaxf(m, a0);
      float sc = __expf(m - mn);
      float ex0 = __expf(a0 - mn);
      l = l * sc + ex0;
#pragma unroll
      for (int c = 0; c < 8; ++c) o[c] = o[c] * sc + ex0 * va[c];
      m = mn;
    }
    ea = ec; eb = ed;
    i += 2;
  }

  float inv = 1.f / (l + 1e-16f);
  f16x8 sv = __builtin_nontemporal_load((const f16x8*)(S16 + (size_t)n * 512 + lane * 8));
  f16x8 hv;
#pragma unroll
  for (int c = 0; c < 8; ++c) {
    float r = o[c] * inv + (float)sv[c];
    hv[c] = (_Float16)fmaxf(r, 0.f);
  }
  __builtin_nontemporal_store(hv, (f16x8*)(Hout + (size_t)n * 512 + lane * 8));
}

// ---------------- attention H=1 C=64: 8-lane group per node, fp16 KV ----------------
__global__ __launch_bounds__(256)
void attn_h1_kernel(const __half* __restrict__ QS, const __half* __restrict__ KV,
                    const int* __restrict__ rowptr, const int* __restrict__ col,
                    float* __restrict__ out, int N) {
  int n = (blockIdx.x * 256 + threadIdx.x) >> 3;
  if (n >= N) return;
  int gl = threadIdx.x & 7;
  size_t rbase = (size_t)n * 128 + gl * 8;

  f16x8 qv = __builtin_nontemporal_load((const f16x8*)(QS + rbase));
  float qf[8];
#pragma unroll
  for (int j = 0; j < 8; ++j) qf[j] = (float)qv[j];

  int e0 = rowptr[n], e1 = rowptr[n + 1];
  float m = -INFINITY, l = 0.f;
  float o[8] = {};

  f16x8 ka = {}, va = {}, kb = {}, vb = {};
  int i = e0;
  if (i < e1) {
    const __half* p = KV + (size_t)col[i] * 128 + gl * 8;
    ka = *(const f16x8*)p; va = *(const f16x8*)(p + 64);
  }
  if (i + 1 < e1) {
    const __half* p = KV + (size_t)col[i + 1] * 128 + gl * 8;
    kb = *(const f16x8*)p; vb = *(const f16x8*)(p + 64);
  }

  while (i < e1) {
    int rem = e1 - i;
    f16x8 kc = {}, vc = {}, kd = {}, vd = {};
    if (rem > 2) {
      const __half* p = KV + (size_t)col[i + 2] * 128 + gl * 8;
      kc = *(const f16x8*)p; vc = *(const f16x8*)(p + 64);
    }
    if (rem > 3) {
      const __half* p = KV + (size_t)col[i + 3] * 128 + gl * 8;
      kd = *(const f16x8*)p; vd = *(const f16x8*)(p + 64);
    }
    float pa = 0.f, pb = 0.f;
#pragma unroll
    for (int j = 0; j < 8; ++j) { pa += (float)ka[j] * qf[j]; pb += (float)kb[j] * qf[j]; }
    pa += __shfl_xor(pa, 1, 64); pb += __shfl_xor(pb, 1, 64);
    pa += __shfl_xor(pa, 2, 64); pb += __shfl_xor(pb, 2, 64);
    pa += __shfl_xor(pa, 4, 64); pb += __shfl_xor(pb, 4, 64);
    float a0 = pa * 0.125f;
    if (rem > 1) {
      float a1 = pb * 0.125f;
      float mn = fmaxf(m, fmaxf(a0, a1));
      float sc = __expf(m - mn);
      float ea = __expf(a0 - mn), eb = __expf(a1 - mn);
      l = l * sc + ea + eb;
#pragma unroll
      for (int c = 0; c < 8; ++c)
        o[c] = o[c] * sc + ea * (float)va[c] + eb * (float)vb[c];
      m = mn;
    } else {
      float mn = fmaxf(m, a0);
      float sc = __expf(m - mn);
      float ea = __expf(a0 - mn);
      l = l * sc + ea;
#pragma unroll
      for (int c = 0; c < 8; ++c) o[c] = o[c] * sc + ea * (float)va[c];
      m = mn;
    }
    ka = kc; va = vc; kb = kd; vb = vd;
    i += 2;
  }

  float inv = 1.f / (l + 1e-16f);
  f16x8 sv = __builtin_nontemporal_load((const f16x8*)(QS + rbase + 64));
  f32x4 r0, r1;
#pragma unroll
  for (int c = 0; c < 4; ++c) r0[c] = o[c] * inv + (float)sv[c];
#pragma unroll
  for (int c = 0; c < 4; ++c) r1[c] = o[c + 4] * inv + (float)sv[c + 4];
  float* op = out + (size_t)n * 64 + gl * 8;
  *(f32x4*)op = r0;
  *(f32x4*)(op + 4) = r1;
}

extern "C" void kernel_launch(void* const* d_in, const int* in_sizes, int n_in,
                              void* d_out, int out_size, void* d_ws, size_t ws_size,
                              hipStream_t stream) {
  const float* x = (const float*)d_in[0];
  const int* ei = (const int*)d_in[1];
  const int N = in_sizes[0] / 128;
  const int E = in_sizes[1] / 2;
  // pad M so mtiles is a multiple of 8 (XCD striping)
  const int Npad = ((N + 1023) / 1024) * 1024;
  const int mtiles = Npad / 128;
  const int* srcp = ei;
  const int* dstp = ei + E;

  const float* Wq0 = (const float*)d_in[2];  const float* bq0 = (const float*)d_in[3];
  const float* Wk0 = (const float*)d_in[4];  const float* bk0 = (const float*)d_in[5];
  const float* Wv0 = (const float*)d_in[6];  const float* bv0 = (const float*)d_in[7];
  const float* Ws0 = (const float*)d_in[8];  const float* bs0 = (const float*)d_in[9];
  const float* Wq1 = (const float*)d_in[10]; const float* bq1 = (const float*)d_in[11];
  const float* Wk1 = (const float*)d_in[12]; const float* bk1 = (const float*)d_in[13];
  const float* Wv1 = (const float*)d_in[14]; const float* bv1 = (const float*)d_in[15];
  const float* Ws1 = (const float*)d_in[16]; const float* bs1 = (const float*)d_in[17];
  const float* Wq2 = (const float*)d_in[18]; const float* bq2 = (const float*)d_in[19];
  const float* Wk2 = (const float*)d_in[20]; const float* bk2 = (const float*)d_in[21];
  const float* Wv2 = (const float*)d_in[22]; const float* bv2 = (const float*)d_in[23];
  const float* Ws2 = (const float*)d_in[24]; const float* bs2 = (const float*)d_in[25];

  // ---- workspace layout ----
  char* p = (char*)d_ws;
  __half* S16 = (__half*)p;              p += (size_t)Npad * 512 * 2;   // 51.4 MB (S; layer2 reuses as QS 128-half rows)
  unsigned char* Q8 = (unsigned char*)p; p += (size_t)Npad * 512;       // 25.7 MB
  __half* KV = (__half*)p;               p += (size_t)Npad * 1024;      // fp8 1KB rows; layer2 fp16 256B rows
  __half* H  = (__half*)p;               p += (size_t)Npad * 512 * 2;   // 51.4 MB
  __half* xh = (__half*)p;               p += (size_t)Npad * 128 * 2;   // 12.8 MB
  __half* Wt = (__half*)p;               p += (size_t)1441792 * 2;      // 2.88 MB
  float* bias_arena = (float*)p;         p += 4352 * 4;
  int* deg    = (int*)p;                 p += (size_t)N * 4;
  int* rowptr = (int*)p;                 p += (size_t)(N + 1) * 4;
  int* cursor = (int*)p;                 p += (size_t)(N + 1) * 4;
  int* colv   = (int*)p;                 p += (size_t)E * 4;
  int* bsum   = (int*)p;                 p += 256 * 4;
  size_t need = p - (char*)d_ws;
  if (ws_size < need) {
    fprintf(stderr, "kernel_launch: ws_size=%zu < need=%zu — aborting cleanly\n",
            ws_size, need);
    return;
  }

  const int nscan = (N + 255) / 256;

  // ---- prep ----
  transpose_all_kernel<<<dim3(16, 16, 12), 256, 0, stream>>>(
      Wq0, Wk0, Wv0, Ws0, Wq1, Wk1, Wv1, Ws1, Wq2, Wk2, Wv2, Ws2, Wt);
  bias_all_kernel<<<12, 256, 0, stream>>>(
      bq0, bk0, bv0, bs0, bq1, bk1, bv1, bs1, bq2, bk2, bv2, bs2, bias_arena);
  prep_x_kernel<<<(Npad * 16 + 255) / 256, 256, 0, stream>>>(x, xh, deg, H, N, Npad);

  // ---- CSR build ----
  degree_kernel<<<(E + 255) / 256, 256, 0, stream>>>(dstp, deg, E);
  scan_a_kernel<<<nscan, 256, 0, stream>>>(deg, rowptr, bsum, N);
  scan_b_kernel<<<1, 256, 0, stream>>>(bsum, nscan);
  scan_c_kernel<<<nscan, 256, 0, stream>>>(rowptr, cursor, bsum, N);
  scatter_kernel<<<(E + 255) / 256, 256, 0, stream>>>(srcp, dstp, cursor, colv, E);

  __half* Wt0 = Wt;
  __half* Wt1 = Wt + 262144;
  __half* Wt2 = Wt + 1310720;

  // ---- layer 0: K=128, D=512, n-tiles 8 ----
  gemm_mfma_kernel<0><<<mtiles * 8, 256, 0, stream>>>(
      xh, Wt0, bias_arena, S16, KV, Q8, S16);
  attn_h8_kernel<<<(N + 3) / 4, 256, 0, stream>>>(Q8, S16, (const unsigned char*)KV,
                                                  rowptr, colv, H, N);

  // ---- layer 1: K=512, D=512, n-tiles 8 ----
  gemm_mfma_kernel<1><<<mtiles * 8, 256, 0, stream>>>(
      H, Wt1, bias_arena + 2048, S16, KV, Q8, S16);
  attn_h8_kernel<<<(N + 3) / 4, 256, 0, stream>>>(Q8, S16, (const unsigned char*)KV,
                                                  rowptr, colv, H, N);

  // ---- layer 2: K=512, D=64, n-tiles 1 (fp16 path, S16 reused as QS) ----
  gemm_mfma_kernel<2><<<mtiles, 256, 0, stream>>>(
      H, Wt2, bias_arena + 4096, S16, KV, Q8, S16);
  attn_h1_kernel<<<(N + 31) / 32, 256, 0, stream>>>(S16, KV, rowptr, colv,
                                                    (float*)d_out, N);
}

// Round 11
// 701.087 us; speedup vs baseline: 1.8723x; 1.0196x over previous
//
#include <hip/hip_runtime.h>
#include <hip/hip_fp16.h>
#include <math.h>
#include <stdio.h>

// N=50000, E=800000, IN=128, C=64, H=8, H*C=512
// R9: GEMM tile 128x256 -> 128x128 (wave tile 64x64, acc[4][4]=64 VGPR).
// Evidence: 146us across 4 schedules + write-cut; ALL counters 16-31% =
// latency-bound at 2 blocks/CU (72KB LDS). Now: 16KB x 3 buffers = 48KB ->
// 3 blocks/CU; launch_bounds(256,3) safe with halved acc (R3's spill was
// acc[4][8]). vmcnt ledger: 4 loads/thread/step -> waits 8/4/0.
// Epilogue re-derived for BN=128 (same staged-store structure, validated).
// attn fp8 Q/KV (R2/R8) + CSR unchanged.
// R10: identical resubmit — R9 bench was an infra failure ("container
// failed twice", same as R0 which passed on resubmit). Predictions carry.

using f16x8 = __attribute__((ext_vector_type(8))) _Float16;
using f32x4 = __attribute__((ext_vector_type(4))) float;

__device__ __forceinline__ void load_lds16(const void* g, void* l) {
  __builtin_amdgcn_global_load_lds((const __attribute__((address_space(1))) void*)g,
                                   (__attribute__((address_space(3))) void*)l,
                                   16, 0, 0);
}

// ---- fp8 e4m3 helpers (HW cvt on gfx950; software fallback kept for safety) ----
__device__ __forceinline__ void fp8x4_to_f32(unsigned int w, float* o4) {
#if __has_builtin(__builtin_amdgcn_cvt_pk_f32_fp8)
  auto lo = __builtin_amdgcn_cvt_pk_f32_fp8(w, false);
  auto hi = __builtin_amdgcn_cvt_pk_f32_fp8(w, true);
  o4[0] = lo[0]; o4[1] = lo[1]; o4[2] = hi[0]; o4[3] = hi[1];
#else
#pragma unroll
  for (int t = 0; t < 4; ++t) {
    unsigned int b = (w >> (8 * t)) & 0xFFu;
    unsigned short h = (unsigned short)(((b & 0x80u) << 8) | ((b & 0x7Fu) << 7));
    __half hv = *(__half*)&h;
    o4[t] = (float)hv * 256.0f;
  }
#endif
}

__device__ __forceinline__ unsigned int fp8_pack2_sw(float a, float b) {
  unsigned int r = 0;
#pragma unroll
  for (int t = 0; t < 2; ++t) {
    float f = t ? b : a;
    __half h = __float2half(f * (1.0f / 256.0f));
    unsigned short hb = *(unsigned short*)&h;
    unsigned int sign = (hb >> 8) & 0x80u;
    unsigned int mag = (hb & 0x7FFFu) + 0x40u;  // round
    unsigned int e = (mag >> 7) & 0x7Fu;
    if ((mag >> 7) > 0x7Eu) e = 0x7Eu;          // clamp below NaN pattern
    r |= (sign | e) << (8 * t);
  }
  return r;
}

__device__ __forceinline__ uint2 fp8_pack8(const float* f) {
#if __has_builtin(__builtin_amdgcn_cvt_pk_fp8_f32)
  int w0 = __builtin_amdgcn_cvt_pk_fp8_f32(f[0], f[1], 0, false);
  w0 = __builtin_amdgcn_cvt_pk_fp8_f32(f[2], f[3], w0, true);
  int w1 = __builtin_amdgcn_cvt_pk_fp8_f32(f[4], f[5], 0, false);
  w1 = __builtin_amdgcn_cvt_pk_fp8_f32(f[6], f[7], w1, true);
  uint2 r; r.x = (unsigned)w0; r.y = (unsigned)w1; return r;
#else
  uint2 r;
  r.x = fp8_pack2_sw(f[0], f[1]) | (fp8_pack2_sw(f[2], f[3]) << 16);
  r.y = fp8_pack2_sw(f[4], f[5]) | (fp8_pack2_sw(f[6], f[7]) << 16);
  return r;
#endif
}

// ---------------- prep: zero deg, zero H pad, convert x->fp16 ----------------
__global__ void prep_x_kernel(const float* __restrict__ x, __half* __restrict__ xh,
                              int* __restrict__ deg, __half* __restrict__ H,
                              int N, int Npad) {
  int t = blockIdx.x * 256 + threadIdx.x;
  if (t < N) deg[t] = 0;
  int nz = (Npad - N) * 64;  // pad vec8 slots of H
  if (t < nz) {
    f16x8 z = {};
    *(f16x8*)(H + (size_t)N * 512 + (size_t)t * 8) = z;
  }
  if (t < Npad * 16) {
    int row = t >> 4;
    f16x8 hv = {};
    if (row < N) {
      const float* g = x + (size_t)t * 8;
      float4 f0 = *(const float4*)g;
      float4 f1 = *(const float4*)(g + 4);
      hv[0] = (_Float16)f0.x; hv[1] = (_Float16)f0.y;
      hv[2] = (_Float16)f0.z; hv[3] = (_Float16)f0.w;
      hv[4] = (_Float16)f1.x; hv[5] = (_Float16)f1.y;
      hv[6] = (_Float16)f1.z; hv[7] = (_Float16)f1.w;
    }
    *(f16x8*)(xh + (size_t)t * 8) = hv;
  }
}

// ---------------- CSR build ----------------
__global__ void degree_kernel(const int* __restrict__ dst, int* __restrict__ deg, int E) {
  int e = blockIdx.x * blockDim.x + threadIdx.x;
  if (e < E) atomicAdd(&deg[dst[e]], 1);
}

__global__ __launch_bounds__(256)
void scan_a_kernel(const int* __restrict__ deg, int* __restrict__ rowptr,
                   int* __restrict__ bsum, int n) {
  __shared__ int tmp[256];
  int t = threadIdx.x;
  int i = blockIdx.x * 256 + t;
  int v = (i < n) ? deg[i] : 0;
  tmp[t] = v;
  __syncthreads();
#pragma unroll
  for (int off = 1; off < 256; off <<= 1) {
    int u = (t >= off) ? tmp[t - off] : 0;
    __syncthreads();
    tmp[t] += u;
    __syncthreads();
  }
  if (i < n) rowptr[i + 1] = tmp[t];
  if (t == 255) bsum[blockIdx.x] = tmp[255];
}

__global__ __launch_bounds__(256)
void scan_b_kernel(int* __restrict__ bsum, int nb) {
  __shared__ int tmp[256];
  int t = threadIdx.x;
  int v = (t < nb) ? bsum[t] : 0;
  tmp[t] = v;
  __syncthreads();
#pragma unroll
  for (int off = 1; off < 256; off <<= 1) {
    int u = (t >= off) ? tmp[t - off] : 0;
    __syncthreads();
    tmp[t] += u;
    __syncthreads();
  }
  if (t < nb) bsum[t] = tmp[t] - v;  // exclusive
}

__global__ __launch_bounds__(256)
void scan_c_kernel(int* __restrict__ rowptr, int* __restrict__ cursor,
                   const int* __restrict__ bsum, int n) {
  int i = blockIdx.x * 256 + threadIdx.x;
  if (i < n) {
    int r = rowptr[i + 1] + bsum[blockIdx.x];
    rowptr[i + 1] = r;
    cursor[i + 1] = r;
  }
  if (i == 0) { rowptr[0] = 0; cursor[0] = 0; }
}

__global__ void scatter_kernel(const int* __restrict__ src, const int* __restrict__ dst,
                               int* __restrict__ cursor, int* __restrict__ col, int E) {
  int e = blockIdx.x * blockDim.x + threadIdx.x;
  if (e < E) {
    int pos = atomicAdd(&cursor[dst[e]], 1);
    col[pos] = src[e];
  }
}

// ---------------- prep: weights/biases ----------------
__global__ __launch_bounds__(256)
void transpose_all_kernel(
    const float* __restrict__ Wq0, const float* __restrict__ Wk0,
    const float* __restrict__ Wv0, const float* __restrict__ Ws0,
    const float* __restrict__ Wq1, const float* __restrict__ Wk1,
    const float* __restrict__ Wv1, const float* __restrict__ Ws1,
    const float* __restrict__ Wq2, const float* __restrict__ Wk2,
    const float* __restrict__ Wv2, const float* __restrict__ Ws2,
    __half* __restrict__ Wt) {
  int z = blockIdx.z;
  int layer = z >> 2, m = z & 3;
  int K = (layer == 0) ? 128 : 512;
  int D = (layer == 2) ? 64 : 512;
  int c0 = blockIdx.x * 32, k0 = blockIdx.y * 32;
  if (c0 >= D || k0 >= K) return;
  const float* W;
  switch (z) {
    case 0: W = Wq0; break; case 1: W = Wk0; break;
    case 2: W = Wv0; break; case 3: W = Ws0; break;
    case 4: W = Wq1; break; case 5: W = Wk1; break;
    case 6: W = Wv1; break; case 7: W = Ws1; break;
    case 8: W = Wq2; break; case 9: W = Wk2; break;
    case 10: W = Wv2; break; default: W = Ws2; break;
  }
  __half* dstBase = Wt + ((layer == 0) ? 0 : (layer == 1) ? 262144 : 1310720);
  __shared__ float t[32][33];
  int tx = threadIdx.x & 31, ty = threadIdx.x >> 5;  // (32,8)
#pragma unroll
  for (int r = 0; r < 4; ++r)
    t[ty + 8 * r][tx] = W[(size_t)(k0 + ty + 8 * r) * D + c0 + tx];
  __syncthreads();
#pragma unroll
  for (int r = 0; r < 4; ++r)
    dstBase[(size_t)(m * D + c0 + ty + 8 * r) * K + k0 + tx] =
        __float2half(t[tx][ty + 8 * r]);
}

__global__ void bias_all_kernel(
    const float* __restrict__ b0, const float* __restrict__ b1,
    const float* __restrict__ b2, const float* __restrict__ b3,
    const float* __restrict__ b4, const float* __restrict__ b5,
    const float* __restrict__ b6, const float* __restrict__ b7,
    const float* __restrict__ b8, const float* __restrict__ b9,
    const float* __restrict__ b10, const float* __restrict__ b11,
    float* __restrict__ bias_arena) {
  int z = blockIdx.x;
  int layer = z >> 2, m = z & 3;
  int D = (layer == 2) ? 64 : 512;
  const float* b;
  switch (z) {
    case 0: b = b0; break; case 1: b = b1; break;
    case 2: b = b2; break; case 3: b = b3; break;
    case 4: b = b4; break; case 5: b = b5; break;
    case 6: b = b6; break; case 7: b = b7; break;
    case 8: b = b8; break; case 9: b = b9; break;
    case 10: b = b10; break; default: b = b11; break;
  }
  float* dst = bias_arena + ((layer == 0) ? 0 : (layer == 1) ? 2048 : 4096) + m * D;
  for (int c = threadIdx.x; c < D; c += 256) dst[c] = b[c];
}

// ---------------- MFMA GEMM: 128x128 block tile, 64x64 wave tile ----------------
// BK=32, 3-deep LDS pipeline (3 x 16KB = 48KB -> 3 blocks/CU). Counted vmcnt:
// 4 loads/thread/step, waits 8/4/0. acc[4][4] = 64 VGPR -> (256,3) safe.
// Epilogue: LDS-staged coalesced stores for BN=128.
template <int LAYER>
__global__ __launch_bounds__(256, 3)
void gemm_mfma_kernel(const __half* __restrict__ Aptr,
                      const __half* __restrict__ Wt,
                      const float* __restrict__ bias,
                      __half* __restrict__ QS, __half* __restrict__ KV,
                      unsigned char* __restrict__ Q8,
                      __half* __restrict__ S16) {
  constexpr int K = (LAYER == 0) ? 128 : 512;
  constexpr int lda = (LAYER == 0) ? 128 : 512;
  constexpr int NT = (LAYER == 2) ? 2 : 16;  // 128-wide n-tiles
  constexpr int NSTEP = K / 32;
  __shared__ __align__(16) char smem_raw[49152];  // 3 x 16KB
  __half* sm = (__half*)smem_raw;
  int tid = threadIdx.x;
  int wave = tid >> 6, lane = tid & 63;
  int wr = wave >> 1, wc = wave & 1;
  int bid = blockIdx.x;
  int xcd = bid & 7;
  int r = bid >> 3;
  int n0 = (r % NT) * 128;
  int m0 = ((r / NT) * 8 + xcd) * 128;
  // staging decomposition: lane -> (row-in-16, slot-in-4)
  int srow = lane >> 2;
  int sslot = lane & 3;
  int skc = (sslot ^ ((srow >> 1) & 3)) << 3;  // swizzled k offset (halves)
  // fragment read decomposition
  int quad = lane >> 4, rr = lane & 15;
  int rslot = (quad ^ ((rr >> 1) & 3)) << 3;   // read k offset within row

  f32x4 acc[4][4] = {};

  auto stage = [&](int buf, int kt) {
    __half* As = sm + buf * 8192;   // 16KB buffer: A 4096 halves + B 4096
    __half* Bs = As + 4096;
#pragma unroll
    for (int p = 0; p < 2; ++p) {
      int rbase = wave * 32 + p * 16;
      const __half* ga = Aptr + (size_t)(m0 + rbase + srow) * lda + kt + skc;
      load_lds16(ga, &As[rbase * 32]);
    }
#pragma unroll
    for (int p = 0; p < 2; ++p) {
      int rbase = wave * 32 + p * 16;
      const __half* gb = Wt + (size_t)(n0 + rbase + srow) * K + kt + skc;
      load_lds16(gb, &Bs[rbase * 32]);
    }
  };

  // prologue: 3 tiles in flight (NSTEP >= 4 for all layers)
  stage(0, 0);
  stage(1, 32);
  stage(2, 64);

  for (int t = 0; t < NSTEP; ++t) {
    if (t + 2 < NSTEP)      asm volatile("s_waitcnt vmcnt(8)" ::: "memory");
    else if (t + 1 < NSTEP) asm volatile("s_waitcnt vmcnt(4)" ::: "memory");
    else                    asm volatile("s_waitcnt vmcnt(0)" ::: "memory");
    __builtin_amdgcn_s_barrier();  // all waves' tile-t loads landed

    const __half* As = sm + (t % 3) * 8192;
    const __half* Bs = As + 4096;
    f16x8 a[4], b[4];
#pragma unroll
    for (int i = 0; i < 4; ++i) {
      int row = wr * 64 + i * 16 + rr;
      a[i] = *(const f16x8*)&As[row * 32 + rslot];
    }
#pragma unroll
    for (int j = 0; j < 4; ++j) {
      int row = wc * 64 + j * 16 + rr;
      b[j] = *(const f16x8*)&Bs[row * 32 + rslot];
    }
    __builtin_amdgcn_s_setprio(1);
#pragma unroll
    for (int i = 0; i < 4; ++i)
#pragma unroll
      for (int j = 0; j < 4; ++j)
        acc[i][j] = __builtin_amdgcn_mfma_f32_16x16x32_f16(a[i], b[j], acc[i][j], 0, 0, 0);
    __builtin_amdgcn_s_setprio(0);
    __builtin_amdgcn_s_barrier();  // reads of buf t%3 all consumed
    if (t + 3 < NSTEP) stage(t % 3, (t + 3) * 32);
  }
  __syncthreads();  // protect epilogue's smem reuse

  // ---- epilogue: LDS-staged coalesced stores (BN=128) ----
  int cl = lane & 15, rb = (lane >> 4) * 4;

  if constexpr (LAYER == 2) {
    // fp16; 2 rounds of 64 rows; per-chunk seg routing (2 segs per block)
    __half* S = (__half*)smem_raw;  // [64][136] halves
#pragma unroll
    for (int round = 0; round < 2; ++round) {
      if (wr == round) {
#pragma unroll
        for (int i = 0; i < 4; ++i)
#pragma unroll
          for (int j = 0; j < 4; ++j) {
            int colL = wc * 64 + j * 16 + cl;
            float bj = bias[n0 + colL];
#pragma unroll
            for (int rg = 0; rg < 4; ++rg) {
              int rowL = i * 16 + rb + rg;
              S[rowL * 136 + colL] = __float2half(acc[i][j][rg] + bj);
            }
          }
      }
      __syncthreads();
#pragma unroll
      for (int it = 0; it < 4; ++it) {
        int id = it * 256 + tid;
        int rowL = id >> 4, ch = id & 15;
        int grow = m0 + round * 64 + rowL;
        int gcol = n0 + ch * 8;
        int seg = gcol >> 6, c = gcol & 63;
        __half* base = (seg == 0) ? QS + (size_t)grow * 128 + c
                     : (seg == 3) ? QS + (size_t)grow * 128 + 64 + c
                     : (seg == 1) ? KV + (size_t)grow * 128 + c
                                  : KV + (size_t)grow * 128 + 64 + c;
        *(f16x8*)base = *(const f16x8*)&S[rowL * 136 + ch * 8];
      }
      __syncthreads();
    }
  } else {
    const int msegB = n0 >> 9;   // block-uniform mseg (0=Q,1=K,2=V,3=S)
    const int cb = n0 & 511;     // col base within the 512-wide matrix
    if (msegB == 3) {
      // fp16 path -> S16 (512-half rows)
      __half* S = (__half*)smem_raw;  // [64][136] halves
#pragma unroll
      for (int round = 0; round < 2; ++round) {
        if (wr == round) {
#pragma unroll
          for (int i = 0; i < 4; ++i)
#pragma unroll
            for (int j = 0; j < 4; ++j) {
              int colL = wc * 64 + j * 16 + cl;
              float bj = bias[n0 + colL];
#pragma unroll
              for (int rg = 0; rg < 4; ++rg) {
                int rowL = i * 16 + rb + rg;
                S[rowL * 136 + colL] = __float2half(acc[i][j][rg] + bj);
              }
            }
        }
        __syncthreads();
#pragma unroll
        for (int it = 0; it < 4; ++it) {
          int id = it * 256 + tid;
          int rowL = id >> 4, ch = id & 15;
          int grow = m0 + round * 64 + rowL;
          int colb = ch * 8;
          *(f16x8*)(S16 + (size_t)grow * 512 + cb + colb) =
              *(const f16x8*)&S[rowL * 136 + colb];
        }
        __syncthreads();
      }
    } else if (msegB == 0) {
      // fp8 dense path -> Q8 (512-byte rows)
      float* S = (float*)smem_raw;  // [32][132] floats
#pragma unroll
      for (int round = 0; round < 4; ++round) {
        if (wr == (round >> 1)) {
#pragma unroll
          for (int ii = 0; ii < 2; ++ii) {
#pragma unroll
            for (int j = 0; j < 4; ++j) {
              int colL = wc * 64 + j * 16 + cl;
              float bj = bias[n0 + colL];
#pragma unroll
              for (int rg = 0; rg < 4; ++rg) {
                int rowL = ii * 16 + rb + rg;
                S[rowL * 132 + colL] = acc[(round & 1) * 2 + ii][j][rg] + bj;
              }
            }
          }
        }
        __syncthreads();
#pragma unroll
        for (int it = 0; it < 2; ++it) {
          int id = it * 256 + tid;
          int rowL = id >> 4, ch = id & 15;
          int grow = m0 + round * 32 + rowL;
          int colb = ch * 8;
          float f[8];
          f32x4 lo = *(const f32x4*)&S[rowL * 132 + colb];
          f32x4 hi = *(const f32x4*)&S[rowL * 132 + colb + 4];
          f[0] = lo[0]; f[1] = lo[1]; f[2] = lo[2]; f[3] = lo[3];
          f[4] = hi[0]; f[5] = hi[1]; f[6] = hi[2]; f[7] = hi[3];
          uint2 pk = fp8_pack8(f);
          *(uint2*)(Q8 + (size_t)grow * 512 + cb + colb) = pk;
        }
        __syncthreads();
      }
    } else {
      // fp8 path -> KV8 interleaved [K 8B | V 8B] per 8-col group (1KB rows)
      float* S = (float*)smem_raw;  // [32][132] floats
      unsigned char* KV8 = (unsigned char*)KV;
      const int koff = (msegB == 2) ? 8 : 0;
#pragma unroll
      for (int round = 0; round < 4; ++round) {
        if (wr == (round >> 1)) {
#pragma unroll
          for (int ii = 0; ii < 2; ++ii) {
#pragma unroll
            for (int j = 0; j < 4; ++j) {
              int colL = wc * 64 + j * 16 + cl;
              float bj = bias[n0 + colL];
#pragma unroll
              for (int rg = 0; rg < 4; ++rg) {
                int rowL = ii * 16 + rb + rg;
                S[rowL * 132 + colL] = acc[(round & 1) * 2 + ii][j][rg] + bj;
              }
            }
          }
        }
        __syncthreads();
#pragma unroll
        for (int it = 0; it < 2; ++it) {
          int id = it * 256 + tid;
          int rowL = id >> 4, ch = id & 15;
          int grow = m0 + round * 32 + rowL;
          int colb = ch * 8;
          float f[8];
          f32x4 lo = *(const f32x4*)&S[rowL * 132 + colb];
          f32x4 hi = *(const f32x4*)&S[rowL * 132 + colb + 4];
          f[0] = lo[0]; f[1] = lo[1]; f[2] = lo[2]; f[3] = lo[3];
          f[4] = hi[0]; f[5] = hi[1]; f[6] = hi[2]; f[7] = hi[3];
          uint2 pk = fp8_pack8(f);
          *(uint2*)(KV8 + (size_t)grow * 1024 + ((cb + colb) >> 3) * 16 + koff) = pk;
        }
        __syncthreads();
      }
    }
  }
}

// ---------------- attention H=8 C=64: one WAVE per node, fp8 Q/KV ----------------
__global__ __launch_bounds__(256)
void attn_h8_kernel(const unsigned char* __restrict__ Q8,
                    const __half* __restrict__ S16,
                    const unsigned char* __restrict__ KV8,
                    const int* __restrict__ rowptr, const int* __restrict__ col,
                    __half* __restrict__ Hout, int N) {
  int n = blockIdx.x * 4 + (threadIdx.x >> 6);
  if (n >= N) return;
  int lane = threadIdx.x & 63;

  uint2 qw = *(const uint2*)(Q8 + (size_t)n * 512 + lane * 8);
  float qf[8];
  fp8x4_to_f32(qw.x, qf);
  fp8x4_to_f32(qw.y, qf + 4);

  int e0 = rowptr[n], e1 = rowptr[n + 1];
  float m = -INFINITY, l = 0.f;
  float o[8] = {};

  const uint4* KVL = (const uint4*)KV8;  // one row = 64 uint4 (lane-interleaved K|V)
  uint4 ea = {}, eb = {};
  int i = e0;
  if (i < e1)     ea = KVL[(size_t)col[i] * 64 + lane];
  if (i + 1 < e1) eb = KVL[(size_t)col[i + 1] * 64 + lane];

  while (i < e1) {
    int rem = e1 - i;
    uint4 ec = {}, ed = {};
    if (rem > 2) ec = KVL[(size_t)col[i + 2] * 64 + lane];
    if (rem > 3) ed = KVL[(size_t)col[i + 3] * 64 + lane];
    float ka[8], kb[8];
    fp8x4_to_f32(ea.x, ka); fp8x4_to_f32(ea.y, ka + 4);
    fp8x4_to_f32(eb.x, kb); fp8x4_to_f32(eb.y, kb + 4);
    float pa = 0.f, pb = 0.f;
#pragma unroll
    for (int j = 0; j < 8; ++j) { pa += ka[j] * qf[j]; pb += kb[j] * qf[j]; }
    pa += __shfl_xor(pa, 1, 64); pb += __shfl_xor(pb, 1, 64);
    pa += __shfl_xor(pa, 2, 64); pb += __shfl_xor(pb, 2, 64);
    pa += __shfl_xor(pa, 4, 64); pb += __shfl_xor(pb, 4, 64);
    float a0 = pa * 0.125f;
    float va[8];
    fp8x4_to_f32(ea.z, va); fp8x4_to_f32(ea.w, va + 4);
    if (rem > 1) {
      float vb[8];
      fp8x4_to_f32(eb.z, vb); fp8x4_to_f32(eb.w, vb + 4);
      float a1 = pb * 0.125f;
      float mn = fmaxf(m, fmaxf(a0, a1));
      float sc = __expf(m - mn);
      float ex0 = __expf(a0 - mn), ex1 = __expf(a1 - mn);
      l = l * sc + ex0 + ex1;
#pragma unroll
      for (int c = 0; c < 8; ++c)
        o[c] = o[c] * sc + ex0 * va[c] + ex1 * vb[c];
      m = mn;
    } else {
      float mn = fmaxf(m, a0);
      float sc = __expf(m - mn);
      float ex0 = __expf(a0 - mn);
      l = l * sc + ex0;
#pragma unroll
      for (int c = 0; c < 8; ++c) o[c] = o[c] * sc + ex0 * va[c];
      m = mn;
    }
    ea = ec; eb = ed;
    i += 2;
  }

  float inv = 1.f / (l + 1e-16f);
  f16x8 sv = __builtin_nontemporal_load((const f16x8*)(S16 + (size_t)n * 512 + lane * 8));
  f16x8 hv;
#pragma unroll
  for (int c = 0; c < 8; ++c) {
    float r = o[c] * inv + (float)sv[c];
    hv[c] = (_Float16)fmaxf(r, 0.f);
  }
  __builtin_nontemporal_store(hv, (f16x8*)(Hout + (size_t)n * 512 + lane * 8));
}

// ---------------- attention H=1 C=64: 8-lane group per node, fp16 KV ----------------
__global__ __launch_bounds__(256)
void attn_h1_kernel(const __half* __restrict__ QS, const __half* __restrict__ KV,
                    const int* __restrict__ rowptr, const int* __restrict__ col,
                    float* __restrict__ out, int N) {
  int n = (blockIdx.x * 256 + threadIdx.x) >> 3;
  if (n >= N) return;
  int gl = threadIdx.x & 7;
  size_t rbase = (size_t)n * 128 + gl * 8;

  f16x8 qv = __builtin_nontemporal_load((const f16x8*)(QS + rbase));
  float qf[8];
#pragma unroll
  for (int j = 0; j < 8; ++j) qf[j] = (float)qv[j];

  int e0 = rowptr[n], e1 = rowptr[n + 1];
  float m = -INFINITY, l = 0.f;
  float o[8] = {};

  f16x8 ka = {}, va = {}, kb = {}, vb = {};
  int i = e0;
  if (i < e1) {
    const __half* p = KV + (size_t)col[i] * 128 + gl * 8;
    ka = *(const f16x8*)p; va = *(const f16x8*)(p + 64);
  }
  if (i + 1 < e1) {
    const __half* p = KV + (size_t)col[i + 1] * 128 + gl * 8;
    kb = *(const f16x8*)p; vb = *(const f16x8*)(p + 64);
  }

  while (i < e1) {
    int rem = e1 - i;
    f16x8 kc = {}, vc = {}, kd = {}, vd = {};
    if (rem > 2) {
      const __half* p = KV + (size_t)col[i + 2] * 128 + gl * 8;
      kc = *(const f16x8*)p; vc = *(const f16x8*)(p + 64);
    }
    if (rem > 3) {
      const __half* p = KV + (size_t)col[i + 3] * 128 + gl * 8;
      kd = *(const f16x8*)p; vd = *(const f16x8*)(p + 64);
    }
    float pa = 0.f, pb = 0.f;
#pragma unroll
    for (int j = 0; j < 8; ++j) { pa += (float)ka[j] * qf[j]; pb += (float)kb[j] * qf[j]; }
    pa += __shfl_xor(pa, 1, 64); pb += __shfl_xor(pb, 1, 64);
    pa += __shfl_xor(pa, 2, 64); pb += __shfl_xor(pb, 2, 64);
    pa += __shfl_xor(pa, 4, 64); pb += __shfl_xor(pb, 4, 64);
    float a0 = pa * 0.125f;
    if (rem > 1) {
      float a1 = pb * 0.125f;
      float mn = fmaxf(m, fmaxf(a0, a1));
      float sc = __expf(m - mn);
      float ea = __expf(a0 - mn), eb = __expf(a1 - mn);
      l = l * sc + ea + eb;
#pragma unroll
      for (int c = 0; c < 8; ++c)
        o[c] = o[c] * sc + ea * (float)va[c] + eb * (float)vb[c];
      m = mn;
    } else {
      float mn = fmaxf(m, a0);
      float sc = __expf(m - mn);
      float ea = __expf(a0 - mn);
      l = l * sc + ea;
#pragma unroll
      for (int c = 0; c < 8; ++c) o[c] = o[c] * sc + ea * (float)va[c];
      m = mn;
    }
    ka = kc; va = vc; kb = kd; vb = vd;
    i += 2;
  }

  float inv = 1.f / (l + 1e-16f);
  f16x8 sv = __builtin_nontemporal_load((const f16x8*)(QS + rbase + 64));
  f32x4 r0, r1;
#pragma unroll
  for (int c = 0; c < 4; ++c) r0[c] = o[c] * inv + (float)sv[c];
#pragma unroll
  for (int c = 0; c < 4; ++c) r1[c] = o[c + 4] * inv + (float)sv[c + 4];
  float* op = out + (size_t)n * 64 + gl * 8;
  *(f32x4*)op = r0;
  *(f32x4*)(op + 4) = r1;
}

extern "C" void kernel_launch(void* const* d_in, const int* in_sizes, int n_in,
                              void* d_out, int out_size, void* d_ws, size_t ws_size,
                              hipStream_t stream) {
  const float* x = (const float*)d_in[0];
  const int* ei = (const int*)d_in[1];
  const int N = in_sizes[0] / 128;
  const int E = in_sizes[1] / 2;
  // pad M so mtiles is a multiple of 8 (XCD striping)
  const int Npad = ((N + 1023) / 1024) * 1024;
  const int mtiles = Npad / 128;
  const int* srcp = ei;
  const int* dstp = ei + E;

  const float* Wq0 = (const float*)d_in[2];  const float* bq0 = (const float*)d_in[3];
  const float* Wk0 = (const float*)d_in[4];  const float* bk0 = (const float*)d_in[5];
  const float* Wv0 = (const float*)d_in[6];  const float* bv0 = (const float*)d_in[7];
  const float* Ws0 = (const float*)d_in[8];  const float* bs0 = (const float*)d_in[9];
  const float* Wq1 = (const float*)d_in[10]; const float* bq1 = (const float*)d_in[11];
  const float* Wk1 = (const float*)d_in[12]; const float* bk1 = (const float*)d_in[13];
  const float* Wv1 = (const float*)d_in[14]; const float* bv1 = (const float*)d_in[15];
  const float* Ws1 = (const float*)d_in[16]; const float* bs1 = (const float*)d_in[17];
  const float* Wq2 = (const float*)d_in[18]; const float* bq2 = (const float*)d_in[19];
  const float* Wk2 = (const float*)d_in[20]; const float* bk2 = (const float*)d_in[21];
  const float* Wv2 = (const float*)d_in[22]; const float* bv2 = (const float*)d_in[23];
  const float* Ws2 = (const float*)d_in[24]; const float* bs2 = (const float*)d_in[25];

  // ---- workspace layout ----
  char* p = (char*)d_ws;
  __half* S16 = (__half*)p;              p += (size_t)Npad * 512 * 2;   // 51.4 MB (S; layer2 reuses as QS 128-half rows)
  unsigned char* Q8 = (unsigned char*)p; p += (size_t)Npad * 512;       // 25.7 MB
  __half* KV = (__half*)p;               p += (size_t)Npad * 1024;      // fp8 1KB rows; layer2 fp16 256B rows
  __half* H  = (__half*)p;               p += (size_t)Npad * 512 * 2;   // 51.4 MB
  __half* xh = (__half*)p;               p += (size_t)Npad * 128 * 2;   // 12.8 MB
  __half* Wt = (__half*)p;               p += (size_t)1441792 * 2;      // 2.88 MB
  float* bias_arena = (float*)p;         p += 4352 * 4;
  int* deg    = (int*)p;                 p += (size_t)N * 4;
  int* rowptr = (int*)p;                 p += (size_t)(N + 1) * 4;
  int* cursor = (int*)p;                 p += (size_t)(N + 1) * 4;
  int* colv   = (int*)p;                 p += (size_t)E * 4;
  int* bsum   = (int*)p;                 p += 256 * 4;
  size_t need = p - (char*)d_ws;
  if (ws_size < need) {
    fprintf(stderr, "kernel_launch: ws_size=%zu < need=%zu — aborting cleanly\n",
            ws_size, need);
    return;
  }

  const int nscan = (N + 255) / 256;

  // ---- prep ----
  transpose_all_kernel<<<dim3(16, 16, 12), 256, 0, stream>>>(
      Wq0, Wk0, Wv0, Ws0, Wq1, Wk1, Wv1, Ws1, Wq2, Wk2, Wv2, Ws2, Wt);
  bias_all_kernel<<<12, 256, 0, stream>>>(
      bq0, bk0, bv0, bs0, bq1, bk1, bv1, bs1, bq2, bk2, bv2, bs2, bias_arena);
  prep_x_kernel<<<(Npad * 16 + 255) / 256, 256, 0, stream>>>(x, xh, deg, H, N, Npad);

  // ---- CSR build ----
  degree_kernel<<<(E + 255) / 256, 256, 0, stream>>>(dstp, deg, E);
  scan_a_kernel<<<nscan, 256, 0, stream>>>(deg, rowptr, bsum, N);
  scan_b_kernel<<<1, 256, 0, stream>>>(bsum, nscan);
  scan_c_kernel<<<nscan, 256, 0, stream>>>(rowptr, cursor, bsum, N);
  scatter_kernel<<<(E + 255) / 256, 256, 0, stream>>>(srcp, dstp, cursor, colv, E);

  __half* Wt0 = Wt;
  __half* Wt1 = Wt + 262144;
  __half* Wt2 = Wt + 1310720;

  // ---- layer 0: K=128, D=2048 cols, n-tiles 16 ----
  gemm_mfma_kernel<0><<<mtiles * 16, 256, 0, stream>>>(
      xh, Wt0, bias_arena, S16, KV, Q8, S16);
  attn_h8_kernel<<<(N + 3) / 4, 256, 0, stream>>>(Q8, S16, (const unsigned char*)KV,
                                                  rowptr, colv, H, N);

  // ---- layer 1: K=512, D=2048 cols, n-tiles 16 ----
  gemm_mfma_kernel<1><<<mtiles * 16, 256, 0, stream>>>(
      H, Wt1, bias_arena + 2048, S16, KV, Q8, S16);
  attn_h8_kernel<<<(N + 3) / 4, 256, 0, stream>>>(Q8, S16, (const unsigned char*)KV,
                                                  rowptr, colv, H, N);

  // ---- layer 2: K=512, D=256 cols, n-tiles 2 (fp16 path, S16 reused as QS) ----
  gemm_mfma_kernel<2><<<mtiles * 2, 256, 0, stream>>>(
      H, Wt2, bias_arena + 4096, S16, KV, Q8, S16);
  attn_h1_kernel<<<(N + 31) / 32, 256, 0, stream>>>(S16, KV, rowptr, colv,
                                                    (float*)d_out, N);
}